// Round 3
// baseline (661.865 us; speedup 1.0000x reference)
//
#include <hip/hip_runtime.h>
#include <hip/hip_bf16.h>

#define NN 100000
#define NE 600000

using bf16 = __hip_bfloat16;
typedef unsigned short ushort_t;

__device__ __forceinline__ float b2f(bf16 v) { return __bfloat162float(v); }

__device__ __forceinline__ float bu2f(unsigned int u16) {
    union { float f; unsigned int i; } c; c.i = u16 << 16; return c.f;
}
__device__ __forceinline__ unsigned int f2bu(float f) {
    bf16 h = __float2bfloat16(f);
    return (unsigned int)*reinterpret_cast<unsigned short*>(&h);
}
__device__ __forceinline__ float4 ld4bf(uint2 u) {
    float4 r;
    r.x = bu2f(u.x & 0xffffu); r.y = bu2f(u.x >> 16);
    r.z = bu2f(u.y & 0xffffu); r.w = bu2f(u.y >> 16);
    return r;
}
__device__ __forceinline__ uint2 st4bf(float4 a) {
    uint2 u;
    u.x = f2bu(a.x) | (f2bu(a.y) << 16);
    u.y = f2bu(a.z) | (f2bu(a.w) << 16);
    return u;
}

template<bool BF16>
__device__ __forceinline__ float4 ld4(const void* base, size_t idx4) {
    if constexpr (BF16) return ld4bf(((const uint2*)base)[idx4]);
    else return ((const float4*)base)[idx4];
}
template<bool BF16>
__device__ __forceinline__ void st4(void* base, size_t idx4, float4 v) {
    if constexpr (BF16) ((uint2*)base)[idx4] = st4bf(v);
    else ((float4*)base)[idx4] = v;
}

// ---------- dtype probe: fp32 (flag=1) vs bf16 (flag=0) ----------
__global__ void k_probe(const void* x, int* flag) {
    __shared__ int bad;
    if (threadIdx.x == 0) bad = 0;
    __syncthreads();
    const unsigned short* u = (const unsigned short*)x;
    int mybad = 0;
    for (int i = threadIdx.x; i < 2048; i += 256) {
        unsigned short h = u[i];
        unsigned int e = (h >> 7) & 0xffu;
        bool zero = (h & 0x7fffu) == 0;
        bool plaus = zero || (e >= 96u && e <= 140u);
        if (!plaus) mybad++;
    }
    atomicAdd(&bad, mybad);
    __syncthreads();
    if (threadIdx.x == 0) *flag = (bad > 64) ? 1 : 0;
}

__global__ void k_cvt(const void* src, float* dst, int n, const int* flag) {
    int i = blockIdx.x * 256 + threadIdx.x;
    if (i >= n) return;
    if (*flag) dst[i] = ((const float*)src)[i];
    else       dst[i] = b2f(((const bf16*)src)[i]);
}

__global__ void k_cvt_params(const void* W1, const void* b1, const void* W2, const void* b2,
                             const void* W3, const void* b3, const void* W4, const void* b4,
                             const void* C2, const void* L1W, const void* L1b,
                             const void* L2W, const void* L2b, const void* L3W, const void* L3b,
                             float* dst, const int* flag) {
    int i = blockIdx.x * 256 + threadIdx.x;
    const void* p; int off;
    if      (i < 256)    { p = W1;  off = i; }
    else if (i < 288)    { p = b1;  off = i - 256; }
    else if (i < 4384)   { p = W2;  off = i - 288; }
    else if (i < 4512)   { p = b2;  off = i - 4384; }
    else if (i < 20896)  { p = W3;  off = i - 4512; }
    else if (i < 21024)  { p = b3;  off = i - 20896; }
    else if (i < 25120)  { p = W4;  off = i - 21024; }
    else if (i < 25152)  { p = b4;  off = i - 25120; }
    else if (i < 25156)  { p = C2;  off = i - 25152; }
    else if (i < 33860)  { p = L1W; off = i - 25156; }
    else if (i < 33988)  { p = L1b; off = i - 33860; }
    else if (i < 50372)  { p = L2W; off = i - 33988; }
    else if (i < 50500)  { p = L2b; off = i - 50372; }
    else if (i < 51780)  { p = L3W; off = i - 50500; }
    else if (i < 51790)  { p = L3b; off = i - 51780; }
    else return;
    if (*flag) dst[i] = ((const float*)p)[off];
    else       dst[i] = b2f(((const bf16*)p)[off]);
}

// ---------- prep ----------
__global__ void k_init(float* deg, int* counts, int* cursor, float* x0x1) {
    int i = blockIdx.x * 256 + threadIdx.x;
    if (i < NN) { deg[i] = 1.0f; counts[i] = 0; cursor[i] = 0; }
    if (i < 64) x0x1[i] = 0.0f;
}

__global__ void k_hist(const int* dstI, const float* ewf, float* deg, int* counts) {
    int e = blockIdx.x * 256 + threadIdx.x;
    if (e >= NE) return;
    int d = dstI[e];
    atomicAdd(&deg[d], ewf[e]);
    atomicAdd(&counts[d], 1);
}

__global__ void k_rsqrt(float* deg) {
    int i = blockIdx.x * 256 + threadIdx.x;
    if (i < NN) deg[i] = rsqrtf(deg[i]);
}

__global__ void k_scan1(const int* counts, int* row_off, int* blk) {
    __shared__ int sm[1024];
    int t = threadIdx.x;
    int i = blockIdx.x * 1024 + t;
    int v = (i < NN) ? counts[i] : 0;
    sm[t] = v;
    __syncthreads();
    for (int off = 1; off < 1024; off <<= 1) {
        int x = (t >= off) ? sm[t - off] : 0;
        __syncthreads();
        sm[t] += x;
        __syncthreads();
    }
    if (i < NN) row_off[i] = sm[t] - v;
    if (t == 1023) blk[blockIdx.x] = sm[t];
}

__global__ void k_scan2(int* blk) {
    if (threadIdx.x == 0 && blockIdx.x == 0) {
        int acc = 0;
        for (int i = 0; i < 98; i++) { int v = blk[i]; blk[i] = acc; acc += v; }
    }
}

__global__ void k_scan3(int* row_off, const int* blk) {
    int i = blockIdx.x * 256 + threadIdx.x;
    if (i < NN) row_off[i] += blk[i >> 10];
}

__global__ void k_fill(const int* srcI, const int* dstI, const float* ewf, const float* dinv,
                       const int* row_off, int* cursor, int* srcs, float* normv) {
    int e = blockIdx.x * 256 + threadIdx.x;
    if (e >= NE) return;
    int s = srcI[e], d = dstI[e];
    int pos = row_off[d] + atomicAdd(&cursor[d], 1);
    srcs[pos] = s;
    normv[pos] = dinv[s] * ewf[e] * dinv[d];
}

// ---------- dense: T = h_in @ W ----------
template<int CIN, int COUT, bool BIN, bool BOUT>
__global__ void k_gemm(const void* hin, const float* __restrict__ Wf, void* __restrict__ hW) {
    constexpr int CG = COUT / 4;
    constexpr int ING = CIN / 4;
    constexpr int NH = NN / 2;
    int tid = blockIdx.x * 256 + threadIdx.x;
    int n = tid / CG, cg = tid - n * CG;
    if (n >= NH) return;
    int n2 = n + NH;
    const float4* wr = (const float4*)Wf;
    float4 a0 = make_float4(0.f, 0.f, 0.f, 0.f);
    float4 a1 = make_float4(0.f, 0.f, 0.f, 0.f);
#pragma unroll
    for (int k4 = 0; k4 < ING; k4++) {
        float4 x0 = ld4<BIN>(hin, (size_t)n * ING + k4);
        float4 x1 = ld4<BIN>(hin, (size_t)n2 * ING + k4);
        float xs0[4] = {x0.x, x0.y, x0.z, x0.w};
        float xs1[4] = {x1.x, x1.y, x1.z, x1.w};
#pragma unroll
        for (int j = 0; j < 4; j++) {
            float4 w = wr[(k4 * 4 + j) * CG + cg];
            a0.x = fmaf(xs0[j], w.x, a0.x); a0.y = fmaf(xs0[j], w.y, a0.y);
            a0.z = fmaf(xs0[j], w.z, a0.z); a0.w = fmaf(xs0[j], w.w, a0.w);
            a1.x = fmaf(xs1[j], w.x, a1.x); a1.y = fmaf(xs1[j], w.y, a1.y);
            a1.z = fmaf(xs1[j], w.z, a1.z); a1.w = fmaf(xs1[j], w.w, a1.w);
        }
    }
    st4<BOUT>(hW, (size_t)n * CG + cg, a0);
    st4<BOUT>(hW, (size_t)n2 * CG + cg, a1);
}

// ---------- sparse aggregate + bias + relu (+ segment_max) ----------
template<int COUT, bool DOMAX, bool BT, bool BH>
__global__ void k_gather(const void* __restrict__ hW, const float* __restrict__ dinv,
                         const int* __restrict__ row_off, const int* __restrict__ counts,
                         const int* __restrict__ srcs, const float* __restrict__ normv,
                         const float* __restrict__ bias, void* __restrict__ hout,
                         float* xmax) {
    constexpr int CG = COUT / 4;
    __shared__ int smax[COUT];
    int tid = blockIdx.x * 256 + threadIdx.x;
    int n = tid / CG, cg = tid - n * CG;
    if (DOMAX) {
        if (threadIdx.x < COUT) smax[threadIdx.x] = 0;
        __syncthreads();
    }
    float4 acc = make_float4(0.f, 0.f, 0.f, 0.f);
    bool valid = (n < NN);
    if (valid) {
        float di = dinv[n];
        float d2 = di * di;
        float4 s4 = ld4<BT>(hW, (size_t)n * CG + cg);
        acc.x = s4.x * d2; acc.y = s4.y * d2; acc.z = s4.z * d2; acc.w = s4.w * d2;
        int start = row_off[n];
        int len = counts[n];
        for (int i = 0; i < len; i++) {
            int s = srcs[start + i];
            float w = normv[start + i];
            float4 v = ld4<BT>(hW, (size_t)s * CG + cg);
            acc.x = fmaf(w, v.x, acc.x); acc.y = fmaf(w, v.y, acc.y);
            acc.z = fmaf(w, v.z, acc.z); acc.w = fmaf(w, v.w, acc.w);
        }
        const float4* b4 = (const float4*)bias;
        float4 bb = b4[cg];
        acc.x = fmaxf(acc.x + bb.x, 0.f);
        acc.y = fmaxf(acc.y + bb.y, 0.f);
        acc.z = fmaxf(acc.z + bb.z, 0.f);
        acc.w = fmaxf(acc.w + bb.w, 0.f);
        st4<BH>(hout, (size_t)n * CG + cg, acc);
    }
    if (DOMAX) {
        if (valid) {   // relu output >= 0 so int-compare on float bits is monotone
            atomicMax(&smax[cg * 4 + 0], __float_as_int(acc.x));
            atomicMax(&smax[cg * 4 + 1], __float_as_int(acc.y));
            atomicMax(&smax[cg * 4 + 2], __float_as_int(acc.z));
            atomicMax(&smax[cg * 4 + 3], __float_as_int(acc.w));
        }
        __syncthreads();
        if (threadIdx.x < COUT) atomicMax((int*)&xmax[threadIdx.x], smax[threadIdx.x]);
    }
}

// ---------- head MLP + softmax + fp32 output ----------
__global__ void k_mlp(const float* x0x1, const float* Pc, float* out) {
    const float* C2  = Pc + 25152;
    const float* L1W = Pc + 25156;
    const float* L1b = Pc + 33860;
    const float* L2W = Pc + 33988;
    const float* L2b = Pc + 50372;
    const float* L3W = Pc + 50500;
    const float* L3b = Pc + 51780;
    __shared__ float code[68], z1[128], z2[128];
    int t = threadIdx.x;
    if (t < 64) code[t] = x0x1[t];
    else if (t < 68) code[t] = C2[t - 64];
    __syncthreads();
    float acc = L1b[t];
    for (int i = 0; i < 68; i++) acc = fmaf(code[i], L1W[i * 128 + t], acc);
    z1[t] = fmaxf(acc, 0.f);
    __syncthreads();
    acc = L2b[t];
    for (int i = 0; i < 128; i++) acc = fmaf(z1[i], L2W[i * 128 + t], acc);
    z2[t] = fmaxf(acc, 0.f);
    __syncthreads();
    if (t == 0) {
        float lg[10];
        for (int c = 0; c < 10; c++) {
            float a = L3b[c];
            for (int i = 0; i < 128; i++) a = fmaf(z2[i], L3W[i * 10 + c], a);
            lg[c] = a;
        }
        float m = lg[0];
        for (int c = 1; c < 10; c++) m = fmaxf(m, lg[c]);
        float s = 0.f;
        for (int c = 0; c < 10; c++) { lg[c] = __expf(lg[c] - m); s += lg[c]; }
        float inv = 1.f / s;
        for (int c = 0; c < 10; c++) out[c] = lg[c] * inv;
    }
    if (t < 68) out[10 + t] = code[t];
}

// ---------- full pipeline for a given (BT, BH) storage mode ----------
template<bool BT, bool BH>
static void run_pipeline(const void* x, const int* ei, const void* ew, const void* C2ER,
                         void* const* d_in, float* out,
                         void* H, void* T, float* xf, float* ewf, int* srcs, float* normv,
                         float* dinv, int* counts, int* rowoff, int* cursor, int* blk,
                         float* x0x1, float* Pc, int* flag, hipStream_t stream) {
    const int* srcI = ei;
    const int* dstI = ei + NE;
    dim3 B(256);
    k_probe<<<dim3(1), B, 0, stream>>>(x, flag);
    k_cvt<<<dim3((NN * 8 + 255) / 256), B, 0, stream>>>(x, xf, NN * 8, flag);
    k_cvt<<<dim3((NE + 255) / 256), B, 0, stream>>>(ew, ewf, NE, flag);
    k_cvt_params<<<dim3((51790 + 255) / 256), B, 0, stream>>>(
        d_in[5], d_in[6], d_in[7], d_in[8], d_in[9], d_in[10], d_in[11], d_in[12],
        C2ER, d_in[13], d_in[14], d_in[15], d_in[16], d_in[17], d_in[18], Pc, flag);

    k_init<<<dim3((NN + 255) / 256), B, 0, stream>>>(dinv, counts, cursor, x0x1);
    k_hist<<<dim3((NE + 255) / 256), B, 0, stream>>>(dstI, ewf, dinv, counts);
    k_rsqrt<<<dim3((NN + 255) / 256), B, 0, stream>>>(dinv);
    k_scan1<<<dim3(98), dim3(1024), 0, stream>>>(counts, rowoff, blk);
    k_scan2<<<dim3(1), dim3(64), 0, stream>>>(blk);
    k_scan3<<<dim3((NN + 255) / 256), B, 0, stream>>>(rowoff, blk);
    k_fill<<<dim3((NE + 255) / 256), B, 0, stream>>>(srcI, dstI, ewf, dinv, rowoff, cursor, srcs, normv);

    const float* W1f = Pc,         * b1f = Pc + 256;
    const float* W2f = Pc + 288,   * b2f = Pc + 4384;
    const float* W3f = Pc + 4512,  * b3f = Pc + 20896;
    const float* W4f = Pc + 21024, * b4f = Pc + 25120;

    k_gemm<8, 32, false, BT><<<dim3((50000 * 8 + 255) / 256), B, 0, stream>>>(xf, W1f, T);
    k_gather<32, true, BT, BH><<<dim3((NN * 8 + 255) / 256), B, 0, stream>>>(T, dinv, rowoff, counts, srcs, normv, b1f, H, x0x1);
    k_gemm<32, 128, BH, BT><<<dim3((50000 * 32 + 255) / 256), B, 0, stream>>>(H, W2f, T);
    k_gather<128, false, BT, BH><<<dim3((NN * 32 + 255) / 256), B, 0, stream>>>(T, dinv, rowoff, counts, srcs, normv, b2f, H, nullptr);
    k_gemm<128, 128, BH, BT><<<dim3((50000 * 32 + 255) / 256), B, 0, stream>>>(H, W3f, T);
    k_gather<128, false, BT, BH><<<dim3((NN * 32 + 255) / 256), B, 0, stream>>>(T, dinv, rowoff, counts, srcs, normv, b3f, H, nullptr);
    k_gemm<128, 32, BH, BT><<<dim3((50000 * 8 + 255) / 256), B, 0, stream>>>(H, W4f, T);
    k_gather<32, true, BT, BH><<<dim3((NN * 8 + 255) / 256), B, 0, stream>>>(T, dinv, rowoff, counts, srcs, normv, b4f, H, x0x1 + 32);

    k_mlp<<<dim3(1), dim3(128), 0, stream>>>(x0x1, Pc, out);
}

extern "C" void kernel_launch(void* const* d_in, const int* in_sizes, int n_in,
                              void* d_out, int out_size, void* d_ws, size_t ws_size,
                              hipStream_t stream) {
    const void* x    = d_in[0];
    const int*  ei   = (const int*)d_in[1];
    const void* ew   = d_in[2];
    const void* C2ER = d_in[4];
    float* out = (float*)d_out;
    (void)in_sizes; (void)n_in; (void)out_size;

    // pick storage mode by available workspace
    const size_t fixed = (size_t)NN * 8 * 4   // xf
                       + (size_t)NE * 4 * 3   // ewf, srcs, normv
                       + (size_t)NN * 4 * 4   // dinv, counts, rowoff, cursor
                       + 1024 + 256 * 4 + 51792 * 4 + 256;     // blk, x0x1, Pc, flag (+pad)
    const size_t szF = (size_t)NN * 128 * 4;  // fp32 feature buffer
    const size_t szB = (size_t)NN * 128 * 2;  // bf16 feature buffer
    int mode;
    if (ws_size >= fixed + 2 * szF + 4096) mode = 0;        // H fp32, T fp32 (~114 MB)
    else if (ws_size >= fixed + szF + szB + 4096) mode = 1; // H fp32, T bf16 (~89 MB)
    else mode = 2;                                          // H bf16, T bf16 (~63 MB)

    char* p = (char*)d_ws;
    void* H = (void*)p; p += (mode <= 1) ? szF : szB;
    void* T = (void*)p; p += (mode == 0) ? szF : szB;
    float* xf    = (float*)p;  p += (size_t)NN * 8 * 4;
    float* ewf   = (float*)p;  p += (size_t)NE * 4;
    int*   srcs  = (int*)p;    p += (size_t)NE * 4;
    float* normv = (float*)p;  p += (size_t)NE * 4;
    float* dinv  = (float*)p;  p += (size_t)NN * 4;
    int*   counts= (int*)p;    p += (size_t)NN * 4;
    int*   rowoff= (int*)p;    p += (size_t)NN * 4;
    int*   cursor= (int*)p;    p += (size_t)NN * 4;
    int*   blk   = (int*)p;    p += 1024;
    float* x0x1  = (float*)p;  p += 256 * 4;
    float* Pc    = (float*)p;  p += 51792 * 4;
    int*   flag  = (int*)p;    p += 64;

    if (mode == 0)
        run_pipeline<false, false>(x, ei, ew, C2ER, d_in, out, H, T, xf, ewf, srcs, normv,
                                   dinv, counts, rowoff, cursor, blk, x0x1, Pc, flag, stream);
    else if (mode == 1)
        run_pipeline<true, false>(x, ei, ew, C2ER, d_in, out, H, T, xf, ewf, srcs, normv,
                                  dinv, counts, rowoff, cursor, blk, x0x1, Pc, flag, stream);
    else
        run_pipeline<true, true>(x, ei, ew, C2ER, d_in, out, H, T, xf, ewf, srcs, normv,
                                 dinv, counts, rowoff, cursor, blk, x0x1, Pc, flag, stream);
}

// Round 4
// 560.958 us; speedup vs baseline: 1.1799x; 1.1799x over previous
//
#include <hip/hip_runtime.h>
#include <hip/hip_bf16.h>

#define NN 100000
#define NE 600000

using bf16 = __hip_bfloat16;
typedef unsigned short ushort_t;

__device__ __forceinline__ float b2f(bf16 v) { return __bfloat162float(v); }

__device__ __forceinline__ float bu2f(unsigned int u16) {
    union { float f; unsigned int i; } c; c.i = u16 << 16; return c.f;
}
__device__ __forceinline__ unsigned int f2bu(float f) {
    bf16 h = __float2bfloat16(f);
    return (unsigned int)*reinterpret_cast<unsigned short*>(&h);
}
__device__ __forceinline__ float4 ld4bf(uint2 u) {
    float4 r;
    r.x = bu2f(u.x & 0xffffu); r.y = bu2f(u.x >> 16);
    r.z = bu2f(u.y & 0xffffu); r.w = bu2f(u.y >> 16);
    return r;
}
__device__ __forceinline__ uint2 st4bf(float4 a) {
    uint2 u;
    u.x = f2bu(a.x) | (f2bu(a.y) << 16);
    u.y = f2bu(a.z) | (f2bu(a.w) << 16);
    return u;
}

template<bool BF16>
__device__ __forceinline__ float4 ld4(const void* base, size_t idx4) {
    if constexpr (BF16) return ld4bf(((const uint2*)base)[idx4]);
    else return ((const float4*)base)[idx4];
}
template<bool BF16>
__device__ __forceinline__ void st4(void* base, size_t idx4, float4 v) {
    if constexpr (BF16) ((uint2*)base)[idx4] = st4bf(v);
    else ((float4*)base)[idx4] = v;
}

// ---------- dtype probe: fp32 (flag=1) vs bf16 (flag=0) ----------
__global__ void k_probe(const void* x, int* flag) {
    __shared__ int bad;
    if (threadIdx.x == 0) bad = 0;
    __syncthreads();
    const unsigned short* u = (const unsigned short*)x;
    int mybad = 0;
    for (int i = threadIdx.x; i < 2048; i += 256) {
        unsigned short h = u[i];
        unsigned int e = (h >> 7) & 0xffu;
        bool zero = (h & 0x7fffu) == 0;
        bool plaus = zero || (e >= 96u && e <= 140u);
        if (!plaus) mybad++;
    }
    atomicAdd(&bad, mybad);
    __syncthreads();
    if (threadIdx.x == 0) *flag = (bad > 64) ? 1 : 0;
}

__global__ void k_cvt(const void* src, float* dst, int n, const int* flag) {
    int i = blockIdx.x * 256 + threadIdx.x;
    if (i >= n) return;
    if (*flag) dst[i] = ((const float*)src)[i];
    else       dst[i] = b2f(((const bf16*)src)[i]);
}

__global__ void k_cvt_params(const void* W1, const void* b1, const void* W2, const void* b2,
                             const void* W3, const void* b3, const void* W4, const void* b4,
                             const void* C2, const void* L1W, const void* L1b,
                             const void* L2W, const void* L2b, const void* L3W, const void* L3b,
                             float* dst, const int* flag) {
    int i = blockIdx.x * 256 + threadIdx.x;
    const void* p; int off;
    if      (i < 256)    { p = W1;  off = i; }
    else if (i < 288)    { p = b1;  off = i - 256; }
    else if (i < 4384)   { p = W2;  off = i - 288; }
    else if (i < 4512)   { p = b2;  off = i - 4384; }
    else if (i < 20896)  { p = W3;  off = i - 4512; }
    else if (i < 21024)  { p = b3;  off = i - 20896; }
    else if (i < 25120)  { p = W4;  off = i - 21024; }
    else if (i < 25152)  { p = b4;  off = i - 25120; }
    else if (i < 25156)  { p = C2;  off = i - 25152; }
    else if (i < 33860)  { p = L1W; off = i - 25156; }
    else if (i < 33988)  { p = L1b; off = i - 33860; }
    else if (i < 50372)  { p = L2W; off = i - 33988; }
    else if (i < 50500)  { p = L2b; off = i - 50372; }
    else if (i < 51780)  { p = L3W; off = i - 50500; }
    else if (i < 51790)  { p = L3b; off = i - 51780; }
    else return;
    if (*flag) dst[i] = ((const float*)p)[off];
    else       dst[i] = b2f(((const bf16*)p)[off]);
}

// ---------- prep ----------
__global__ void k_init(float* deg, int* counts, int* cursor, float* x0x1) {
    int i = blockIdx.x * 256 + threadIdx.x;
    if (i < NN) { deg[i] = 1.0f; counts[i] = 0; cursor[i] = 0; }
    if (i < 64) x0x1[i] = 0.0f;
}

__global__ void k_hist(const int* dstI, const float* ewf, float* deg, int* counts) {
    int e = blockIdx.x * 256 + threadIdx.x;
    if (e >= NE) return;
    int d = dstI[e];
    atomicAdd(&deg[d], ewf[e]);
    atomicAdd(&counts[d], 1);
}

__global__ void k_rsqrt(float* deg) {
    int i = blockIdx.x * 256 + threadIdx.x;
    if (i < NN) deg[i] = rsqrtf(deg[i]);
}

__global__ void k_scan1(const int* counts, int* row_off, int* blk) {
    __shared__ int sm[1024];
    int t = threadIdx.x;
    int i = blockIdx.x * 1024 + t;
    int v = (i < NN) ? counts[i] : 0;
    sm[t] = v;
    __syncthreads();
    for (int off = 1; off < 1024; off <<= 1) {
        int x = (t >= off) ? sm[t - off] : 0;
        __syncthreads();
        sm[t] += x;
        __syncthreads();
    }
    if (i < NN) row_off[i] = sm[t] - v;
    if (t == 1023) blk[blockIdx.x] = sm[t];
}

__global__ void k_scan2(int* blk) {
    if (threadIdx.x == 0 && blockIdx.x == 0) {
        int acc = 0;
        for (int i = 0; i < 98; i++) { int v = blk[i]; blk[i] = acc; acc += v; }
    }
}

__global__ void k_scan3(int* row_off, const int* blk) {
    int i = blockIdx.x * 256 + threadIdx.x;
    if (i < NN) row_off[i] += blk[i >> 10];
}

__global__ void k_fill(const int* srcI, const int* dstI, const float* ewf, const float* dinv,
                       const int* row_off, int* cursor, int* srcs, float* normv) {
    int e = blockIdx.x * 256 + threadIdx.x;
    if (e >= NE) return;
    int s = srcI[e], d = dstI[e];
    int pos = row_off[d] + atomicAdd(&cursor[d], 1);
    srcs[pos] = s;
    normv[pos] = dinv[s] * ewf[e] * dinv[d];
}

// ---------- dense: T = h_in @ W  (LDS-tiled, 4 nodes x 4 cols per thread) ----------
template<int CIN, int COUT> struct GemmCfg {
    static constexpr int CG  = COUT / 4;          // col-groups (float4)
    static constexpr int NG  = 256 / CG;          // node-groups per block
    static constexpr int NPT = (CIN * NG * 16 > 60000) ? 2 : 4;  // nodes per thread (LDS cap 64KB)
    static constexpr int TN  = NG * NPT;          // nodes per block
    static constexpr int STR = CIN + 4;           // LDS row stride (dwords, 16B aligned)
};

template<int CIN, int COUT, bool BIN, bool BOUT>
__global__ __launch_bounds__(256) void k_gemm(const void* __restrict__ hin,
                                              const float* __restrict__ Wf,
                                              void* __restrict__ hW) {
    using C = GemmCfg<CIN, COUT>;
    __shared__ float xs[C::TN * C::STR];
    const int base = blockIdx.x * C::TN;
    const int t = threadIdx.x;
    // stage input tile -> LDS (coalesced global float4 reads)
    constexpr int NF4 = C::TN * CIN / 4;
#pragma unroll
    for (int i = 0; i < NF4 / 256; i++) {
        int idx = t + 256 * i;
        int row = idx / (CIN / 4);
        int k4 = idx - row * (CIN / 4);
        int node = base + row;
        if (node >= NN) node = NN - 1;
        float4 v = ld4<BIN>(hin, (size_t)node * (CIN / 4) + k4);
        *(float4*)&xs[row * C::STR + 4 * k4] = v;
    }
    __syncthreads();
    const int cg = t % C::CG, ng = t / C::CG;
    float4 acc[C::NPT];
#pragma unroll
    for (int i = 0; i < C::NPT; i++) acc[i] = make_float4(0.f, 0.f, 0.f, 0.f);
    const float4* wr = (const float4*)Wf;
#pragma unroll 4
    for (int k4 = 0; k4 < CIN / 4; k4++) {
        float4 w[4];
#pragma unroll
        for (int j = 0; j < 4; j++) w[j] = wr[(4 * k4 + j) * C::CG + cg];
#pragma unroll
        for (int i = 0; i < C::NPT; i++) {
            float4 xv = *(const float4*)&xs[(ng * C::NPT + i) * C::STR + 4 * k4];
            acc[i].x = fmaf(xv.x, w[0].x, acc[i].x);
            acc[i].y = fmaf(xv.x, w[0].y, acc[i].y);
            acc[i].z = fmaf(xv.x, w[0].z, acc[i].z);
            acc[i].w = fmaf(xv.x, w[0].w, acc[i].w);
            acc[i].x = fmaf(xv.y, w[1].x, acc[i].x);
            acc[i].y = fmaf(xv.y, w[1].y, acc[i].y);
            acc[i].z = fmaf(xv.y, w[1].z, acc[i].z);
            acc[i].w = fmaf(xv.y, w[1].w, acc[i].w);
            acc[i].x = fmaf(xv.z, w[2].x, acc[i].x);
            acc[i].y = fmaf(xv.z, w[2].y, acc[i].y);
            acc[i].z = fmaf(xv.z, w[2].z, acc[i].z);
            acc[i].w = fmaf(xv.z, w[2].w, acc[i].w);
            acc[i].x = fmaf(xv.w, w[3].x, acc[i].x);
            acc[i].y = fmaf(xv.w, w[3].y, acc[i].y);
            acc[i].z = fmaf(xv.w, w[3].z, acc[i].z);
            acc[i].w = fmaf(xv.w, w[3].w, acc[i].w);
        }
    }
#pragma unroll
    for (int i = 0; i < C::NPT; i++) {
        int node = base + ng * C::NPT + i;
        if (node < NN) st4<BOUT>(hW, (size_t)node * C::CG + cg, acc[i]);
    }
}

// ---------- sparse aggregate + bias + relu (+ segment_max) ----------
template<int COUT, bool DOMAX, bool BT, bool BH>
__global__ void k_gather(const void* __restrict__ hW, const float* __restrict__ dinv,
                         const int* __restrict__ row_off, const int* __restrict__ counts,
                         const int* __restrict__ srcs, const float* __restrict__ normv,
                         const float* __restrict__ bias, void* __restrict__ hout,
                         float* xmax) {
    constexpr int CG = COUT / 4;
    __shared__ int smax[COUT];
    int tid = blockIdx.x * 256 + threadIdx.x;
    int n = tid / CG, cg = tid - n * CG;
    if (DOMAX) {
        if (threadIdx.x < COUT) smax[threadIdx.x] = 0;
        __syncthreads();
    }
    float4 acc = make_float4(0.f, 0.f, 0.f, 0.f);
    bool valid = (n < NN);
    if (valid) {
        float di = dinv[n];
        float d2 = di * di;
        float4 s4 = ld4<BT>(hW, (size_t)n * CG + cg);
        acc.x = s4.x * d2; acc.y = s4.y * d2; acc.z = s4.z * d2; acc.w = s4.w * d2;
        int start = row_off[n];
        int len = counts[n];
        for (int i = 0; i < len; i++) {
            int s = srcs[start + i];
            float w = normv[start + i];
            float4 v = ld4<BT>(hW, (size_t)s * CG + cg);
            acc.x = fmaf(w, v.x, acc.x); acc.y = fmaf(w, v.y, acc.y);
            acc.z = fmaf(w, v.z, acc.z); acc.w = fmaf(w, v.w, acc.w);
        }
        const float4* b4 = (const float4*)bias;
        float4 bb = b4[cg];
        acc.x = fmaxf(acc.x + bb.x, 0.f);
        acc.y = fmaxf(acc.y + bb.y, 0.f);
        acc.z = fmaxf(acc.z + bb.z, 0.f);
        acc.w = fmaxf(acc.w + bb.w, 0.f);
        st4<BH>(hout, (size_t)n * CG + cg, acc);
    }
    if (DOMAX) {
        if (valid) {   // relu output >= 0 so int-compare on float bits is monotone
            atomicMax(&smax[cg * 4 + 0], __float_as_int(acc.x));
            atomicMax(&smax[cg * 4 + 1], __float_as_int(acc.y));
            atomicMax(&smax[cg * 4 + 2], __float_as_int(acc.z));
            atomicMax(&smax[cg * 4 + 3], __float_as_int(acc.w));
        }
        __syncthreads();
        if (threadIdx.x < COUT) atomicMax((int*)&xmax[threadIdx.x], smax[threadIdx.x]);
    }
}

// ---------- head MLP + softmax + fp32 output ----------
__global__ void k_mlp(const float* x0x1, const float* Pc, float* out) {
    const float* C2  = Pc + 25152;
    const float* L1W = Pc + 25156;
    const float* L1b = Pc + 33860;
    const float* L2W = Pc + 33988;
    const float* L2b = Pc + 50372;
    const float* L3W = Pc + 50500;
    const float* L3b = Pc + 51780;
    __shared__ float code[68], z1[128], z2[128];
    int t = threadIdx.x;
    if (t < 64) code[t] = x0x1[t];
    else if (t < 68) code[t] = C2[t - 64];
    __syncthreads();
    float acc = L1b[t];
    for (int i = 0; i < 68; i++) acc = fmaf(code[i], L1W[i * 128 + t], acc);
    z1[t] = fmaxf(acc, 0.f);
    __syncthreads();
    acc = L2b[t];
    for (int i = 0; i < 128; i++) acc = fmaf(z1[i], L2W[i * 128 + t], acc);
    z2[t] = fmaxf(acc, 0.f);
    __syncthreads();
    if (t == 0) {
        float lg[10];
        for (int c = 0; c < 10; c++) {
            float a = L3b[c];
            for (int i = 0; i < 128; i++) a = fmaf(z2[i], L3W[i * 10 + c], a);
            lg[c] = a;
        }
        float m = lg[0];
        for (int c = 1; c < 10; c++) m = fmaxf(m, lg[c]);
        float s = 0.f;
        for (int c = 0; c < 10; c++) { lg[c] = __expf(lg[c] - m); s += lg[c]; }
        float inv = 1.f / s;
        for (int c = 0; c < 10; c++) out[c] = lg[c] * inv;
    }
    if (t < 68) out[10 + t] = code[t];
}

// ---------- full pipeline for a given (BT, BH) storage mode ----------
template<bool BT, bool BH>
static void run_pipeline(const void* x, const int* ei, const void* ew, const void* C2ER,
                         void* const* d_in, float* out,
                         void* H, void* T, float* xf, float* ewf, int* srcs, float* normv,
                         float* dinv, int* counts, int* rowoff, int* cursor, int* blk,
                         float* x0x1, float* Pc, int* flag, hipStream_t stream) {
    const int* srcI = ei;
    const int* dstI = ei + NE;
    dim3 B(256);
    k_probe<<<dim3(1), B, 0, stream>>>(x, flag);
    k_cvt<<<dim3((NN * 8 + 255) / 256), B, 0, stream>>>(x, xf, NN * 8, flag);
    k_cvt<<<dim3((NE + 255) / 256), B, 0, stream>>>(ew, ewf, NE, flag);
    k_cvt_params<<<dim3((51790 + 255) / 256), B, 0, stream>>>(
        d_in[5], d_in[6], d_in[7], d_in[8], d_in[9], d_in[10], d_in[11], d_in[12],
        C2ER, d_in[13], d_in[14], d_in[15], d_in[16], d_in[17], d_in[18], Pc, flag);

    k_init<<<dim3((NN + 255) / 256), B, 0, stream>>>(dinv, counts, cursor, x0x1);
    k_hist<<<dim3((NE + 255) / 256), B, 0, stream>>>(dstI, ewf, dinv, counts);
    k_rsqrt<<<dim3((NN + 255) / 256), B, 0, stream>>>(dinv);
    k_scan1<<<dim3(98), dim3(1024), 0, stream>>>(counts, rowoff, blk);
    k_scan2<<<dim3(1), dim3(64), 0, stream>>>(blk);
    k_scan3<<<dim3((NN + 255) / 256), B, 0, stream>>>(rowoff, blk);
    k_fill<<<dim3((NE + 255) / 256), B, 0, stream>>>(srcI, dstI, ewf, dinv, rowoff, cursor, srcs, normv);

    const float* W1f = Pc,         * b1f = Pc + 256;
    const float* W2f = Pc + 288,   * b2f = Pc + 4384;
    const float* W3f = Pc + 4512,  * b3f = Pc + 20896;
    const float* W4f = Pc + 21024, * b4f = Pc + 25120;

    constexpr int TN1 = GemmCfg<8, 32>::TN;
    constexpr int TN2 = GemmCfg<32, 128>::TN;
    constexpr int TN3 = GemmCfg<128, 128>::TN;
    constexpr int TN4 = GemmCfg<128, 32>::TN;

    k_gemm<8, 32, false, BT><<<dim3((NN + TN1 - 1) / TN1), B, 0, stream>>>(xf, W1f, T);
    k_gather<32, true, BT, BH><<<dim3((NN * 8 + 255) / 256), B, 0, stream>>>(T, dinv, rowoff, counts, srcs, normv, b1f, H, x0x1);
    k_gemm<32, 128, BH, BT><<<dim3((NN + TN2 - 1) / TN2), B, 0, stream>>>(H, W2f, T);
    k_gather<128, false, BT, BH><<<dim3((NN * 32 + 255) / 256), B, 0, stream>>>(T, dinv, rowoff, counts, srcs, normv, b2f, H, nullptr);
    k_gemm<128, 128, BH, BT><<<dim3((NN + TN3 - 1) / TN3), B, 0, stream>>>(H, W3f, T);
    k_gather<128, false, BT, BH><<<dim3((NN * 32 + 255) / 256), B, 0, stream>>>(T, dinv, rowoff, counts, srcs, normv, b3f, H, nullptr);
    k_gemm<128, 32, BH, BT><<<dim3((NN + TN4 - 1) / TN4), B, 0, stream>>>(H, W4f, T);
    k_gather<32, true, BT, BH><<<dim3((NN * 8 + 255) / 256), B, 0, stream>>>(T, dinv, rowoff, counts, srcs, normv, b4f, H, x0x1 + 32);

    k_mlp<<<dim3(1), dim3(128), 0, stream>>>(x0x1, Pc, out);
}

extern "C" void kernel_launch(void* const* d_in, const int* in_sizes, int n_in,
                              void* d_out, int out_size, void* d_ws, size_t ws_size,
                              hipStream_t stream) {
    const void* x    = d_in[0];
    const int*  ei   = (const int*)d_in[1];
    const void* ew   = d_in[2];
    const void* C2ER = d_in[4];
    float* out = (float*)d_out;
    (void)in_sizes; (void)n_in; (void)out_size;

    const size_t fixed = (size_t)NN * 8 * 4
                       + (size_t)NE * 4 * 3
                       + (size_t)NN * 4 * 4
                       + 1024 + 256 * 4 + 51792 * 4 + 256;
    const size_t szF = (size_t)NN * 128 * 4;
    const size_t szB = (size_t)NN * 128 * 2;
    int mode;
    if (ws_size >= fixed + 2 * szF + 4096) mode = 0;        // H fp32, T fp32
    else if (ws_size >= fixed + szF + szB + 4096) mode = 1; // H fp32, T bf16
    else mode = 2;                                          // H bf16, T bf16

    char* p = (char*)d_ws;
    void* H = (void*)p; p += (mode <= 1) ? szF : szB;
    void* T = (void*)p; p += (mode == 0) ? szF : szB;
    float* xf    = (float*)p;  p += (size_t)NN * 8 * 4;
    float* ewf   = (float*)p;  p += (size_t)NE * 4;
    int*   srcs  = (int*)p;    p += (size_t)NE * 4;
    float* normv = (float*)p;  p += (size_t)NE * 4;
    float* dinv  = (float*)p;  p += (size_t)NN * 4;
    int*   counts= (int*)p;    p += (size_t)NN * 4;
    int*   rowoff= (int*)p;    p += (size_t)NN * 4;
    int*   cursor= (int*)p;    p += (size_t)NN * 4;
    int*   blk   = (int*)p;    p += 1024;
    float* x0x1  = (float*)p;  p += 256 * 4;
    float* Pc    = (float*)p;  p += 51792 * 4;
    int*   flag  = (int*)p;    p += 64;

    if (mode == 0)
        run_pipeline<false, false>(x, ei, ew, C2ER, d_in, out, H, T, xf, ewf, srcs, normv,
                                   dinv, counts, rowoff, cursor, blk, x0x1, Pc, flag, stream);
    else if (mode == 1)
        run_pipeline<true, false>(x, ei, ew, C2ER, d_in, out, H, T, xf, ewf, srcs, normv,
                                  dinv, counts, rowoff, cursor, blk, x0x1, Pc, flag, stream);
    else
        run_pipeline<true, true>(x, ei, ew, C2ER, d_in, out, H, T, xf, ewf, srcs, normv,
                                 dinv, counts, rowoff, cursor, blk, x0x1, Pc, flag, stream);
}

// Round 5
// 463.180 us; speedup vs baseline: 1.4290x; 1.2111x over previous
//
#include <hip/hip_runtime.h>
#include <hip/hip_bf16.h>

#define NN 100000
#define NE 600000

using bf16 = __hip_bfloat16;
typedef unsigned short ushort_t;

__device__ __forceinline__ float b2f(bf16 v) { return __bfloat162float(v); }

__device__ __forceinline__ float bu2f(unsigned int u16) {
    union { float f; unsigned int i; } c; c.i = u16 << 16; return c.f;
}
__device__ __forceinline__ unsigned int f2bu(float f) {
    bf16 h = __float2bfloat16(f);
    return (unsigned int)*reinterpret_cast<unsigned short*>(&h);
}
__device__ __forceinline__ float4 ld4bf(uint2 u) {
    float4 r;
    r.x = bu2f(u.x & 0xffffu); r.y = bu2f(u.x >> 16);
    r.z = bu2f(u.y & 0xffffu); r.w = bu2f(u.y >> 16);
    return r;
}
__device__ __forceinline__ uint2 st4bf(float4 a) {
    uint2 u;
    u.x = f2bu(a.x) | (f2bu(a.y) << 16);
    u.y = f2bu(a.z) | (f2bu(a.w) << 16);
    return u;
}

template<bool BF16>
__device__ __forceinline__ float4 ld4(const void* base, size_t idx4) {
    if constexpr (BF16) return ld4bf(((const uint2*)base)[idx4]);
    else return ((const float4*)base)[idx4];
}
template<bool BF16>
__device__ __forceinline__ void st4(void* base, size_t idx4, float4 v) {
    if constexpr (BF16) ((uint2*)base)[idx4] = st4bf(v);
    else ((float4*)base)[idx4] = v;
}

// ---------- dtype probe: fp32 (flag=1) vs bf16 (flag=0) ----------
__global__ void k_probe(const void* x, int* flag) {
    __shared__ int bad;
    if (threadIdx.x == 0) bad = 0;
    __syncthreads();
    const unsigned short* u = (const unsigned short*)x;
    int mybad = 0;
    for (int i = threadIdx.x; i < 2048; i += 256) {
        unsigned short h = u[i];
        unsigned int e = (h >> 7) & 0xffu;
        bool zero = (h & 0x7fffu) == 0;
        bool plaus = zero || (e >= 96u && e <= 140u);
        if (!plaus) mybad++;
    }
    atomicAdd(&bad, mybad);
    __syncthreads();
    if (threadIdx.x == 0) *flag = (bad > 64) ? 1 : 0;
}

__global__ void k_cvt(const void* src, float* dst, int n, const int* flag) {
    int i = blockIdx.x * 256 + threadIdx.x;
    if (i >= n) return;
    if (*flag) dst[i] = ((const float*)src)[i];
    else       dst[i] = b2f(((const bf16*)src)[i]);
}

__global__ void k_cvt_params(const void* W1, const void* b1, const void* W2, const void* b2,
                             const void* W3, const void* b3, const void* W4, const void* b4,
                             const void* C2, const void* L1W, const void* L1b,
                             const void* L2W, const void* L2b, const void* L3W, const void* L3b,
                             float* dst, const int* flag) {
    int i = blockIdx.x * 256 + threadIdx.x;
    const void* p; int off;
    if      (i < 256)    { p = W1;  off = i; }
    else if (i < 288)    { p = b1;  off = i - 256; }
    else if (i < 4384)   { p = W2;  off = i - 288; }
    else if (i < 4512)   { p = b2;  off = i - 4384; }
    else if (i < 20896)  { p = W3;  off = i - 4512; }
    else if (i < 21024)  { p = b3;  off = i - 20896; }
    else if (i < 25120)  { p = W4;  off = i - 21024; }
    else if (i < 25152)  { p = b4;  off = i - 25120; }
    else if (i < 25156)  { p = C2;  off = i - 25152; }
    else if (i < 33860)  { p = L1W; off = i - 25156; }
    else if (i < 33988)  { p = L1b; off = i - 33860; }
    else if (i < 50372)  { p = L2W; off = i - 33988; }
    else if (i < 50500)  { p = L2b; off = i - 50372; }
    else if (i < 51780)  { p = L3W; off = i - 50500; }
    else if (i < 51790)  { p = L3b; off = i - 51780; }
    else return;
    if (*flag) dst[i] = ((const float*)p)[off];
    else       dst[i] = b2f(((const bf16*)p)[off]);
}

// ---------- prep ----------
__global__ void k_init(float* deg, int* counts, int* cursor, float* x0x1) {
    int i = blockIdx.x * 256 + threadIdx.x;
    if (i < NN) { deg[i] = 1.0f; counts[i] = 0; cursor[i] = 0; }
    if (i < 64) x0x1[i] = 0.0f;
}

__global__ void k_hist(const int* dstI, const float* ewf, float* deg, int* counts) {
    int e = blockIdx.x * 256 + threadIdx.x;
    if (e >= NE) return;
    int d = dstI[e];
    atomicAdd(&deg[d], ewf[e]);
    atomicAdd(&counts[d], 1);
}

__global__ void k_rsqrt(float* deg) {
    int i = blockIdx.x * 256 + threadIdx.x;
    if (i < NN) deg[i] = rsqrtf(deg[i]);
}

__global__ void k_scan1(const int* counts, int* row_off, int* blk) {
    __shared__ int sm[1024];
    int t = threadIdx.x;
    int i = blockIdx.x * 1024 + t;
    int v = (i < NN) ? counts[i] : 0;
    sm[t] = v;
    __syncthreads();
    for (int off = 1; off < 1024; off <<= 1) {
        int x = (t >= off) ? sm[t - off] : 0;
        __syncthreads();
        sm[t] += x;
        __syncthreads();
    }
    if (i < NN) row_off[i] = sm[t] - v;
    if (t == 1023) blk[blockIdx.x] = sm[t];
}

__global__ void k_scan2(int* blk) {
    if (threadIdx.x == 0 && blockIdx.x == 0) {
        int acc = 0;
        for (int i = 0; i < 98; i++) { int v = blk[i]; blk[i] = acc; acc += v; }
    }
}

__global__ void k_scan3(int* row_off, const int* blk) {
    int i = blockIdx.x * 256 + threadIdx.x;
    if (i < NN) row_off[i] += blk[i >> 10];
}

__global__ void k_fill(const int* srcI, const int* dstI, const float* ewf, const float* dinv,
                       const int* row_off, int* cursor, int* srcs, float* normv) {
    int e = blockIdx.x * 256 + threadIdx.x;
    if (e >= NE) return;
    int s = srcI[e], d = dstI[e];
    int pos = row_off[d] + atomicAdd(&cursor[d], 1);
    srcs[pos] = s;
    normv[pos] = dinv[s] * ewf[e] * dinv[d];
}

// ---------- dense: out = in @ W (+bias+relu (+max))  LDS-tiled ----------
template<int CIN, int COUT> struct GemmCfg {
    static constexpr int CG  = COUT / 4;          // col-groups (float4)
    static constexpr int NG  = 256 / CG;          // node-groups per block
    static constexpr int STR = CIN + 4;           // LDS row stride (dwords)
    static constexpr int NPT = (NG * 8 * STR * 4 <= 36864) ? 8
                             : ((NG * 4 * STR * 4 <= 36864) ? 4 : 2);
    static constexpr int TN  = NG * NPT;          // nodes per block
};

// EPI: 0 = plain store, 1 = bias+relu, 2 = bias+relu+colmax
template<int CIN, int COUT, bool BIN, bool BOUT, int EPI>
__global__ __launch_bounds__(256) void k_gemm(const void* __restrict__ hin,
                                              const float* __restrict__ Wf,
                                              void* __restrict__ hW,
                                              const float* __restrict__ bias,
                                              float* xmax) {
    using C = GemmCfg<CIN, COUT>;
    __shared__ float xs[C::TN * C::STR];
    __shared__ int smax[(EPI == 2) ? COUT : 1];
    const int base = blockIdx.x * C::TN;
    const int t = threadIdx.x;
    constexpr int NF4 = C::TN * CIN / 4;
#pragma unroll
    for (int i = 0; i < NF4 / 256; i++) {
        int idx = t + 256 * i;
        int row = idx / (CIN / 4);
        int k4 = idx - row * (CIN / 4);
        int node = base + row;
        if (node >= NN) node = NN - 1;
        float4 v = ld4<BIN>(hin, (size_t)node * (CIN / 4) + k4);
        *(float4*)&xs[row * C::STR + 4 * k4] = v;
    }
    if (EPI == 2 && t < COUT) smax[t] = 0;
    __syncthreads();
    const int cg = t % C::CG, ng = t / C::CG;
    float4 acc[C::NPT];
#pragma unroll
    for (int i = 0; i < C::NPT; i++) acc[i] = make_float4(0.f, 0.f, 0.f, 0.f);
    const float4* wr = (const float4*)Wf;
#pragma unroll 2
    for (int k4 = 0; k4 < CIN / 4; k4++) {
        float4 w[4];
#pragma unroll
        for (int j = 0; j < 4; j++) w[j] = wr[(4 * k4 + j) * C::CG + cg];
#pragma unroll
        for (int i = 0; i < C::NPT; i++) {
            float4 xv = *(const float4*)&xs[(ng * C::NPT + i) * C::STR + 4 * k4];
            acc[i].x = fmaf(xv.x, w[0].x, acc[i].x);
            acc[i].y = fmaf(xv.x, w[0].y, acc[i].y);
            acc[i].z = fmaf(xv.x, w[0].z, acc[i].z);
            acc[i].w = fmaf(xv.x, w[0].w, acc[i].w);
            acc[i].x = fmaf(xv.y, w[1].x, acc[i].x);
            acc[i].y = fmaf(xv.y, w[1].y, acc[i].y);
            acc[i].z = fmaf(xv.y, w[1].z, acc[i].z);
            acc[i].w = fmaf(xv.y, w[1].w, acc[i].w);
            acc[i].x = fmaf(xv.z, w[2].x, acc[i].x);
            acc[i].y = fmaf(xv.z, w[2].y, acc[i].y);
            acc[i].z = fmaf(xv.z, w[2].z, acc[i].z);
            acc[i].w = fmaf(xv.z, w[2].w, acc[i].w);
            acc[i].x = fmaf(xv.w, w[3].x, acc[i].x);
            acc[i].y = fmaf(xv.w, w[3].y, acc[i].y);
            acc[i].z = fmaf(xv.w, w[3].z, acc[i].z);
            acc[i].w = fmaf(xv.w, w[3].w, acc[i].w);
        }
    }
    float4 bb;
    if (EPI >= 1) bb = ((const float4*)bias)[cg];
    float4 mx = make_float4(0.f, 0.f, 0.f, 0.f);
#pragma unroll
    for (int i = 0; i < C::NPT; i++) {
        int node = base + ng * C::NPT + i;
        if (EPI >= 1) {
            acc[i].x = fmaxf(acc[i].x + bb.x, 0.f);
            acc[i].y = fmaxf(acc[i].y + bb.y, 0.f);
            acc[i].z = fmaxf(acc[i].z + bb.z, 0.f);
            acc[i].w = fmaxf(acc[i].w + bb.w, 0.f);
        }
        if (EPI == 2) {
            mx.x = fmaxf(mx.x, acc[i].x); mx.y = fmaxf(mx.y, acc[i].y);
            mx.z = fmaxf(mx.z, acc[i].z); mx.w = fmaxf(mx.w, acc[i].w);
        }
        if (node < NN) st4<BOUT>(hW, (size_t)node * C::CG + cg, acc[i]);
    }
    if (EPI == 2) {
        // relu outputs >= 0 so int-compare on float bits is monotone
        atomicMax(&smax[cg * 4 + 0], __float_as_int(mx.x));
        atomicMax(&smax[cg * 4 + 1], __float_as_int(mx.y));
        atomicMax(&smax[cg * 4 + 2], __float_as_int(mx.z));
        atomicMax(&smax[cg * 4 + 3], __float_as_int(mx.w));
        __syncthreads();
        if (t < COUT) atomicMax((int*)&xmax[t], smax[t]);
    }
}

// ---------- aggregate-first: out[n] = sum norm*in[src] + dinv^2 * in[n]  (fp32 out) ----------
template<int C, bool BIN>
__global__ void k_agg(const void* __restrict__ hin, const float* __restrict__ dinv,
                      const int* __restrict__ row_off, const int* __restrict__ counts,
                      const int* __restrict__ srcs, const float* __restrict__ normv,
                      float* __restrict__ out) {
    constexpr int CG = C / 4;
    int tid = blockIdx.x * 256 + threadIdx.x;
    int n = tid / CG, cg = tid - n * CG;
    if (n >= NN) return;
    float di = dinv[n];
    float d2 = di * di;
    float4 s4 = ld4<BIN>(hin, (size_t)n * CG + cg);
    float4 acc = make_float4(s4.x * d2, s4.y * d2, s4.z * d2, s4.w * d2);
    int start = row_off[n];
    int len = counts[n];
    int i = 0;
    for (; i + 2 <= len; i += 2) {
        int s0 = srcs[start + i], s1 = srcs[start + i + 1];
        float w0 = normv[start + i], w1 = normv[start + i + 1];
        float4 v0 = ld4<BIN>(hin, (size_t)s0 * CG + cg);
        float4 v1 = ld4<BIN>(hin, (size_t)s1 * CG + cg);
        acc.x = fmaf(w0, v0.x, acc.x); acc.y = fmaf(w0, v0.y, acc.y);
        acc.z = fmaf(w0, v0.z, acc.z); acc.w = fmaf(w0, v0.w, acc.w);
        acc.x = fmaf(w1, v1.x, acc.x); acc.y = fmaf(w1, v1.y, acc.y);
        acc.z = fmaf(w1, v1.z, acc.z); acc.w = fmaf(w1, v1.w, acc.w);
    }
    if (i < len) {
        int s0 = srcs[start + i];
        float w0 = normv[start + i];
        float4 v0 = ld4<BIN>(hin, (size_t)s0 * CG + cg);
        acc.x = fmaf(w0, v0.x, acc.x); acc.y = fmaf(w0, v0.y, acc.y);
        acc.z = fmaf(w0, v0.z, acc.z); acc.w = fmaf(w0, v0.w, acc.w);
    }
    ((float4*)out)[(size_t)n * CG + cg] = acc;
}

// ---------- aggregate-after (GEMM output) + bias + relu (+ segment_max) ----------
template<int COUT, bool DOMAX, bool BT, bool BH>
__global__ void k_gather(const void* __restrict__ hW, const float* __restrict__ dinv,
                         const int* __restrict__ row_off, const int* __restrict__ counts,
                         const int* __restrict__ srcs, const float* __restrict__ normv,
                         const float* __restrict__ bias, void* __restrict__ hout,
                         float* xmax) {
    constexpr int CG = COUT / 4;
    __shared__ int smax[COUT];
    int tid = blockIdx.x * 256 + threadIdx.x;
    int n = tid / CG, cg = tid - n * CG;
    if (DOMAX) {
        if (threadIdx.x < COUT) smax[threadIdx.x] = 0;
        __syncthreads();
    }
    float4 acc = make_float4(0.f, 0.f, 0.f, 0.f);
    bool valid = (n < NN);
    if (valid) {
        float di = dinv[n];
        float d2 = di * di;
        float4 s4 = ld4<BT>(hW, (size_t)n * CG + cg);
        acc.x = s4.x * d2; acc.y = s4.y * d2; acc.z = s4.z * d2; acc.w = s4.w * d2;
        int start = row_off[n];
        int len = counts[n];
        int i = 0;
        for (; i + 2 <= len; i += 2) {
            int s0 = srcs[start + i], s1 = srcs[start + i + 1];
            float w0 = normv[start + i], w1 = normv[start + i + 1];
            float4 v0 = ld4<BT>(hW, (size_t)s0 * CG + cg);
            float4 v1 = ld4<BT>(hW, (size_t)s1 * CG + cg);
            acc.x = fmaf(w0, v0.x, acc.x); acc.y = fmaf(w0, v0.y, acc.y);
            acc.z = fmaf(w0, v0.z, acc.z); acc.w = fmaf(w0, v0.w, acc.w);
            acc.x = fmaf(w1, v1.x, acc.x); acc.y = fmaf(w1, v1.y, acc.y);
            acc.z = fmaf(w1, v1.z, acc.z); acc.w = fmaf(w1, v1.w, acc.w);
        }
        if (i < len) {
            int s0 = srcs[start + i];
            float w0 = normv[start + i];
            float4 v0 = ld4<BT>(hW, (size_t)s0 * CG + cg);
            acc.x = fmaf(w0, v0.x, acc.x); acc.y = fmaf(w0, v0.y, acc.y);
            acc.z = fmaf(w0, v0.z, acc.z); acc.w = fmaf(w0, v0.w, acc.w);
        }
        const float4* b4 = (const float4*)bias;
        float4 bb = b4[cg];
        acc.x = fmaxf(acc.x + bb.x, 0.f);
        acc.y = fmaxf(acc.y + bb.y, 0.f);
        acc.z = fmaxf(acc.z + bb.z, 0.f);
        acc.w = fmaxf(acc.w + bb.w, 0.f);
        st4<BH>(hout, (size_t)n * CG + cg, acc);
    }
    if (DOMAX) {
        if (valid) {
            atomicMax(&smax[cg * 4 + 0], __float_as_int(acc.x));
            atomicMax(&smax[cg * 4 + 1], __float_as_int(acc.y));
            atomicMax(&smax[cg * 4 + 2], __float_as_int(acc.z));
            atomicMax(&smax[cg * 4 + 3], __float_as_int(acc.w));
        }
        __syncthreads();
        if (threadIdx.x < COUT) atomicMax((int*)&xmax[threadIdx.x], smax[threadIdx.x]);
    }
}

// ---------- head MLP + softmax + fp32 output ----------
__global__ void k_mlp(const float* x0x1, const float* Pc, float* out) {
    const float* C2  = Pc + 25152;
    const float* L1W = Pc + 25156;
    const float* L1b = Pc + 33860;
    const float* L2W = Pc + 33988;
    const float* L2b = Pc + 50372;
    const float* L3W = Pc + 50500;
    const float* L3b = Pc + 51780;
    __shared__ float code[68], z1[128], z2[128];
    int t = threadIdx.x;
    if (t < 64) code[t] = x0x1[t];
    else if (t < 68) code[t] = C2[t - 64];
    __syncthreads();
    float acc = L1b[t];
    for (int i = 0; i < 68; i++) acc = fmaf(code[i], L1W[i * 128 + t], acc);
    z1[t] = fmaxf(acc, 0.f);
    __syncthreads();
    acc = L2b[t];
    for (int i = 0; i < 128; i++) acc = fmaf(z1[i], L2W[i * 128 + t], acc);
    z2[t] = fmaxf(acc, 0.f);
    __syncthreads();
    if (t == 0) {
        float lg[10];
        for (int c = 0; c < 10; c++) {
            float a = L3b[c];
            for (int i = 0; i < 128; i++) a = fmaf(z2[i], L3W[i * 10 + c], a);
            lg[c] = a;
        }
        float m = lg[0];
        for (int c = 1; c < 10; c++) m = fmaxf(m, lg[c]);
        float s = 0.f;
        for (int c = 0; c < 10; c++) { lg[c] = __expf(lg[c] - m); s += lg[c]; }
        float inv = 1.f / s;
        for (int c = 0; c < 10; c++) out[c] = lg[c] * inv;
    }
    if (t < 68) out[10 + t] = code[t];
}

// ---------- full pipeline ----------
template<bool BT, bool BH>
static void run_pipeline(const void* x, const int* ei, const void* ew, const void* C2ER,
                         void* const* d_in, float* out,
                         void* H, void* T, float* xf, float* ewf, int* srcs, float* normv,
                         float* dinv, int* counts, int* rowoff, int* cursor, int* blk,
                         float* x0x1, float* Pc, int* flag, hipStream_t stream) {
    const int* srcI = ei;
    const int* dstI = ei + NE;
    dim3 B(256);
    k_probe<<<dim3(1), B, 0, stream>>>(x, flag);
    k_cvt<<<dim3((NN * 8 + 255) / 256), B, 0, stream>>>(x, xf, NN * 8, flag);
    k_cvt<<<dim3((NE + 255) / 256), B, 0, stream>>>(ew, ewf, NE, flag);
    k_cvt_params<<<dim3((51790 + 255) / 256), B, 0, stream>>>(
        d_in[5], d_in[6], d_in[7], d_in[8], d_in[9], d_in[10], d_in[11], d_in[12],
        C2ER, d_in[13], d_in[14], d_in[15], d_in[16], d_in[17], d_in[18], Pc, flag);

    k_init<<<dim3((NN + 255) / 256), B, 0, stream>>>(dinv, counts, cursor, x0x1);
    k_hist<<<dim3((NE + 255) / 256), B, 0, stream>>>(dstI, ewf, dinv, counts);
    k_rsqrt<<<dim3((NN + 255) / 256), B, 0, stream>>>(dinv);
    k_scan1<<<dim3(98), dim3(1024), 0, stream>>>(counts, rowoff, blk);
    k_scan2<<<dim3(1), dim3(64), 0, stream>>>(blk);
    k_scan3<<<dim3((NN + 255) / 256), B, 0, stream>>>(rowoff, blk);
    k_fill<<<dim3((NE + 255) / 256), B, 0, stream>>>(srcI, dstI, ewf, dinv, rowoff, cursor, srcs, normv);

    const float* W1f = Pc,         * b1f = Pc + 256;
    const float* W2f = Pc + 288,   * b2f = Pc + 4384;
    const float* W3f = Pc + 4512,  * b3f = Pc + 20896;
    const float* W4f = Pc + 21024, * b4f = Pc + 25120;

    constexpr int TN1 = GemmCfg<8, 32>::TN;
    constexpr int TN2 = GemmCfg<32, 128>::TN;
    constexpr int TN3 = GemmCfg<128, 128>::TN;
    constexpr int TN4 = GemmCfg<128, 32>::TN;

    // L1: aggregate xf at width 8, then GEMM 8->32 (+bias+relu+max)
    k_agg<8, false><<<dim3((NN * 2 + 255) / 256), B, 0, stream>>>(xf, dinv, rowoff, counts, srcs, normv, (float*)T);
    k_gemm<8, 32, false, BH, 2><<<dim3((NN + TN1 - 1) / TN1), B, 0, stream>>>(T, W1f, H, b1f, x0x1);
    // L2: aggregate H at width 32, then GEMM 32->128 (+bias+relu)
    k_agg<32, BH><<<dim3((NN * 8 + 255) / 256), B, 0, stream>>>(H, dinv, rowoff, counts, srcs, normv, (float*)T);
    k_gemm<32, 128, false, BH, 1><<<dim3((NN + TN2 - 1) / TN2), B, 0, stream>>>(T, W2f, H, b2f, nullptr);
    // L3: GEMM 128->128, then aggregate at 128 (+bias+relu)
    k_gemm<128, 128, BH, BT, 0><<<dim3((NN + TN3 - 1) / TN3), B, 0, stream>>>(H, W3f, T, nullptr, nullptr);
    k_gather<128, false, BT, BH><<<dim3((NN * 32 + 255) / 256), B, 0, stream>>>(T, dinv, rowoff, counts, srcs, normv, b3f, H, nullptr);
    // L4: GEMM 128->32, then aggregate at 32 (+bias+relu+max)
    k_gemm<128, 32, BH, false, 0><<<dim3((NN + TN4 - 1) / TN4), B, 0, stream>>>(H, W4f, T, nullptr, nullptr);
    k_gather<32, true, false, BH><<<dim3((NN * 8 + 255) / 256), B, 0, stream>>>(T, dinv, rowoff, counts, srcs, normv, b4f, H, x0x1 + 32);

    k_mlp<<<dim3(1), dim3(128), 0, stream>>>(x0x1, Pc, out);
}

extern "C" void kernel_launch(void* const* d_in, const int* in_sizes, int n_in,
                              void* d_out, int out_size, void* d_ws, size_t ws_size,
                              hipStream_t stream) {
    const void* x    = d_in[0];
    const int*  ei   = (const int*)d_in[1];
    const void* ew   = d_in[2];
    const void* C2ER = d_in[4];
    float* out = (float*)d_out;
    (void)in_sizes; (void)n_in; (void)out_size;

    const size_t fixed = (size_t)NN * 8 * 4
                       + (size_t)NE * 4 * 3
                       + (size_t)NN * 4 * 4
                       + 1024 + 256 * 4 + 51792 * 4 + 256;
    const size_t szF = (size_t)NN * 128 * 4;
    const size_t szB = (size_t)NN * 128 * 2;
    int mode;
    if (ws_size >= fixed + 2 * szF + 4096) mode = 0;        // H fp32, T fp32
    else if (ws_size >= fixed + szF + szB + 4096) mode = 1; // H fp32, T bf16
    else mode = 2;                                          // H bf16, T bf16

    char* p = (char*)d_ws;
    void* H = (void*)p; p += (mode <= 1) ? szF : szB;
    void* T = (void*)p; p += (mode == 0) ? szF : szB;
    float* xf    = (float*)p;  p += (size_t)NN * 8 * 4;
    float* ewf   = (float*)p;  p += (size_t)NE * 4;
    int*   srcs  = (int*)p;    p += (size_t)NE * 4;
    float* normv = (float*)p;  p += (size_t)NE * 4;
    float* dinv  = (float*)p;  p += (size_t)NN * 4;
    int*   counts= (int*)p;    p += (size_t)NN * 4;
    int*   rowoff= (int*)p;    p += (size_t)NN * 4;
    int*   cursor= (int*)p;    p += (size_t)NN * 4;
    int*   blk   = (int*)p;    p += 1024;
    float* x0x1  = (float*)p;  p += 256 * 4;
    float* Pc    = (float*)p;  p += 51792 * 4;
    int*   flag  = (int*)p;    p += 64;

    if (mode == 0)
        run_pipeline<false, false>(x, ei, ew, C2ER, d_in, out, H, T, xf, ewf, srcs, normv,
                                   dinv, counts, rowoff, cursor, blk, x0x1, Pc, flag, stream);
    else if (mode == 1)
        run_pipeline<true, false>(x, ei, ew, C2ER, d_in, out, H, T, xf, ewf, srcs, normv,
                                  dinv, counts, rowoff, cursor, blk, x0x1, Pc, flag, stream);
    else
        run_pipeline<true, true>(x, ei, ew, C2ER, d_in, out, H, T, xf, ewf, srcs, normv,
                                 dinv, counts, rowoff, cursor, blk, x0x1, Pc, flag, stream);
}

// Round 6
// 448.057 us; speedup vs baseline: 1.4772x; 1.0338x over previous
//
#include <hip/hip_runtime.h>
#include <hip/hip_bf16.h>

#define NN 100000
#define NE 600000

using bf16 = __hip_bfloat16;
typedef unsigned short ushort_t;
typedef float f32x4 __attribute__((ext_vector_type(4)));

__device__ __forceinline__ float b2f(bf16 v) { return __bfloat162float(v); }

__device__ __forceinline__ float bu2f(unsigned int u16) {
    union { float f; unsigned int i; } c; c.i = u16 << 16; return c.f;
}
__device__ __forceinline__ unsigned int f2bu(float f) {
    bf16 h = __float2bfloat16(f);
    return (unsigned int)*reinterpret_cast<unsigned short*>(&h);
}
__device__ __forceinline__ float4 ld4bf(uint2 u) {
    float4 r;
    r.x = bu2f(u.x & 0xffffu); r.y = bu2f(u.x >> 16);
    r.z = bu2f(u.y & 0xffffu); r.w = bu2f(u.y >> 16);
    return r;
}
__device__ __forceinline__ uint2 st4bf(float4 a) {
    uint2 u;
    u.x = f2bu(a.x) | (f2bu(a.y) << 16);
    u.y = f2bu(a.z) | (f2bu(a.w) << 16);
    return u;
}

template<bool BF16>
__device__ __forceinline__ float4 ld4(const void* base, size_t idx4) {
    if constexpr (BF16) return ld4bf(((const uint2*)base)[idx4]);
    else return ((const float4*)base)[idx4];
}
template<bool BF16>
__device__ __forceinline__ void st4(void* base, size_t idx4, float4 v) {
    if constexpr (BF16) ((uint2*)base)[idx4] = st4bf(v);
    else ((float4*)base)[idx4] = v;
}
__device__ __forceinline__ void st4_nt(float* p, float4 v) {
    f32x4 t = {v.x, v.y, v.z, v.w};
    __builtin_nontemporal_store(t, (f32x4*)p);
}

// ---------- dtype probe: fp32 (flag=1) vs bf16 (flag=0) ----------
__global__ void k_probe(const void* x, int* flag) {
    __shared__ int bad;
    if (threadIdx.x == 0) bad = 0;
    __syncthreads();
    const unsigned short* u = (const unsigned short*)x;
    int mybad = 0;
    for (int i = threadIdx.x; i < 2048; i += 256) {
        unsigned short h = u[i];
        unsigned int e = (h >> 7) & 0xffu;
        bool zero = (h & 0x7fffu) == 0;
        bool plaus = zero || (e >= 96u && e <= 140u);
        if (!plaus) mybad++;
    }
    atomicAdd(&bad, mybad);
    __syncthreads();
    if (threadIdx.x == 0) *flag = (bad > 64) ? 1 : 0;
}

__global__ void k_cvt(const void* src, float* dst, int n, const int* flag) {
    int i = blockIdx.x * 256 + threadIdx.x;
    if (i >= n) return;
    if (*flag) dst[i] = ((const float*)src)[i];
    else       dst[i] = b2f(((const bf16*)src)[i]);
}

__global__ void k_cvt_params(const void* W1, const void* b1, const void* W2, const void* b2,
                             const void* W3, const void* b3, const void* W4, const void* b4,
                             const void* C2, const void* L1W, const void* L1b,
                             const void* L2W, const void* L2b, const void* L3W, const void* L3b,
                             float* dst, const int* flag) {
    int i = blockIdx.x * 256 + threadIdx.x;
    const void* p; int off;
    if      (i < 256)    { p = W1;  off = i; }
    else if (i < 288)    { p = b1;  off = i - 256; }
    else if (i < 4384)   { p = W2;  off = i - 288; }
    else if (i < 4512)   { p = b2;  off = i - 4384; }
    else if (i < 20896)  { p = W3;  off = i - 4512; }
    else if (i < 21024)  { p = b3;  off = i - 20896; }
    else if (i < 25120)  { p = W4;  off = i - 21024; }
    else if (i < 25152)  { p = b4;  off = i - 25120; }
    else if (i < 25156)  { p = C2;  off = i - 25152; }
    else if (i < 33860)  { p = L1W; off = i - 25156; }
    else if (i < 33988)  { p = L1b; off = i - 33860; }
    else if (i < 50372)  { p = L2W; off = i - 33988; }
    else if (i < 50500)  { p = L2b; off = i - 50372; }
    else if (i < 51780)  { p = L3W; off = i - 50500; }
    else if (i < 51790)  { p = L3b; off = i - 51780; }
    else return;
    if (*flag) dst[i] = ((const float*)p)[off];
    else       dst[i] = b2f(((const bf16*)p)[off]);
}

// ---------- prep ----------
__global__ void k_init(int* counts, int* cursor, float* x0x1) {
    int i = blockIdx.x * 256 + threadIdx.x;
    if (i < NN) { counts[i] = 0; cursor[i] = 0; }
    if (i < 64) x0x1[i] = 0.0f;
}

__global__ void k_count(const int* dstI, int* counts) {
    int e = blockIdx.x * 256 + threadIdx.x;
    if (e >= NE) return;
    atomicAdd(&counts[dstI[e]], 1);
}

__global__ void k_scan1(const int* counts, int* row_off, int* blk) {
    __shared__ int sm[1024];
    int t = threadIdx.x;
    int i = blockIdx.x * 1024 + t;
    int v = (i < NN) ? counts[i] : 0;
    sm[t] = v;
    __syncthreads();
    for (int off = 1; off < 1024; off <<= 1) {
        int x = (t >= off) ? sm[t - off] : 0;
        __syncthreads();
        sm[t] += x;
        __syncthreads();
    }
    if (i < NN) row_off[i] = sm[t] - v;
    if (t == 1023) blk[blockIdx.x] = sm[t];
}

__global__ void k_scan2(int* blk) {
    if (threadIdx.x == 0 && blockIdx.x == 0) {
        int acc = 0;
        for (int i = 0; i < 98; i++) { int v = blk[i]; blk[i] = acc; acc += v; }
    }
}

__global__ void k_scan3(int* row_off, const int* blk) {
    int i = blockIdx.x * 256 + threadIdx.x;
    if (i < NN) row_off[i] += blk[i >> 10];
}

// CSR fill: srcs + raw edge weight into normv
__global__ void k_fill(const int* srcI, const int* dstI, const float* ewf,
                       const int* row_off, int* cursor, int* srcs, float* normv) {
    int e = blockIdx.x * 256 + threadIdx.x;
    if (e >= NE) return;
    int d = dstI[e];
    int pos = row_off[d] + atomicAdd(&cursor[d], 1);
    srcs[pos] = srcI[e];
    normv[pos] = ewf[e];
}

// per-node: deg = 1 + sum(ew) -> dinv
__global__ void k_deg(const int* row_off, const int* counts, const float* normv, float* dinv) {
    int n = blockIdx.x * 256 + threadIdx.x;
    if (n >= NN) return;
    int st = row_off[n], len = counts[n];
    float s = 1.0f;
    for (int i = 0; i < len; i++) s += normv[st + i];
    dinv[n] = rsqrtf(s);
}

// per-node: normv *= dinv[src]*dinv[n]
__global__ void k_norm(const int* row_off, const int* counts, const int* srcs,
                       const float* dinv, float* normv) {
    int n = blockIdx.x * 256 + threadIdx.x;
    if (n >= NN) return;
    float dn = dinv[n];
    int st = row_off[n], len = counts[n];
    for (int i = 0; i < len; i++) normv[st + i] *= dinv[srcs[st + i]] * dn;
}

// ---------- dense: out = in @ W (+bias+relu (+max))  LDS-tiled ----------
template<int CIN, int COUT> struct GemmCfg {
    static constexpr int CG  = COUT / 4;
    static constexpr int NG  = 256 / CG;
    static constexpr int STR = CIN + 4;
    static constexpr int NPT = (NG * 8 * STR * 4 <= 36864) ? 8
                             : ((NG * 4 * STR * 4 <= 36864) ? 4 : 2);
    static constexpr int TN  = NG * NPT;
};

// EPI: 0 = plain store, 1 = bias+relu, 2 = bias+relu+colmax
template<int CIN, int COUT, bool BIN, bool BOUT, int EPI>
__global__ __launch_bounds__(256) void k_gemm(const void* __restrict__ hin,
                                              const float* __restrict__ Wf,
                                              void* __restrict__ hW,
                                              const float* __restrict__ bias,
                                              float* xmax) {
    using C = GemmCfg<CIN, COUT>;
    __shared__ float xs[C::TN * C::STR];
    __shared__ int smax[(EPI == 2) ? COUT : 1];
    const int base = blockIdx.x * C::TN;
    const int t = threadIdx.x;
    constexpr int NF4 = C::TN * CIN / 4;
#pragma unroll
    for (int i = 0; i < NF4 / 256; i++) {
        int idx = t + 256 * i;
        int row = idx / (CIN / 4);
        int k4 = idx - row * (CIN / 4);
        int node = base + row;
        if (node >= NN) node = NN - 1;
        float4 v = ld4<BIN>(hin, (size_t)node * (CIN / 4) + k4);
        *(float4*)&xs[row * C::STR + 4 * k4] = v;
    }
    if (EPI == 2 && t < COUT) smax[t] = 0;
    __syncthreads();
    const int cg = t % C::CG, ng = t / C::CG;
    float4 acc[C::NPT];
#pragma unroll
    for (int i = 0; i < C::NPT; i++) acc[i] = make_float4(0.f, 0.f, 0.f, 0.f);
    const float4* wr = (const float4*)Wf;
#pragma unroll 2
    for (int k4 = 0; k4 < CIN / 4; k4++) {
        float4 w[4];
#pragma unroll
        for (int j = 0; j < 4; j++) w[j] = wr[(4 * k4 + j) * C::CG + cg];
#pragma unroll
        for (int i = 0; i < C::NPT; i++) {
            float4 xv = *(const float4*)&xs[(ng * C::NPT + i) * C::STR + 4 * k4];
            acc[i].x = fmaf(xv.x, w[0].x, acc[i].x);
            acc[i].y = fmaf(xv.x, w[0].y, acc[i].y);
            acc[i].z = fmaf(xv.x, w[0].z, acc[i].z);
            acc[i].w = fmaf(xv.x, w[0].w, acc[i].w);
            acc[i].x = fmaf(xv.y, w[1].x, acc[i].x);
            acc[i].y = fmaf(xv.y, w[1].y, acc[i].y);
            acc[i].z = fmaf(xv.y, w[1].z, acc[i].z);
            acc[i].w = fmaf(xv.y, w[1].w, acc[i].w);
            acc[i].x = fmaf(xv.z, w[2].x, acc[i].x);
            acc[i].y = fmaf(xv.z, w[2].y, acc[i].y);
            acc[i].z = fmaf(xv.z, w[2].z, acc[i].z);
            acc[i].w = fmaf(xv.z, w[2].w, acc[i].w);
            acc[i].x = fmaf(xv.w, w[3].x, acc[i].x);
            acc[i].y = fmaf(xv.w, w[3].y, acc[i].y);
            acc[i].z = fmaf(xv.w, w[3].z, acc[i].z);
            acc[i].w = fmaf(xv.w, w[3].w, acc[i].w);
        }
    }
    float4 bb;
    if (EPI >= 1) bb = ((const float4*)bias)[cg];
    float4 mx = make_float4(0.f, 0.f, 0.f, 0.f);
#pragma unroll
    for (int i = 0; i < C::NPT; i++) {
        int node = base + ng * C::NPT + i;
        if (EPI >= 1) {
            acc[i].x = fmaxf(acc[i].x + bb.x, 0.f);
            acc[i].y = fmaxf(acc[i].y + bb.y, 0.f);
            acc[i].z = fmaxf(acc[i].z + bb.z, 0.f);
            acc[i].w = fmaxf(acc[i].w + bb.w, 0.f);
        }
        if (EPI == 2) {
            mx.x = fmaxf(mx.x, acc[i].x); mx.y = fmaxf(mx.y, acc[i].y);
            mx.z = fmaxf(mx.z, acc[i].z); mx.w = fmaxf(mx.w, acc[i].w);
        }
        if (node < NN) st4<BOUT>(hW, (size_t)node * C::CG + cg, acc[i]);
    }
    if (EPI == 2) {
        atomicMax(&smax[cg * 4 + 0], __float_as_int(mx.x));
        atomicMax(&smax[cg * 4 + 1], __float_as_int(mx.y));
        atomicMax(&smax[cg * 4 + 2], __float_as_int(mx.z));
        atomicMax(&smax[cg * 4 + 3], __float_as_int(mx.w));
        __syncthreads();
        if (t < COUT) atomicMax((int*)&xmax[t], smax[t]);
    }
}

// ---------- aggregate-first (input width), fp32 out ----------
template<int C, bool BIN>
__global__ void k_agg(const void* __restrict__ hin, const float* __restrict__ dinv,
                      const int* __restrict__ row_off, const int* __restrict__ counts,
                      const int* __restrict__ srcs, const float* __restrict__ normv,
                      float* __restrict__ out) {
    constexpr int CG = C / 4;
    int tid = blockIdx.x * 256 + threadIdx.x;
    int n = tid / CG, cg = tid - n * CG;
    if (n >= NN) return;
    float di = dinv[n];
    float d2 = di * di;
    float4 s4 = ld4<BIN>(hin, (size_t)n * CG + cg);
    float4 acc = make_float4(s4.x * d2, s4.y * d2, s4.z * d2, s4.w * d2);
    int start = row_off[n];
    int len = counts[n];
    int i = 0;
    for (; i + 2 <= len; i += 2) {
        int s0 = srcs[start + i], s1 = srcs[start + i + 1];
        float w0 = normv[start + i], w1 = normv[start + i + 1];
        float4 v0 = ld4<BIN>(hin, (size_t)s0 * CG + cg);
        float4 v1 = ld4<BIN>(hin, (size_t)s1 * CG + cg);
        acc.x = fmaf(w0, v0.x, acc.x); acc.y = fmaf(w0, v0.y, acc.y);
        acc.z = fmaf(w0, v0.z, acc.z); acc.w = fmaf(w0, v0.w, acc.w);
        acc.x = fmaf(w1, v1.x, acc.x); acc.y = fmaf(w1, v1.y, acc.y);
        acc.z = fmaf(w1, v1.z, acc.z); acc.w = fmaf(w1, v1.w, acc.w);
    }
    if (i < len) {
        int s0 = srcs[start + i];
        float w0 = normv[start + i];
        float4 v0 = ld4<BIN>(hin, (size_t)s0 * CG + cg);
        acc.x = fmaf(w0, v0.x, acc.x); acc.y = fmaf(w0, v0.y, acc.y);
        acc.z = fmaf(w0, v0.z, acc.z); acc.w = fmaf(w0, v0.w, acc.w);
    }
    ((float4*)out)[(size_t)n * CG + cg] = acc;
}

// ---------- 128-wide gather, bf16 in, column-chunked (grid.y = chunk of 32 cols) ----------
__global__ __launch_bounds__(256) void k_gather128c(
        const unsigned int* __restrict__ T, const float* __restrict__ dinv,
        const int* __restrict__ row_off, const int* __restrict__ counts,
        const int* __restrict__ srcs, const float* __restrict__ normv,
        const float* __restrict__ bias, float* __restrict__ H) {
    int tid = blockIdx.x * 256 + threadIdx.x;
    int n = tid >> 3;
    if (n >= NN) return;
    int cg = blockIdx.y * 8 + (tid & 7);
    const uint2* t2 = (const uint2*)T;
    float di = dinv[n];
    float d2 = di * di;
    float4 s4 = ld4bf(t2[(size_t)n * 32 + cg]);
    float4 acc = make_float4(s4.x * d2, s4.y * d2, s4.z * d2, s4.w * d2);
    int start = row_off[n];
    int len = counts[n];
    int i = 0;
    for (; i + 2 <= len; i += 2) {
        int s0 = srcs[start + i], s1 = srcs[start + i + 1];
        float w0 = normv[start + i], w1 = normv[start + i + 1];
        float4 v0 = ld4bf(t2[(size_t)s0 * 32 + cg]);
        float4 v1 = ld4bf(t2[(size_t)s1 * 32 + cg]);
        acc.x = fmaf(w0, v0.x, acc.x); acc.y = fmaf(w0, v0.y, acc.y);
        acc.z = fmaf(w0, v0.z, acc.z); acc.w = fmaf(w0, v0.w, acc.w);
        acc.x = fmaf(w1, v1.x, acc.x); acc.y = fmaf(w1, v1.y, acc.y);
        acc.z = fmaf(w1, v1.z, acc.z); acc.w = fmaf(w1, v1.w, acc.w);
    }
    if (i < len) {
        int s0 = srcs[start + i];
        float w0 = normv[start + i];
        float4 v0 = ld4bf(t2[(size_t)s0 * 32 + cg]);
        acc.x = fmaf(w0, v0.x, acc.x); acc.y = fmaf(w0, v0.y, acc.y);
        acc.z = fmaf(w0, v0.z, acc.z); acc.w = fmaf(w0, v0.w, acc.w);
    }
    float4 bb = ((const float4*)bias)[cg];
    acc.x = fmaxf(acc.x + bb.x, 0.f);
    acc.y = fmaxf(acc.y + bb.y, 0.f);
    acc.z = fmaxf(acc.z + bb.z, 0.f);
    acc.w = fmaxf(acc.w + bb.w, 0.f);
    st4_nt(&H[((size_t)n * 32 + cg) * 4], acc);  // non-temporal: don't evict T from L2
}

// ---------- 32-wide gather (bf16 in) + bias + relu + segment_max ----------
__global__ __launch_bounds__(256) void k_gather32(
        const unsigned int* __restrict__ T, const float* __restrict__ dinv,
        const int* __restrict__ row_off, const int* __restrict__ counts,
        const int* __restrict__ srcs, const float* __restrict__ normv,
        const float* __restrict__ bias, float* __restrict__ H, float* xmax) {
    __shared__ int smax[32];
    int tid = blockIdx.x * 256 + threadIdx.x;
    int n = tid >> 3, cg = tid & 7;
    if (threadIdx.x < 32) smax[threadIdx.x] = 0;
    __syncthreads();
    float4 acc = make_float4(0.f, 0.f, 0.f, 0.f);
    bool valid = (n < NN);
    if (valid) {
        const uint2* t2 = (const uint2*)T;
        float di = dinv[n];
        float d2 = di * di;
        float4 s4 = ld4bf(t2[(size_t)n * 8 + cg]);
        acc.x = s4.x * d2; acc.y = s4.y * d2; acc.z = s4.z * d2; acc.w = s4.w * d2;
        int start = row_off[n];
        int len = counts[n];
        int i = 0;
        for (; i + 2 <= len; i += 2) {
            int s0 = srcs[start + i], s1 = srcs[start + i + 1];
            float w0 = normv[start + i], w1 = normv[start + i + 1];
            float4 v0 = ld4bf(t2[(size_t)s0 * 8 + cg]);
            float4 v1 = ld4bf(t2[(size_t)s1 * 8 + cg]);
            acc.x = fmaf(w0, v0.x, acc.x); acc.y = fmaf(w0, v0.y, acc.y);
            acc.z = fmaf(w0, v0.z, acc.z); acc.w = fmaf(w0, v0.w, acc.w);
            acc.x = fmaf(w1, v1.x, acc.x); acc.y = fmaf(w1, v1.y, acc.y);
            acc.z = fmaf(w1, v1.z, acc.z); acc.w = fmaf(w1, v1.w, acc.w);
        }
        if (i < len) {
            int s0 = srcs[start + i];
            float w0 = normv[start + i];
            float4 v0 = ld4bf(t2[(size_t)s0 * 8 + cg]);
            acc.x = fmaf(w0, v0.x, acc.x); acc.y = fmaf(w0, v0.y, acc.y);
            acc.z = fmaf(w0, v0.z, acc.z); acc.w = fmaf(w0, v0.w, acc.w);
        }
        float4 bb = ((const float4*)bias)[cg];
        acc.x = fmaxf(acc.x + bb.x, 0.f);
        acc.y = fmaxf(acc.y + bb.y, 0.f);
        acc.z = fmaxf(acc.z + bb.z, 0.f);
        acc.w = fmaxf(acc.w + bb.w, 0.f);
        st4_nt(&H[((size_t)n * 8 + cg) * 4], acc);
        atomicMax(&smax[cg * 4 + 0], __float_as_int(acc.x));
        atomicMax(&smax[cg * 4 + 1], __float_as_int(acc.y));
        atomicMax(&smax[cg * 4 + 2], __float_as_int(acc.z));
        atomicMax(&smax[cg * 4 + 3], __float_as_int(acc.w));
    }
    __syncthreads();
    if (threadIdx.x < 32) atomicMax((int*)&xmax[threadIdx.x], smax[threadIdx.x]);
}

// ---------- head MLP + softmax + fp32 output ----------
__global__ void k_mlp(const float* x0x1, const float* Pc, float* out) {
    const float* C2  = Pc + 25152;
    const float* L1W = Pc + 25156;
    const float* L1b = Pc + 33860;
    const float* L2W = Pc + 33988;
    const float* L2b = Pc + 50372;
    const float* L3W = Pc + 50500;
    const float* L3b = Pc + 51780;
    __shared__ float code[68], z1[128], z2[128];
    int t = threadIdx.x;
    if (t < 64) code[t] = x0x1[t];
    else if (t < 68) code[t] = C2[t - 64];
    __syncthreads();
    float acc = L1b[t];
    for (int i = 0; i < 68; i++) acc = fmaf(code[i], L1W[i * 128 + t], acc);
    z1[t] = fmaxf(acc, 0.f);
    __syncthreads();
    acc = L2b[t];
    for (int i = 0; i < 128; i++) acc = fmaf(z1[i], L2W[i * 128 + t], acc);
    z2[t] = fmaxf(acc, 0.f);
    __syncthreads();
    if (t == 0) {
        float lg[10];
        for (int c = 0; c < 10; c++) {
            float a = L3b[c];
            for (int i = 0; i < 128; i++) a = fmaf(z2[i], L3W[i * 10 + c], a);
            lg[c] = a;
        }
        float m = lg[0];
        for (int c = 1; c < 10; c++) m = fmaxf(m, lg[c]);
        float s = 0.f;
        for (int c = 0; c < 10; c++) { lg[c] = __expf(lg[c] - m); s += lg[c]; }
        float inv = 1.f / s;
        for (int c = 0; c < 10; c++) out[c] = lg[c] * inv;
    }
    if (t < 68) out[10 + t] = code[t];
}

extern "C" void kernel_launch(void* const* d_in, const int* in_sizes, int n_in,
                              void* d_out, int out_size, void* d_ws, size_t ws_size,
                              hipStream_t stream) {
    const void* x    = d_in[0];
    const int*  ei   = (const int*)d_in[1];
    const void* ew   = d_in[2];
    const void* C2ER = d_in[4];
    float* out = (float*)d_out;
    (void)in_sizes; (void)n_in; (void)out_size; (void)ws_size;

    const size_t szF = (size_t)NN * 128 * 4;
    char* p = (char*)d_ws;
    char* H      = p;          p += szF;              // fp32 wide buffer
    char* T      = p;          p += szF;              // mixed fp32/bf16 staging
    float* xf    = (float*)p;  p += (size_t)NN * 8 * 4;
    float* ewf   = (float*)p;  p += (size_t)NE * 4;
    int*   srcs  = (int*)p;    p += (size_t)NE * 4;
    float* normv = (float*)p;  p += (size_t)NE * 4;
    float* dinv  = (float*)p;  p += (size_t)NN * 4;
    int*   counts= (int*)p;    p += (size_t)NN * 4;
    int*   rowoff= (int*)p;    p += (size_t)NN * 4;
    int*   cursor= (int*)p;    p += (size_t)NN * 4;
    int*   blk   = (int*)p;    p += 1024;
    float* x0x1  = (float*)p;  p += 256 * 4;
    float* Pc    = (float*)p;  p += 51792 * 4;
    int*   flag  = (int*)p;    p += 64;

    const int* srcI = ei;
    const int* dstI = ei + NE;

    dim3 B(256);
    k_probe<<<dim3(1), B, 0, stream>>>(x, flag);
    k_cvt<<<dim3((NN * 8 + 255) / 256), B, 0, stream>>>(x, xf, NN * 8, flag);
    k_cvt<<<dim3((NE + 255) / 256), B, 0, stream>>>(ew, ewf, NE, flag);
    k_cvt_params<<<dim3((51790 + 255) / 256), B, 0, stream>>>(
        d_in[5], d_in[6], d_in[7], d_in[8], d_in[9], d_in[10], d_in[11], d_in[12],
        C2ER, d_in[13], d_in[14], d_in[15], d_in[16], d_in[17], d_in[18], Pc, flag);

    k_init<<<dim3((NN + 255) / 256), B, 0, stream>>>(counts, cursor, x0x1);
    k_count<<<dim3((NE + 255) / 256), B, 0, stream>>>(dstI, counts);
    k_scan1<<<dim3(98), dim3(1024), 0, stream>>>(counts, rowoff, blk);
    k_scan2<<<dim3(1), dim3(64), 0, stream>>>(blk);
    k_scan3<<<dim3((NN + 255) / 256), B, 0, stream>>>(rowoff, blk);
    k_fill<<<dim3((NE + 255) / 256), B, 0, stream>>>(srcI, dstI, ewf, rowoff, cursor, srcs, normv);
    k_deg<<<dim3((NN + 255) / 256), B, 0, stream>>>(rowoff, counts, normv, dinv);
    k_norm<<<dim3((NN + 255) / 256), B, 0, stream>>>(rowoff, counts, srcs, dinv, normv);

    const float* W1f = Pc,         * b1f = Pc + 256;
    const float* W2f = Pc + 288,   * b2f = Pc + 4384;
    const float* W3f = Pc + 4512,  * b3f = Pc + 20896;
    const float* W4f = Pc + 21024, * b4f = Pc + 25120;

    constexpr int TN1 = GemmCfg<8, 32>::TN;
    constexpr int TN2 = GemmCfg<32, 128>::TN;
    constexpr int TN3 = GemmCfg<128, 128>::TN;
    constexpr int TN4 = GemmCfg<128, 32>::TN;

    // L1: agg xf @8 (fp32) -> gemm 8->32 (+bias+relu+max) -> H32 bf16
    k_agg<8, false><<<dim3((NN * 2 + 255) / 256), B, 0, stream>>>(xf, dinv, rowoff, counts, srcs, normv, (float*)T);
    k_gemm<8, 32, false, true, 2><<<dim3((NN + TN1 - 1) / TN1), B, 0, stream>>>(T, W1f, H, b1f, x0x1);
    // L2: agg H32(bf16) @32 -> T fp32 -> gemm 32->128 (+bias+relu) -> H128 fp32
    k_agg<32, true><<<dim3((NN * 8 + 255) / 256), B, 0, stream>>>(H, dinv, rowoff, counts, srcs, normv, (float*)T);
    k_gemm<32, 128, false, false, 1><<<dim3((NN + TN2 - 1) / TN2), B, 0, stream>>>(T, W2f, H, b2f, nullptr);
    // L3: gemm 128->128 -> T bf16 -> chunked gather (+bias+relu) -> H128 fp32
    k_gemm<128, 128, false, true, 0><<<dim3((NN + TN3 - 1) / TN3), B, 0, stream>>>(H, W3f, T, nullptr, nullptr);
    k_gather128c<<<dim3((NN * 8 + 255) / 256, 4), B, 0, stream>>>((const unsigned int*)T, dinv, rowoff, counts, srcs, normv, b3f, (float*)H);
    // L4: gemm 128->32 -> T bf16 -> gather32 (+bias+relu+max)
    k_gemm<128, 32, false, true, 0><<<dim3((NN + TN4 - 1) / TN4), B, 0, stream>>>(H, W4f, T, nullptr, nullptr);
    k_gather32<<<dim3((NN * 8 + 255) / 256), B, 0, stream>>>((const unsigned int*)T, dinv, rowoff, counts, srcs, normv, b4f, (float*)H, x0x1 + 32);

    k_mlp<<<dim3(1), dim3(128), 0, stream>>>(x0x1, Pc, out);
}

// Round 7
// 445.076 us; speedup vs baseline: 1.4871x; 1.0067x over previous
//
#include <hip/hip_runtime.h>
#include <hip/hip_bf16.h>

#define NN 100000
#define NE 600000

using bf16 = __hip_bfloat16;
typedef float f32x4 __attribute__((ext_vector_type(4)));

__device__ __forceinline__ float b2f(bf16 v) { return __bfloat162float(v); }

__device__ __forceinline__ float bu2f(unsigned int u16) {
    union { float f; unsigned int i; } c; c.i = u16 << 16; return c.f;
}
__device__ __forceinline__ unsigned int f2bu(float f) {
    bf16 h = __float2bfloat16(f);
    return (unsigned int)*reinterpret_cast<unsigned short*>(&h);
}
__device__ __forceinline__ float4 ld4bf(uint2 u) {
    float4 r;
    r.x = bu2f(u.x & 0xffffu); r.y = bu2f(u.x >> 16);
    r.z = bu2f(u.y & 0xffffu); r.w = bu2f(u.y >> 16);
    return r;
}
__device__ __forceinline__ uint2 st4bf(float4 a) {
    uint2 u;
    u.x = f2bu(a.x) | (f2bu(a.y) << 16);
    u.y = f2bu(a.z) | (f2bu(a.w) << 16);
    return u;
}

template<bool BF16>
__device__ __forceinline__ float4 ld4(const void* base, size_t idx4) {
    if constexpr (BF16) return ld4bf(((const uint2*)base)[idx4]);
    else return ((const float4*)base)[idx4];
}
template<bool BF16>
__device__ __forceinline__ void st4(void* base, size_t idx4, float4 v) {
    if constexpr (BF16) ((uint2*)base)[idx4] = st4bf(v);
    else ((float4*)base)[idx4] = v;
}
__device__ __forceinline__ void st4_nt(float* p, float4 v) {
    f32x4 t = {v.x, v.y, v.z, v.w};
    __builtin_nontemporal_store(t, (f32x4*)p);
}

// ---------- dtype probe ----------
__global__ void k_probe(const void* x, int* flag) {
    __shared__ int bad;
    if (threadIdx.x == 0) bad = 0;
    __syncthreads();
    const unsigned short* u = (const unsigned short*)x;
    int mybad = 0;
    for (int i = threadIdx.x; i < 2048; i += 256) {
        unsigned short h = u[i];
        unsigned int e = (h >> 7) & 0xffu;
        bool zero = (h & 0x7fffu) == 0;
        bool plaus = zero || (e >= 96u && e <= 140u);
        if (!plaus) mybad++;
    }
    atomicAdd(&bad, mybad);
    __syncthreads();
    if (threadIdx.x == 0) *flag = (bad > 64) ? 1 : 0;
}

__global__ void k_cvt(const void* src, float* dst, int n, const int* flag) {
    int i = blockIdx.x * 256 + threadIdx.x;
    if (i >= n) return;
    if (*flag) dst[i] = ((const float*)src)[i];
    else       dst[i] = b2f(((const bf16*)src)[i]);
}

__global__ void k_cvt_params(const void* W1, const void* b1, const void* W2, const void* b2,
                             const void* W3, const void* b3, const void* W4, const void* b4,
                             const void* C2, const void* L1W, const void* L1b,
                             const void* L2W, const void* L2b, const void* L3W, const void* L3b,
                             float* dst, const int* flag) {
    int i = blockIdx.x * 256 + threadIdx.x;
    const void* p; int off;
    if      (i < 256)    { p = W1;  off = i; }
    else if (i < 288)    { p = b1;  off = i - 256; }
    else if (i < 4384)   { p = W2;  off = i - 288; }
    else if (i < 4512)   { p = b2;  off = i - 4384; }
    else if (i < 20896)  { p = W3;  off = i - 4512; }
    else if (i < 21024)  { p = b3;  off = i - 20896; }
    else if (i < 25120)  { p = W4;  off = i - 21024; }
    else if (i < 25152)  { p = b4;  off = i - 25120; }
    else if (i < 25156)  { p = C2;  off = i - 25152; }
    else if (i < 33860)  { p = L1W; off = i - 25156; }
    else if (i < 33988)  { p = L1b; off = i - 33860; }
    else if (i < 50372)  { p = L2W; off = i - 33988; }
    else if (i < 50500)  { p = L2b; off = i - 50372; }
    else if (i < 51780)  { p = L3W; off = i - 50500; }
    else if (i < 51790)  { p = L3b; off = i - 51780; }
    else return;
    if (*flag) dst[i] = ((const float*)p)[off];
    else       dst[i] = b2f(((const bf16*)p)[off]);
}

// ---------- prep ----------
__global__ void k_init(int* counts, int* cursor, float* x0x1) {
    int i = blockIdx.x * 256 + threadIdx.x;
    if (i < NN) { counts[i] = 0; cursor[i] = 0; }
    if (i < 64) x0x1[i] = 0.0f;
}

__global__ void k_count(const int* dstI, int* counts) {
    int e = blockIdx.x * 256 + threadIdx.x;
    if (e >= NE) return;
    atomicAdd(&counts[dstI[e]], 1);
}

__global__ void k_scan1(const int* counts, int* row_off, int* blk) {
    __shared__ int sm[1024];
    int t = threadIdx.x;
    int i = blockIdx.x * 1024 + t;
    int v = (i < NN) ? counts[i] : 0;
    sm[t] = v;
    __syncthreads();
    for (int off = 1; off < 1024; off <<= 1) {
        int x = (t >= off) ? sm[t - off] : 0;
        __syncthreads();
        sm[t] += x;
        __syncthreads();
    }
    if (i < NN) row_off[i] = sm[t] - v;
    if (t == 1023) blk[blockIdx.x] = sm[t];
}

__global__ void k_scan2(int* blk) {
    if (threadIdx.x == 0 && blockIdx.x == 0) {
        int acc = 0;
        for (int i = 0; i < 98; i++) { int v = blk[i]; blk[i] = acc; acc += v; }
    }
}

__global__ void k_scan3(int* row_off, const int* blk) {
    int i = blockIdx.x * 256 + threadIdx.x;
    if (i < NN) row_off[i] += blk[i >> 10];
}

__global__ void k_fill(const int* srcI, const int* dstI, const float* ewf,
                       const int* row_off, int* cursor, int* srcs, float* normv) {
    int e = blockIdx.x * 256 + threadIdx.x;
    if (e >= NE) return;
    int d = dstI[e];
    int pos = row_off[d] + atomicAdd(&cursor[d], 1);
    srcs[pos] = srcI[e];
    normv[pos] = ewf[e];
}

__global__ void k_deg(const int* row_off, const int* counts, const float* normv, float* dinv) {
    int n = blockIdx.x * 256 + threadIdx.x;
    if (n >= NN) return;
    int st = row_off[n], len = counts[n];
    float s = 1.0f;
    for (int i = 0; i < len; i++) s += normv[st + i];
    dinv[n] = rsqrtf(s);
}

__global__ void k_norm(const int* row_off, const int* counts, const int* srcs,
                       const float* dinv, float* normv) {
    int n = blockIdx.x * 256 + threadIdx.x;
    if (n >= NN) return;
    float dn = dinv[n];
    int st = row_off[n], len = counts[n];
    for (int i = 0; i < len; i++) normv[st + i] *= dinv[srcs[st + i]] * dn;
}

// ---------- dense: out = in @ W (+bias+relu (+max))  LDS-tiled ----------
template<int CIN, int COUT> struct GemmCfg {
    static constexpr int CG  = COUT / 4;
    static constexpr int NG  = 256 / CG;
    static constexpr int STR = CIN + 4;
    static constexpr int NPT = (NG * 8 * STR * 4 <= 36864) ? 8
                             : ((NG * 4 * STR * 4 <= 36864) ? 4 : 2);
    static constexpr int TN  = NG * NPT;
};

// EPI: 0 plain, 1 bias+relu, 2 bias+relu+colmax. CHOUT: bf16 chunk-major store (16 cols/chunk)
template<int CIN, int COUT, bool BIN, bool BOUT, bool CHOUT, int EPI>
__global__ __launch_bounds__(256) void k_gemm(const void* __restrict__ hin,
                                              const float* __restrict__ Wf,
                                              void* __restrict__ hW,
                                              const float* __restrict__ bias,
                                              float* xmax) {
    using C = GemmCfg<CIN, COUT>;
    __shared__ float xs[C::TN * C::STR];
    __shared__ int smax[(EPI == 2) ? COUT : 1];
    const int base = blockIdx.x * C::TN;
    const int t = threadIdx.x;
    constexpr int NF4 = C::TN * CIN / 4;
#pragma unroll
    for (int i = 0; i < NF4 / 256; i++) {
        int idx = t + 256 * i;
        int row = idx / (CIN / 4);
        int k4 = idx - row * (CIN / 4);
        int node = base + row;
        if (node >= NN) node = NN - 1;
        float4 v = ld4<BIN>(hin, (size_t)node * (CIN / 4) + k4);
        *(float4*)&xs[row * C::STR + 4 * k4] = v;
    }
    if (EPI == 2 && t < COUT) smax[t] = 0;
    __syncthreads();
    const int cg = t % C::CG, ng = t / C::CG;
    float4 acc[C::NPT];
#pragma unroll
    for (int i = 0; i < C::NPT; i++) acc[i] = make_float4(0.f, 0.f, 0.f, 0.f);
    const float4* wr = (const float4*)Wf;
#pragma unroll 2
    for (int k4 = 0; k4 < CIN / 4; k4++) {
        float4 w[4];
#pragma unroll
        for (int j = 0; j < 4; j++) w[j] = wr[(4 * k4 + j) * C::CG + cg];
#pragma unroll
        for (int i = 0; i < C::NPT; i++) {
            float4 xv = *(const float4*)&xs[(ng * C::NPT + i) * C::STR + 4 * k4];
            acc[i].x = fmaf(xv.x, w[0].x, acc[i].x);
            acc[i].y = fmaf(xv.x, w[0].y, acc[i].y);
            acc[i].z = fmaf(xv.x, w[0].z, acc[i].z);
            acc[i].w = fmaf(xv.x, w[0].w, acc[i].w);
            acc[i].x = fmaf(xv.y, w[1].x, acc[i].x);
            acc[i].y = fmaf(xv.y, w[1].y, acc[i].y);
            acc[i].z = fmaf(xv.y, w[1].z, acc[i].z);
            acc[i].w = fmaf(xv.y, w[1].w, acc[i].w);
            acc[i].x = fmaf(xv.z, w[2].x, acc[i].x);
            acc[i].y = fmaf(xv.z, w[2].y, acc[i].y);
            acc[i].z = fmaf(xv.z, w[2].z, acc[i].z);
            acc[i].w = fmaf(xv.z, w[2].w, acc[i].w);
            acc[i].x = fmaf(xv.w, w[3].x, acc[i].x);
            acc[i].y = fmaf(xv.w, w[3].y, acc[i].y);
            acc[i].z = fmaf(xv.w, w[3].z, acc[i].z);
            acc[i].w = fmaf(xv.w, w[3].w, acc[i].w);
        }
    }
    float4 bb;
    if (EPI >= 1) bb = ((const float4*)bias)[cg];
    float4 mx = make_float4(0.f, 0.f, 0.f, 0.f);
#pragma unroll
    for (int i = 0; i < C::NPT; i++) {
        int node = base + ng * C::NPT + i;
        if (EPI >= 1) {
            acc[i].x = fmaxf(acc[i].x + bb.x, 0.f);
            acc[i].y = fmaxf(acc[i].y + bb.y, 0.f);
            acc[i].z = fmaxf(acc[i].z + bb.z, 0.f);
            acc[i].w = fmaxf(acc[i].w + bb.w, 0.f);
        }
        if (EPI == 2) {
            mx.x = fmaxf(mx.x, acc[i].x); mx.y = fmaxf(mx.y, acc[i].y);
            mx.z = fmaxf(mx.z, acc[i].z); mx.w = fmaxf(mx.w, acc[i].w);
        }
        if (node < NN) {
            if constexpr (CHOUT) {
                size_t idx = ((size_t)(cg >> 2) * NN + node) * 4 + (cg & 3);
                st4<true>(hW, idx, acc[i]);
            } else {
                st4<BOUT>(hW, (size_t)node * C::CG + cg, acc[i]);
            }
        }
    }
    if (EPI == 2) {
        atomicMax(&smax[cg * 4 + 0], __float_as_int(mx.x));
        atomicMax(&smax[cg * 4 + 1], __float_as_int(mx.y));
        atomicMax(&smax[cg * 4 + 2], __float_as_int(mx.z));
        atomicMax(&smax[cg * 4 + 3], __float_as_int(mx.w));
        __syncthreads();
        if (t < COUT) atomicMax((int*)&xmax[t], smax[t]);
    }
}

// ---------- unified chunked aggregate ----------
// W total cols, CPC cols per chunk (grid.y = W/CPC). INCH: input chunk-major.
// EPI: 0 = agg only -> fp32 out; 1 = agg+bias+relu -> fp32 out; 3 = agg+bias+relu+colmax, NO store
template<int W, int CPC, bool BIN, bool INCH, int EPI>
__global__ __launch_bounds__(256) void k_ag(const void* __restrict__ hin,
        const float* __restrict__ dinv, const int* __restrict__ row_off,
        const int* __restrict__ counts, const int* __restrict__ srcs,
        const float* __restrict__ normv, const float* __restrict__ bias,
        float* __restrict__ outF, float* __restrict__ xmax) {
    constexpr int LPN = CPC / 4;
    __shared__ int smax[(EPI == 3) ? CPC : 1];
    int tid = blockIdx.x * 256 + threadIdx.x;
    int n = tid / LPN, g = tid % LPN;
    const int c = blockIdx.y;
    if (EPI == 3) {
        if (threadIdx.x < CPC) smax[threadIdx.x] = 0;
        __syncthreads();
    }
    bool valid = (n < NN);
    float4 acc = make_float4(0.f, 0.f, 0.f, 0.f);
    if (valid) {
        float di = dinv[n];
        float d2 = di * di;
        size_t selfIdx = INCH ? (((size_t)c * NN + n) * LPN + g)
                              : ((size_t)n * (W / 4) + c * LPN + g);
        float4 s4 = ld4<BIN>(hin, selfIdx);
        acc.x = s4.x * d2; acc.y = s4.y * d2; acc.z = s4.z * d2; acc.w = s4.w * d2;
        int start = row_off[n];
        int len = counts[n];
        int i = 0;
        for (; i + 2 <= len; i += 2) {
            int s0 = srcs[start + i], s1 = srcs[start + i + 1];
            float w0 = normv[start + i], w1 = normv[start + i + 1];
            size_t i0 = INCH ? (((size_t)c * NN + s0) * LPN + g) : ((size_t)s0 * (W / 4) + c * LPN + g);
            size_t i1 = INCH ? (((size_t)c * NN + s1) * LPN + g) : ((size_t)s1 * (W / 4) + c * LPN + g);
            float4 v0 = ld4<BIN>(hin, i0);
            float4 v1 = ld4<BIN>(hin, i1);
            acc.x = fmaf(w0, v0.x, acc.x); acc.y = fmaf(w0, v0.y, acc.y);
            acc.z = fmaf(w0, v0.z, acc.z); acc.w = fmaf(w0, v0.w, acc.w);
            acc.x = fmaf(w1, v1.x, acc.x); acc.y = fmaf(w1, v1.y, acc.y);
            acc.z = fmaf(w1, v1.z, acc.z); acc.w = fmaf(w1, v1.w, acc.w);
        }
        if (i < len) {
            int s0 = srcs[start + i];
            float w0 = normv[start + i];
            size_t i0 = INCH ? (((size_t)c * NN + s0) * LPN + g) : ((size_t)s0 * (W / 4) + c * LPN + g);
            float4 v0 = ld4<BIN>(hin, i0);
            acc.x = fmaf(w0, v0.x, acc.x); acc.y = fmaf(w0, v0.y, acc.y);
            acc.z = fmaf(w0, v0.z, acc.z); acc.w = fmaf(w0, v0.w, acc.w);
        }
        if (EPI >= 1) {
            float4 bb = ((const float4*)bias)[c * LPN + g];
            acc.x = fmaxf(acc.x + bb.x, 0.f);
            acc.y = fmaxf(acc.y + bb.y, 0.f);
            acc.z = fmaxf(acc.z + bb.z, 0.f);
            acc.w = fmaxf(acc.w + bb.w, 0.f);
        }
        if (EPI != 3) {
            st4_nt(&outF[((size_t)n * (W / 4) + c * LPN + g) * 4], acc);
        } else {
            atomicMax(&smax[g * 4 + 0], __float_as_int(acc.x));
            atomicMax(&smax[g * 4 + 1], __float_as_int(acc.y));
            atomicMax(&smax[g * 4 + 2], __float_as_int(acc.z));
            atomicMax(&smax[g * 4 + 3], __float_as_int(acc.w));
        }
    }
    if (EPI == 3) {
        __syncthreads();
        if (threadIdx.x < CPC) atomicMax((int*)&xmax[c * CPC + threadIdx.x], smax[threadIdx.x]);
    }
}

// ---------- head MLP + softmax + fp32 output ----------
__global__ void k_mlp(const float* x0x1, const float* Pc, float* out) {
    const float* C2  = Pc + 25152;
    const float* L1W = Pc + 25156;
    const float* L1b = Pc + 33860;
    const float* L2W = Pc + 33988;
    const float* L2b = Pc + 50372;
    const float* L3W = Pc + 50500;
    const float* L3b = Pc + 51780;
    __shared__ float code[68], z1[128], z2[128];
    int t = threadIdx.x;
    if (t < 64) code[t] = x0x1[t];
    else if (t < 68) code[t] = C2[t - 64];
    __syncthreads();
    float acc = L1b[t];
    for (int i = 0; i < 68; i++) acc = fmaf(code[i], L1W[i * 128 + t], acc);
    z1[t] = fmaxf(acc, 0.f);
    __syncthreads();
    acc = L2b[t];
    for (int i = 0; i < 128; i++) acc = fmaf(z1[i], L2W[i * 128 + t], acc);
    z2[t] = fmaxf(acc, 0.f);
    __syncthreads();
    if (t == 0) {
        float lg[10];
        for (int c = 0; c < 10; c++) {
            float a = L3b[c];
            for (int i = 0; i < 128; i++) a = fmaf(z2[i], L3W[i * 10 + c], a);
            lg[c] = a;
        }
        float m = lg[0];
        for (int c = 1; c < 10; c++) m = fmaxf(m, lg[c]);
        float s = 0.f;
        for (int c = 0; c < 10; c++) { lg[c] = __expf(lg[c] - m); s += lg[c]; }
        float inv = 1.f / s;
        for (int c = 0; c < 10; c++) out[c] = lg[c] * inv;
    }
    if (t < 68) out[10 + t] = code[t];
}

extern "C" void kernel_launch(void* const* d_in, const int* in_sizes, int n_in,
                              void* d_out, int out_size, void* d_ws, size_t ws_size,
                              hipStream_t stream) {
    const void* x    = d_in[0];
    const int*  ei   = (const int*)d_in[1];
    const void* ew   = d_in[2];
    const void* C2ER = d_in[4];
    float* out = (float*)d_out;
    (void)in_sizes; (void)n_in; (void)out_size; (void)ws_size;

    const size_t szF = (size_t)NN * 128 * 4;
    char* p = (char*)d_ws;
    char* H      = p;          p += szF;   // H1 bf16-chunked / H2 bf16 / H3 fp32
    char* T      = p;          p += szF;   // T1 fp32 / T2 fp32 / T3,T4 bf16-chunked
    float* xf    = (float*)p;  p += (size_t)NN * 8 * 4;
    float* ewf   = (float*)p;  p += (size_t)NE * 4;
    int*   srcs  = (int*)p;    p += (size_t)NE * 4;
    float* normv = (float*)p;  p += (size_t)NE * 4;
    float* dinv  = (float*)p;  p += (size_t)NN * 4;
    int*   counts= (int*)p;    p += (size_t)NN * 4;
    int*   rowoff= (int*)p;    p += (size_t)NN * 4;
    int*   cursor= (int*)p;    p += (size_t)NN * 4;
    int*   blk   = (int*)p;    p += 1024;
    float* x0x1  = (float*)p;  p += 256 * 4;
    float* Pc    = (float*)p;  p += 51792 * 4;
    int*   flag  = (int*)p;    p += 64;

    const int* srcI = ei;
    const int* dstI = ei + NE;

    dim3 B(256);
    k_probe<<<dim3(1), B, 0, stream>>>(x, flag);
    k_cvt<<<dim3((NN * 8 + 255) / 256), B, 0, stream>>>(x, xf, NN * 8, flag);
    k_cvt<<<dim3((NE + 255) / 256), B, 0, stream>>>(ew, ewf, NE, flag);
    k_cvt_params<<<dim3((51790 + 255) / 256), B, 0, stream>>>(
        d_in[5], d_in[6], d_in[7], d_in[8], d_in[9], d_in[10], d_in[11], d_in[12],
        C2ER, d_in[13], d_in[14], d_in[15], d_in[16], d_in[17], d_in[18], Pc, flag);

    k_init<<<dim3((NN + 255) / 256), B, 0, stream>>>(counts, cursor, x0x1);
    k_count<<<dim3((NE + 255) / 256), B, 0, stream>>>(dstI, counts);
    k_scan1<<<dim3(98), dim3(1024), 0, stream>>>(counts, rowoff, blk);
    k_scan2<<<dim3(1), dim3(64), 0, stream>>>(blk);
    k_scan3<<<dim3((NN + 255) / 256), B, 0, stream>>>(rowoff, blk);
    k_fill<<<dim3((NE + 255) / 256), B, 0, stream>>>(srcI, dstI, ewf, rowoff, cursor, srcs, normv);
    k_deg<<<dim3((NN + 255) / 256), B, 0, stream>>>(rowoff, counts, normv, dinv);
    k_norm<<<dim3((NN + 255) / 256), B, 0, stream>>>(rowoff, counts, srcs, dinv, normv);

    const float* W1f = Pc,         * b1f = Pc + 256;
    const float* W2f = Pc + 288,   * b2f = Pc + 4384;
    const float* W3f = Pc + 4512,  * b3f = Pc + 20896;
    const float* W4f = Pc + 21024, * b4f = Pc + 25120;

    constexpr int TN1 = GemmCfg<8, 32>::TN;
    constexpr int TN2 = GemmCfg<32, 128>::TN;
    constexpr int TN3 = GemmCfg<128, 128>::TN;
    constexpr int TN4 = GemmCfg<128, 32>::TN;

    // L1: agg xf @8 (fp32, 3.2MB L2-resident) -> T1 fp32; gemm 8->32 +bias+relu+max -> H1 bf16 chunk-major
    k_ag<8, 8, false, false, 0><<<dim3((NN * 2 + 255) / 256, 1), B, 0, stream>>>(
        xf, dinv, rowoff, counts, srcs, normv, nullptr, (float*)T, nullptr);
    k_gemm<8, 32, false, true, true, 2><<<dim3((NN + TN1 - 1) / TN1), B, 0, stream>>>(T, W1f, H, b1f, x0x1);
    // L2: agg H1 (bf16 chunk-major, 2 chunks x 3.2MB) -> T2 fp32; gemm 32->128 +bias+relu -> H2 bf16 linear
    k_ag<32, 16, true, true, 0><<<dim3((NN * 4 + 255) / 256, 2), B, 0, stream>>>(
        H, dinv, rowoff, counts, srcs, normv, nullptr, (float*)T, nullptr);
    k_gemm<32, 128, false, true, false, 1><<<dim3((NN + TN2 - 1) / TN2), B, 0, stream>>>(T, W2f, H, b2f, nullptr);
    // L3: gemm 128->128 (bf16 in) -> T3 bf16 chunk-major; agg 8 chunks x 3.2MB +bias+relu -> H3 fp32
    k_gemm<128, 128, true, true, true, 0><<<dim3((NN + TN3 - 1) / TN3), B, 0, stream>>>(H, W3f, T, nullptr, nullptr);
    k_ag<128, 16, true, true, 1><<<dim3((NN * 4 + 255) / 256, 8), B, 0, stream>>>(
        T, dinv, rowoff, counts, srcs, normv, b3f, (float*)H, nullptr);
    // L4: gemm 128->32 (fp32 in) -> T4 bf16 chunk-major; agg 2 chunks +bias+relu+max (no store)
    k_gemm<128, 32, false, true, true, 0><<<dim3((NN + TN4 - 1) / TN4), B, 0, stream>>>(H, W4f, T, nullptr, nullptr);
    k_ag<32, 16, true, true, 3><<<dim3((NN * 4 + 255) / 256, 2), B, 0, stream>>>(
        T, dinv, rowoff, counts, srcs, normv, b4f, nullptr, x0x1 + 32);

    k_mlp<<<dim3(1), dim3(128), 0, stream>>>(x0x1, Pc, out);
}

// Round 8
// 399.847 us; speedup vs baseline: 1.6553x; 1.1131x over previous
//
#include <hip/hip_runtime.h>
#include <hip/hip_bf16.h>

#define NN 100000
#define NE 600000

using bf16 = __hip_bfloat16;
typedef float f32x4 __attribute__((ext_vector_type(4)));

__device__ __forceinline__ float b2f(bf16 v) { return __bfloat162float(v); }

__device__ __forceinline__ float bu2f(unsigned int u16) {
    union { float f; unsigned int i; } c; c.i = u16 << 16; return c.f;
}
__device__ __forceinline__ unsigned int f2bu(float f) {
    bf16 h = __float2bfloat16(f);
    return (unsigned int)*reinterpret_cast<unsigned short*>(&h);
}
__device__ __forceinline__ float4 ld4bf(uint2 u) {
    float4 r;
    r.x = bu2f(u.x & 0xffffu); r.y = bu2f(u.x >> 16);
    r.z = bu2f(u.y & 0xffffu); r.w = bu2f(u.y >> 16);
    return r;
}
__device__ __forceinline__ uint2 st4bf(float4 a) {
    uint2 u;
    u.x = f2bu(a.x) | (f2bu(a.y) << 16);
    u.y = f2bu(a.z) | (f2bu(a.w) << 16);
    return u;
}
__device__ __forceinline__ void up8(uint4 u, float* a) {
    a[0] = bu2f(u.x & 0xffffu); a[1] = bu2f(u.x >> 16);
    a[2] = bu2f(u.y & 0xffffu); a[3] = bu2f(u.y >> 16);
    a[4] = bu2f(u.z & 0xffffu); a[5] = bu2f(u.z >> 16);
    a[6] = bu2f(u.w & 0xffffu); a[7] = bu2f(u.w >> 16);
}

template<bool BF16>
__device__ __forceinline__ float4 ld4(const void* base, size_t idx4) {
    if constexpr (BF16) return ld4bf(((const uint2*)base)[idx4]);
    else return ((const float4*)base)[idx4];
}
template<bool BF16>
__device__ __forceinline__ void st4(void* base, size_t idx4, float4 v) {
    if constexpr (BF16) ((uint2*)base)[idx4] = st4bf(v);
    else ((float4*)base)[idx4] = v;
}
__device__ __forceinline__ void st4_nt(float* p, float4 v) {
    f32x4 t = {v.x, v.y, v.z, v.w};
    __builtin_nontemporal_store(t, (f32x4*)p);
}

// ---------- dtype probe ----------
__global__ void k_probe(const void* x, int* flag) {
    __shared__ int bad;
    if (threadIdx.x == 0) bad = 0;
    __syncthreads();
    const unsigned short* u = (const unsigned short*)x;
    int mybad = 0;
    for (int i = threadIdx.x; i < 2048; i += 256) {
        unsigned short h = u[i];
        unsigned int e = (h >> 7) & 0xffu;
        bool zero = (h & 0x7fffu) == 0;
        bool plaus = zero || (e >= 96u && e <= 140u);
        if (!plaus) mybad++;
    }
    atomicAdd(&bad, mybad);
    __syncthreads();
    if (threadIdx.x == 0) *flag = (bad > 64) ? 1 : 0;
}

__global__ void k_cvt(const void* src, float* dst, int n, const int* flag) {
    int i = blockIdx.x * 256 + threadIdx.x;
    if (i >= n) return;
    if (*flag) dst[i] = ((const float*)src)[i];
    else       dst[i] = b2f(((const bf16*)src)[i]);
}

__global__ void k_cvt_params(const void* W1, const void* b1, const void* W2, const void* b2,
                             const void* W3, const void* b3, const void* W4, const void* b4,
                             const void* C2, const void* L1W, const void* L1b,
                             const void* L2W, const void* L2b, const void* L3W, const void* L3b,
                             float* dst, const int* flag) {
    int i = blockIdx.x * 256 + threadIdx.x;
    const void* p; int off;
    if      (i < 256)    { p = W1;  off = i; }
    else if (i < 288)    { p = b1;  off = i - 256; }
    else if (i < 4384)   { p = W2;  off = i - 288; }
    else if (i < 4512)   { p = b2;  off = i - 4384; }
    else if (i < 20896)  { p = W3;  off = i - 4512; }
    else if (i < 21024)  { p = b3;  off = i - 20896; }
    else if (i < 25120)  { p = W4;  off = i - 21024; }
    else if (i < 25152)  { p = b4;  off = i - 25120; }
    else if (i < 25156)  { p = C2;  off = i - 25152; }
    else if (i < 33860)  { p = L1W; off = i - 25156; }
    else if (i < 33988)  { p = L1b; off = i - 33860; }
    else if (i < 50372)  { p = L2W; off = i - 33988; }
    else if (i < 50500)  { p = L2b; off = i - 50372; }
    else if (i < 51780)  { p = L3W; off = i - 50500; }
    else if (i < 51790)  { p = L3b; off = i - 51780; }
    else return;
    if (*flag) dst[i] = ((const float*)p)[off];
    else       dst[i] = b2f(((const bf16*)p)[off]);
}

// ---------- prep ----------
__global__ void k_init(int* counts, int* cursor, float* x0x1) {
    int i = blockIdx.x * 256 + threadIdx.x;
    if (i < NN) { counts[i] = 0; cursor[i] = 0; }
    if (i < 64) x0x1[i] = 0.0f;
}

__global__ void k_count(const int* dstI, int* counts) {
    int e = blockIdx.x * 256 + threadIdx.x;
    if (e >= NE) return;
    atomicAdd(&counts[dstI[e]], 1);
}

__global__ void k_scan1(const int* counts, int* row_off, int* blk) {
    __shared__ int sm[1024];
    int t = threadIdx.x;
    int i = blockIdx.x * 1024 + t;
    int v = (i < NN) ? counts[i] : 0;
    sm[t] = v;
    __syncthreads();
    for (int off = 1; off < 1024; off <<= 1) {
        int x = (t >= off) ? sm[t - off] : 0;
        __syncthreads();
        sm[t] += x;
        __syncthreads();
    }
    if (i < NN) row_off[i] = sm[t] - v;
    if (t == 1023) blk[blockIdx.x] = sm[t];
}

__global__ void k_scan2(int* blk) {
    if (threadIdx.x == 0 && blockIdx.x == 0) {
        int acc = 0;
        for (int i = 0; i < 98; i++) { int v = blk[i]; blk[i] = acc; acc += v; }
    }
}

__global__ void k_scan3(int* row_off, const int* blk) {
    int i = blockIdx.x * 256 + threadIdx.x;
    if (i < NN) row_off[i] += blk[i >> 10];
}

__global__ void k_fill(const int* srcI, const int* dstI, const float* ewf,
                       const int* row_off, int* cursor, int* srcs, float* normv) {
    int e = blockIdx.x * 256 + threadIdx.x;
    if (e >= NE) return;
    int d = dstI[e];
    int pos = row_off[d] + atomicAdd(&cursor[d], 1);
    srcs[pos] = srcI[e];
    normv[pos] = ewf[e];
}

__global__ void k_deg(const int* row_off, const int* counts, const float* normv, float* dinv) {
    int n = blockIdx.x * 256 + threadIdx.x;
    if (n >= NN) return;
    int st = row_off[n], len = counts[n];
    float s = 1.0f;
    for (int i = 0; i < len; i++) s += normv[st + i];
    dinv[n] = rsqrtf(s);
}

__global__ void k_norm(const int* row_off, const int* counts, const int* srcs,
                       const float* dinv, float* normv) {
    int n = blockIdx.x * 256 + threadIdx.x;
    if (n >= NN) return;
    float dn = dinv[n];
    int st = row_off[n], len = counts[n];
    for (int i = 0; i < len; i++) normv[st + i] *= dinv[srcs[st + i]] * dn;
}

// ---------- dense: out = in @ W (+bias+relu (+max))  LDS-tiled ----------
template<int CIN, int COUT> struct GemmCfg {
    static constexpr int CG  = COUT / 4;
    static constexpr int NG  = 256 / CG;
    static constexpr int STR = CIN + 4;
    static constexpr int NPT = (NG * 8 * STR * 4 <= 36864) ? 8
                             : ((NG * 4 * STR * 4 <= 36864) ? 4 : 2);
    static constexpr int TN  = NG * NPT;
};

// EPI: 0 plain, 1 bias+relu, 2 bias+relu+colmax
template<int CIN, int COUT, bool BIN, bool BOUT, int EPI>
__global__ __launch_bounds__(256) void k_gemm(const void* __restrict__ hin,
                                              const float* __restrict__ Wf,
                                              void* __restrict__ hW,
                                              const float* __restrict__ bias,
                                              float* xmax) {
    using C = GemmCfg<CIN, COUT>;
    __shared__ float xs[C::TN * C::STR];
    __shared__ int smax[(EPI == 2) ? COUT : 1];
    const int base = blockIdx.x * C::TN;
    const int t = threadIdx.x;
    constexpr int NF4 = C::TN * CIN / 4;
#pragma unroll
    for (int i = 0; i < NF4 / 256; i++) {
        int idx = t + 256 * i;
        int row = idx / (CIN / 4);
        int k4 = idx - row * (CIN / 4);
        int node = base + row;
        if (node >= NN) node = NN - 1;
        float4 v = ld4<BIN>(hin, (size_t)node * (CIN / 4) + k4);
        *(float4*)&xs[row * C::STR + 4 * k4] = v;
    }
    if (EPI == 2 && t < COUT) smax[t] = 0;
    __syncthreads();
    const int cg = t % C::CG, ng = t / C::CG;
    float4 acc[C::NPT];
#pragma unroll
    for (int i = 0; i < C::NPT; i++) acc[i] = make_float4(0.f, 0.f, 0.f, 0.f);
    const float4* wr = (const float4*)Wf;
#pragma unroll 2
    for (int k4 = 0; k4 < CIN / 4; k4++) {
        float4 w[4];
#pragma unroll
        for (int j = 0; j < 4; j++) w[j] = wr[(4 * k4 + j) * C::CG + cg];
#pragma unroll
        for (int i = 0; i < C::NPT; i++) {
            float4 xv = *(const float4*)&xs[(ng * C::NPT + i) * C::STR + 4 * k4];
            acc[i].x = fmaf(xv.x, w[0].x, acc[i].x);
            acc[i].y = fmaf(xv.x, w[0].y, acc[i].y);
            acc[i].z = fmaf(xv.x, w[0].z, acc[i].z);
            acc[i].w = fmaf(xv.x, w[0].w, acc[i].w);
            acc[i].x = fmaf(xv.y, w[1].x, acc[i].x);
            acc[i].y = fmaf(xv.y, w[1].y, acc[i].y);
            acc[i].z = fmaf(xv.y, w[1].z, acc[i].z);
            acc[i].w = fmaf(xv.y, w[1].w, acc[i].w);
            acc[i].x = fmaf(xv.z, w[2].x, acc[i].x);
            acc[i].y = fmaf(xv.z, w[2].y, acc[i].y);
            acc[i].z = fmaf(xv.z, w[2].z, acc[i].z);
            acc[i].w = fmaf(xv.z, w[2].w, acc[i].w);
            acc[i].x = fmaf(xv.w, w[3].x, acc[i].x);
            acc[i].y = fmaf(xv.w, w[3].y, acc[i].y);
            acc[i].z = fmaf(xv.w, w[3].z, acc[i].z);
            acc[i].w = fmaf(xv.w, w[3].w, acc[i].w);
        }
    }
    float4 bb;
    if (EPI >= 1) bb = ((const float4*)bias)[cg];
    float4 mx = make_float4(0.f, 0.f, 0.f, 0.f);
#pragma unroll
    for (int i = 0; i < C::NPT; i++) {
        int node = base + ng * C::NPT + i;
        if (EPI >= 1) {
            acc[i].x = fmaxf(acc[i].x + bb.x, 0.f);
            acc[i].y = fmaxf(acc[i].y + bb.y, 0.f);
            acc[i].z = fmaxf(acc[i].z + bb.z, 0.f);
            acc[i].w = fmaxf(acc[i].w + bb.w, 0.f);
        }
        if (EPI == 2) {
            mx.x = fmaxf(mx.x, acc[i].x); mx.y = fmaxf(mx.y, acc[i].y);
            mx.z = fmaxf(mx.z, acc[i].z); mx.w = fmaxf(mx.w, acc[i].w);
        }
        if (node < NN) st4<BOUT>(hW, (size_t)node * C::CG + cg, acc[i]);
    }
    if (EPI == 2) {
        atomicMax(&smax[cg * 4 + 0], __float_as_int(mx.x));
        atomicMax(&smax[cg * 4 + 1], __float_as_int(mx.y));
        atomicMax(&smax[cg * 4 + 2], __float_as_int(mx.z));
        atomicMax(&smax[cg * 4 + 3], __float_as_int(mx.w));
        __syncthreads();
        if (t < COUT) atomicMax((int*)&xmax[t], smax[t]);
    }
}

// ---------- fp32 aggregate for L1 (width 8) ----------
__global__ __launch_bounds__(256) void k_ag8(const float* __restrict__ hin,
        const float* __restrict__ dinv, const int* __restrict__ row_off,
        const int* __restrict__ counts, const int* __restrict__ srcs,
        const float* __restrict__ normv, float* __restrict__ outF) {
    int tid = blockIdx.x * 256 + threadIdx.x;
    int n = tid >> 1, g = tid & 1;
    if (n >= NN) return;
    float di = dinv[n];
    float d2 = di * di;
    const float4* h4 = (const float4*)hin;
    float4 s4 = h4[(size_t)n * 2 + g];
    float4 acc = make_float4(s4.x * d2, s4.y * d2, s4.z * d2, s4.w * d2);
    int start = row_off[n], len = counts[n];
    int i = 0;
    for (; i + 2 <= len; i += 2) {
        int s0 = srcs[start + i], s1 = srcs[start + i + 1];
        float w0 = normv[start + i], w1 = normv[start + i + 1];
        float4 v0 = h4[(size_t)s0 * 2 + g];
        float4 v1 = h4[(size_t)s1 * 2 + g];
        acc.x = fmaf(w0, v0.x, acc.x); acc.y = fmaf(w0, v0.y, acc.y);
        acc.z = fmaf(w0, v0.z, acc.z); acc.w = fmaf(w0, v0.w, acc.w);
        acc.x = fmaf(w1, v1.x, acc.x); acc.y = fmaf(w1, v1.y, acc.y);
        acc.z = fmaf(w1, v1.z, acc.z); acc.w = fmaf(w1, v1.w, acc.w);
    }
    if (i < len) {
        int s0 = srcs[start + i];
        float w0 = normv[start + i];
        float4 v0 = h4[(size_t)s0 * 2 + g];
        acc.x = fmaf(w0, v0.x, acc.x); acc.y = fmaf(w0, v0.y, acc.y);
        acc.z = fmaf(w0, v0.z, acc.z); acc.w = fmaf(w0, v0.w, acc.w);
    }
    ((float4*)outF)[(size_t)n * 2 + g] = acc;
}

// ---------- bf16 aggregate, 16B/lane (8 cols/thread) ----------
// EPI: 0 = store fp32; 1 = bias+relu+store fp32; 3 = bias+relu+colmax, NO store
template<int W, int EPI>
__global__ __launch_bounds__(256) void k_ag16(const uint4* __restrict__ hin,
        const float* __restrict__ dinv, const int* __restrict__ row_off,
        const int* __restrict__ counts, const int* __restrict__ srcs,
        const float* __restrict__ normv, const float* __restrict__ bias,
        float* __restrict__ outF, float* __restrict__ xmax) {
    constexpr int TPN = W / 8;
    __shared__ int smax[(EPI == 3) ? W : 1];
    int tid = blockIdx.x * 256 + threadIdx.x;
    int n = tid / TPN, c = tid % TPN;
    if (EPI == 3) {
        if (threadIdx.x < W) smax[threadIdx.x] = 0;
        __syncthreads();
    }
    float acc[8];
    bool valid = (n < NN);
    if (valid) {
        float di = dinv[n];
        float d2 = di * di;
        float a[8];
        up8(hin[(size_t)n * TPN + c], a);
#pragma unroll
        for (int j = 0; j < 8; j++) acc[j] = a[j] * d2;
        int start = row_off[n], len = counts[n];
        int i = 0;
        for (; i + 2 <= len; i += 2) {
            int s0 = srcs[start + i], s1 = srcs[start + i + 1];
            float w0 = normv[start + i], w1 = normv[start + i + 1];
            uint4 u0 = hin[(size_t)s0 * TPN + c];
            uint4 u1 = hin[(size_t)s1 * TPN + c];
            float a0[8], a1[8];
            up8(u0, a0); up8(u1, a1);
#pragma unroll
            for (int j = 0; j < 8; j++) acc[j] = fmaf(w0, a0[j], acc[j]);
#pragma unroll
            for (int j = 0; j < 8; j++) acc[j] = fmaf(w1, a1[j], acc[j]);
        }
        if (i < len) {
            int s0 = srcs[start + i];
            float w0 = normv[start + i];
            float a0[8];
            up8(hin[(size_t)s0 * TPN + c], a0);
#pragma unroll
            for (int j = 0; j < 8; j++) acc[j] = fmaf(w0, a0[j], acc[j]);
        }
        if (EPI >= 1) {
#pragma unroll
            for (int j = 0; j < 8; j++) {
                acc[j] = fmaxf(acc[j] + bias[c * 8 + j], 0.f);
            }
        }
        if (EPI != 3) {
            st4_nt(&outF[(size_t)n * W + c * 8],     make_float4(acc[0], acc[1], acc[2], acc[3]));
            st4_nt(&outF[(size_t)n * W + c * 8 + 4], make_float4(acc[4], acc[5], acc[6], acc[7]));
        } else {
#pragma unroll
            for (int j = 0; j < 8; j++) atomicMax(&smax[c * 8 + j], __float_as_int(acc[j]));
        }
    }
    if (EPI == 3) {
        __syncthreads();
        if (threadIdx.x < W) atomicMax((int*)&xmax[threadIdx.x], smax[threadIdx.x]);
    }
}

// ---------- head MLP + softmax + fp32 output ----------
__global__ void k_mlp(const float* x0x1, const float* Pc, float* out) {
    const float* C2  = Pc + 25152;
    const float* L1W = Pc + 25156;
    const float* L1b = Pc + 33860;
    const float* L2W = Pc + 33988;
    const float* L2b = Pc + 50372;
    const float* L3W = Pc + 50500;
    const float* L3b = Pc + 51780;
    __shared__ float code[68], z1[128], z2[128];
    int t = threadIdx.x;
    if (t < 64) code[t] = x0x1[t];
    else if (t < 68) code[t] = C2[t - 64];
    __syncthreads();
    float acc = L1b[t];
    for (int i = 0; i < 68; i++) acc = fmaf(code[i], L1W[i * 128 + t], acc);
    z1[t] = fmaxf(acc, 0.f);
    __syncthreads();
    acc = L2b[t];
    for (int i = 0; i < 128; i++) acc = fmaf(z1[i], L2W[i * 128 + t], acc);
    z2[t] = fmaxf(acc, 0.f);
    __syncthreads();
    if (t == 0) {
        float lg[10];
        for (int c = 0; c < 10; c++) {
            float a = L3b[c];
            for (int i = 0; i < 128; i++) a = fmaf(z2[i], L3W[i * 10 + c], a);
            lg[c] = a;
        }
        float m = lg[0];
        for (int c = 1; c < 10; c++) m = fmaxf(m, lg[c]);
        float s = 0.f;
        for (int c = 0; c < 10; c++) { lg[c] = __expf(lg[c] - m); s += lg[c]; }
        float inv = 1.f / s;
        for (int c = 0; c < 10; c++) out[c] = lg[c] * inv;
    }
    if (t < 68) out[10 + t] = code[t];
}

extern "C" void kernel_launch(void* const* d_in, const int* in_sizes, int n_in,
                              void* d_out, int out_size, void* d_ws, size_t ws_size,
                              hipStream_t stream) {
    const void* x    = d_in[0];
    const int*  ei   = (const int*)d_in[1];
    const void* ew   = d_in[2];
    const void* C2ER = d_in[4];
    float* out = (float*)d_out;
    (void)in_sizes; (void)n_in; (void)out_size; (void)ws_size;

    const size_t szF = (size_t)NN * 128 * 4;
    char* p = (char*)d_ws;
    char* H      = p;          p += szF;   // H1 bf16 / H2 bf16 / H3 fp32
    char* T      = p;          p += szF;   // T1 fp32 / T2 fp32 / T3,T4 bf16
    float* xf    = (float*)p;  p += (size_t)NN * 8 * 4;
    float* ewf   = (float*)p;  p += (size_t)NE * 4;
    int*   srcs  = (int*)p;    p += (size_t)NE * 4;
    float* normv = (float*)p;  p += (size_t)NE * 4;
    float* dinv  = (float*)p;  p += (size_t)NN * 4;
    int*   counts= (int*)p;    p += (size_t)NN * 4;
    int*   rowoff= (int*)p;    p += (size_t)NN * 4;
    int*   cursor= (int*)p;    p += (size_t)NN * 4;
    int*   blk   = (int*)p;    p += 1024;
    float* x0x1  = (float*)p;  p += 256 * 4;
    float* Pc    = (float*)p;  p += 51792 * 4;
    int*   flag  = (int*)p;    p += 64;

    const int* srcI = ei;
    const int* dstI = ei + NE;

    dim3 B(256);
    k_probe<<<dim3(1), B, 0, stream>>>(x, flag);
    k_cvt<<<dim3((NN * 8 + 255) / 256), B, 0, stream>>>(x, xf, NN * 8, flag);
    k_cvt<<<dim3((NE + 255) / 256), B, 0, stream>>>(ew, ewf, NE, flag);
    k_cvt_params<<<dim3((51790 + 255) / 256), B, 0, stream>>>(
        d_in[5], d_in[6], d_in[7], d_in[8], d_in[9], d_in[10], d_in[11], d_in[12],
        C2ER, d_in[13], d_in[14], d_in[15], d_in[16], d_in[17], d_in[18], Pc, flag);

    k_init<<<dim3((NN + 255) / 256), B, 0, stream>>>(counts, cursor, x0x1);
    k_count<<<dim3((NE + 255) / 256), B, 0, stream>>>(dstI, counts);
    k_scan1<<<dim3(98), dim3(1024), 0, stream>>>(counts, rowoff, blk);
    k_scan2<<<dim3(1), dim3(64), 0, stream>>>(blk);
    k_scan3<<<dim3((NN + 255) / 256), B, 0, stream>>>(rowoff, blk);
    k_fill<<<dim3((NE + 255) / 256), B, 0, stream>>>(srcI, dstI, ewf, rowoff, cursor, srcs, normv);
    k_deg<<<dim3((NN + 255) / 256), B, 0, stream>>>(rowoff, counts, normv, dinv);
    k_norm<<<dim3((NN + 255) / 256), B, 0, stream>>>(rowoff, counts, srcs, dinv, normv);

    const float* W1f = Pc,         * b1f = Pc + 256;
    const float* W2f = Pc + 288,   * b2f = Pc + 4384;
    const float* W3f = Pc + 4512,  * b3f = Pc + 20896;
    const float* W4f = Pc + 21024, * b4f = Pc + 25120;

    constexpr int TN1 = GemmCfg<8, 32>::TN;
    constexpr int TN2 = GemmCfg<32, 128>::TN;
    constexpr int TN3 = GemmCfg<128, 128>::TN;
    constexpr int TN4 = GemmCfg<128, 32>::TN;

    // L1: agg xf @8 fp32 -> T1 fp32; gemm 8->32 +bias+relu+max -> H1 bf16
    k_ag8<<<dim3((NN * 2 + 255) / 256), B, 0, stream>>>(xf, dinv, rowoff, counts, srcs, normv, (float*)T);
    k_gemm<8, 32, false, true, 2><<<dim3((NN + TN1 - 1) / TN1), B, 0, stream>>>(T, W1f, H, b1f, x0x1);
    // L2: agg H1 bf16 @32 (uint4 loads) -> T2 fp32; gemm 32->128 +bias+relu -> H2 bf16
    k_ag16<32, 0><<<dim3((NN * 4 + 255) / 256), B, 0, stream>>>(
        (const uint4*)H, dinv, rowoff, counts, srcs, normv, nullptr, (float*)T, nullptr);
    k_gemm<32, 128, false, true, 1><<<dim3((NN + TN2 - 1) / TN2), B, 0, stream>>>(T, W2f, H, b2f, nullptr);
    // L3: gemm 128->128 (bf16 in) -> T3 bf16; agg @128 (uint4) +bias+relu -> H3 fp32
    k_gemm<128, 128, true, true, 0><<<dim3((NN + TN3 - 1) / TN3), B, 0, stream>>>(H, W3f, T, nullptr, nullptr);
    k_ag16<128, 1><<<dim3((NN * 16 + 255) / 256), B, 0, stream>>>(
        (const uint4*)T, dinv, rowoff, counts, srcs, normv, b3f, (float*)H, nullptr);
    // L4: gemm 128->32 (fp32 in) -> T4 bf16; agg @32 +bias+relu+max (no store)
    k_gemm<128, 32, false, true, 0><<<dim3((NN + TN4 - 1) / TN4), B, 0, stream>>>(H, W4f, T, nullptr, nullptr);
    k_ag16<32, 3><<<dim3((NN * 4 + 255) / 256), B, 0, stream>>>(
        (const uint4*)T, dinv, rowoff, counts, srcs, normv, b4f, nullptr, x0x1 + 32);

    k_mlp<<<dim3(1), dim3(128), 0, stream>>>(x0x1, Pc, out);
}

// Round 9
// 352.075 us; speedup vs baseline: 1.8799x; 1.1357x over previous
//
#include <hip/hip_runtime.h>
#include <hip/hip_bf16.h>

#define NN 100000
#define NE 600000

using bf16 = __hip_bfloat16;
typedef float f32x4 __attribute__((ext_vector_type(4)));
typedef short s16x8 __attribute__((ext_vector_type(8)));

__device__ __forceinline__ float b2f(bf16 v) { return __bfloat162float(v); }

__device__ __forceinline__ float bu2f(unsigned int u16) {
    union { float f; unsigned int i; } c; c.i = u16 << 16; return c.f;
}
__device__ __forceinline__ unsigned int f2bu(float f) {
    bf16 h = __float2bfloat16(f);
    return (unsigned int)*reinterpret_cast<unsigned short*>(&h);
}
__device__ __forceinline__ float4 ld4bf(uint2 u) {
    float4 r;
    r.x = bu2f(u.x & 0xffffu); r.y = bu2f(u.x >> 16);
    r.z = bu2f(u.y & 0xffffu); r.w = bu2f(u.y >> 16);
    return r;
}
__device__ __forceinline__ uint2 st4bf(float4 a) {
    uint2 u;
    u.x = f2bu(a.x) | (f2bu(a.y) << 16);
    u.y = f2bu(a.z) | (f2bu(a.w) << 16);
    return u;
}
__device__ __forceinline__ void up8(uint4 u, float* a) {
    a[0] = bu2f(u.x & 0xffffu); a[1] = bu2f(u.x >> 16);
    a[2] = bu2f(u.y & 0xffffu); a[3] = bu2f(u.y >> 16);
    a[4] = bu2f(u.z & 0xffffu); a[5] = bu2f(u.z >> 16);
    a[6] = bu2f(u.w & 0xffffu); a[7] = bu2f(u.w >> 16);
}

template<bool BF16>
__device__ __forceinline__ float4 ld4(const void* base, size_t idx4) {
    if constexpr (BF16) return ld4bf(((const uint2*)base)[idx4]);
    else return ((const float4*)base)[idx4];
}
template<bool BF16>
__device__ __forceinline__ void st4(void* base, size_t idx4, float4 v) {
    if constexpr (BF16) ((uint2*)base)[idx4] = st4bf(v);
    else ((float4*)base)[idx4] = v;
}
__device__ __forceinline__ void st4_nt(float* p, float4 v) {
    f32x4 t = {v.x, v.y, v.z, v.w};
    __builtin_nontemporal_store(t, (f32x4*)p);
}

// ---------- dtype probe ----------
__global__ void k_probe(const void* x, int* flag) {
    __shared__ int bad;
    if (threadIdx.x == 0) bad = 0;
    __syncthreads();
    const unsigned short* u = (const unsigned short*)x;
    int mybad = 0;
    for (int i = threadIdx.x; i < 2048; i += 256) {
        unsigned short h = u[i];
        unsigned int e = (h >> 7) & 0xffu;
        bool zero = (h & 0x7fffu) == 0;
        bool plaus = zero || (e >= 96u && e <= 140u);
        if (!plaus) mybad++;
    }
    atomicAdd(&bad, mybad);
    __syncthreads();
    if (threadIdx.x == 0) *flag = (bad > 64) ? 1 : 0;
}

__global__ void k_cvt(const void* src, float* dst, int n, const int* flag) {
    int i = blockIdx.x * 256 + threadIdx.x;
    if (i >= n) return;
    if (*flag) dst[i] = ((const float*)src)[i];
    else       dst[i] = b2f(((const bf16*)src)[i]);
}

__global__ void k_cvt_params(const void* W1, const void* b1, const void* W2, const void* b2,
                             const void* W3, const void* b3, const void* W4, const void* b4,
                             const void* C2, const void* L1W, const void* L1b,
                             const void* L2W, const void* L2b, const void* L3W, const void* L3b,
                             float* dst, const int* flag) {
    int i = blockIdx.x * 256 + threadIdx.x;
    const void* p; int off;
    if      (i < 256)    { p = W1;  off = i; }
    else if (i < 288)    { p = b1;  off = i - 256; }
    else if (i < 4384)   { p = W2;  off = i - 288; }
    else if (i < 4512)   { p = b2;  off = i - 4384; }
    else if (i < 20896)  { p = W3;  off = i - 4512; }
    else if (i < 21024)  { p = b3;  off = i - 20896; }
    else if (i < 25120)  { p = W4;  off = i - 21024; }
    else if (i < 25152)  { p = b4;  off = i - 25120; }
    else if (i < 25156)  { p = C2;  off = i - 25152; }
    else if (i < 33860)  { p = L1W; off = i - 25156; }
    else if (i < 33988)  { p = L1b; off = i - 33860; }
    else if (i < 50372)  { p = L2W; off = i - 33988; }
    else if (i < 50500)  { p = L2b; off = i - 50372; }
    else if (i < 51780)  { p = L3W; off = i - 50500; }
    else if (i < 51790)  { p = L3b; off = i - 51780; }
    else return;
    if (*flag) dst[i] = ((const float*)p)[off];
    else       dst[i] = b2f(((const bf16*)p)[off]);
}

// ---------- transposed bf16 weights Wt[n][k] for MFMA B-fragments ----------
__global__ void k_wt(const float* Pc, short* Wt2, short* Wt3, short* Wt4) {
    int i = blockIdx.x * 256 + threadIdx.x;
    if (i < 4096) {                       // W2: [k=32][n=128] -> Wt2[n][k]
        int n = i >> 5, k = i & 31;
        Wt2[n * 32 + k] = (short)f2bu(Pc[288 + k * 128 + n]);
    } else if (i < 20480) {               // W3: [128][128] -> Wt3[n][k]
        int j = i - 4096; int n = j >> 7, k = j & 127;
        Wt3[n * 128 + k] = (short)f2bu(Pc[4512 + k * 128 + n]);
    } else if (i < 24576) {               // W4: [k=128][n=32] -> Wt4[n][k]
        int j = i - 20480; int n = j >> 7, k = j & 127;
        Wt4[n * 128 + k] = (short)f2bu(Pc[21024 + k * 32 + n]);
    }
}

// ---------- prep ----------
__global__ void k_init(int* counts, int* cursor, float* x0x1) {
    int i = blockIdx.x * 256 + threadIdx.x;
    if (i < NN) { counts[i] = 0; cursor[i] = 0; }
    if (i < 64) x0x1[i] = 0.0f;
}

__global__ void k_count(const int* dstI, int* counts) {
    int e = blockIdx.x * 256 + threadIdx.x;
    if (e >= NE) return;
    atomicAdd(&counts[dstI[e]], 1);
}

__global__ void k_scan1(const int* counts, int* row_off, int* blk) {
    __shared__ int sm[1024];
    int t = threadIdx.x;
    int i = blockIdx.x * 1024 + t;
    int v = (i < NN) ? counts[i] : 0;
    sm[t] = v;
    __syncthreads();
    for (int off = 1; off < 1024; off <<= 1) {
        int x = (t >= off) ? sm[t - off] : 0;
        __syncthreads();
        sm[t] += x;
        __syncthreads();
    }
    if (i < NN) row_off[i] = sm[t] - v;
    if (t == 1023) blk[blockIdx.x] = sm[t];
}

__global__ void k_scan2(int* blk) {
    if (threadIdx.x == 0 && blockIdx.x == 0) {
        int acc = 0;
        for (int i = 0; i < 98; i++) { int v = blk[i]; blk[i] = acc; acc += v; }
    }
}

__global__ void k_scan3(int* row_off, const int* blk) {
    int i = blockIdx.x * 256 + threadIdx.x;
    if (i < NN) row_off[i] += blk[i >> 10];
}

__global__ void k_fill(const int* srcI, const int* dstI, const float* ewf,
                       const int* row_off, int* cursor, int* srcs, float* normv) {
    int e = blockIdx.x * 256 + threadIdx.x;
    if (e >= NE) return;
    int d = dstI[e];
    int pos = row_off[d] + atomicAdd(&cursor[d], 1);
    srcs[pos] = srcI[e];
    normv[pos] = ewf[e];
}

__global__ void k_deg(const int* row_off, const int* counts, const float* normv, float* dinv) {
    int n = blockIdx.x * 256 + threadIdx.x;
    if (n >= NN) return;
    int st = row_off[n], len = counts[n];
    float s = 1.0f;
    for (int i = 0; i < len; i++) s += normv[st + i];
    dinv[n] = rsqrtf(s);
}

__global__ void k_norm(const int* row_off, const int* counts, const int* srcs,
                       const float* dinv, float* normv) {
    int n = blockIdx.x * 256 + threadIdx.x;
    if (n >= NN) return;
    float dn = dinv[n];
    int st = row_off[n], len = counts[n];
    for (int i = 0; i < len; i++) normv[st + i] *= dinv[srcs[st + i]] * dn;
}

// ---------- VALU GEMM (kept only for 8->32) ----------
template<int CIN, int COUT> struct GemmCfg {
    static constexpr int CG  = COUT / 4;
    static constexpr int NG  = 256 / CG;
    static constexpr int STR = CIN + 4;
    static constexpr int NPT = (NG * 8 * STR * 4 <= 36864) ? 8
                             : ((NG * 4 * STR * 4 <= 36864) ? 4 : 2);
    static constexpr int TN  = NG * NPT;
};

template<int CIN, int COUT, bool BIN, bool BOUT, int EPI>
__global__ __launch_bounds__(256) void k_gemm(const void* __restrict__ hin,
                                              const float* __restrict__ Wf,
                                              void* __restrict__ hW,
                                              const float* __restrict__ bias,
                                              float* xmax) {
    using C = GemmCfg<CIN, COUT>;
    __shared__ float xs[C::TN * C::STR];
    __shared__ int smax[(EPI == 2) ? COUT : 1];
    const int base = blockIdx.x * C::TN;
    const int t = threadIdx.x;
    constexpr int NF4 = C::TN * CIN / 4;
#pragma unroll
    for (int i = 0; i < NF4 / 256; i++) {
        int idx = t + 256 * i;
        int row = idx / (CIN / 4);
        int k4 = idx - row * (CIN / 4);
        int node = base + row;
        if (node >= NN) node = NN - 1;
        float4 v = ld4<BIN>(hin, (size_t)node * (CIN / 4) + k4);
        *(float4*)&xs[row * C::STR + 4 * k4] = v;
    }
    if (EPI == 2 && t < COUT) smax[t] = 0;
    __syncthreads();
    const int cg = t % C::CG, ng = t / C::CG;
    float4 acc[C::NPT];
#pragma unroll
    for (int i = 0; i < C::NPT; i++) acc[i] = make_float4(0.f, 0.f, 0.f, 0.f);
    const float4* wr = (const float4*)Wf;
#pragma unroll 2
    for (int k4 = 0; k4 < CIN / 4; k4++) {
        float4 w[4];
#pragma unroll
        for (int j = 0; j < 4; j++) w[j] = wr[(4 * k4 + j) * C::CG + cg];
#pragma unroll
        for (int i = 0; i < C::NPT; i++) {
            float4 xv = *(const float4*)&xs[(ng * C::NPT + i) * C::STR + 4 * k4];
            acc[i].x = fmaf(xv.x, w[0].x, acc[i].x);
            acc[i].y = fmaf(xv.x, w[0].y, acc[i].y);
            acc[i].z = fmaf(xv.x, w[0].z, acc[i].z);
            acc[i].w = fmaf(xv.x, w[0].w, acc[i].w);
            acc[i].x = fmaf(xv.y, w[1].x, acc[i].x);
            acc[i].y = fmaf(xv.y, w[1].y, acc[i].y);
            acc[i].z = fmaf(xv.y, w[1].z, acc[i].z);
            acc[i].w = fmaf(xv.y, w[1].w, acc[i].w);
            acc[i].x = fmaf(xv.z, w[2].x, acc[i].x);
            acc[i].y = fmaf(xv.z, w[2].y, acc[i].y);
            acc[i].z = fmaf(xv.z, w[2].z, acc[i].z);
            acc[i].w = fmaf(xv.z, w[2].w, acc[i].w);
            acc[i].x = fmaf(xv.w, w[3].x, acc[i].x);
            acc[i].y = fmaf(xv.w, w[3].y, acc[i].y);
            acc[i].z = fmaf(xv.w, w[3].z, acc[i].z);
            acc[i].w = fmaf(xv.w, w[3].w, acc[i].w);
        }
    }
    float4 bb;
    if (EPI >= 1) bb = ((const float4*)bias)[cg];
    float4 mx = make_float4(0.f, 0.f, 0.f, 0.f);
#pragma unroll
    for (int i = 0; i < C::NPT; i++) {
        int node = base + ng * C::NPT + i;
        if (EPI >= 1) {
            acc[i].x = fmaxf(acc[i].x + bb.x, 0.f);
            acc[i].y = fmaxf(acc[i].y + bb.y, 0.f);
            acc[i].z = fmaxf(acc[i].z + bb.z, 0.f);
            acc[i].w = fmaxf(acc[i].w + bb.w, 0.f);
        }
        if (EPI == 2) {
            mx.x = fmaxf(mx.x, acc[i].x); mx.y = fmaxf(mx.y, acc[i].y);
            mx.z = fmaxf(mx.z, acc[i].z); mx.w = fmaxf(mx.w, acc[i].w);
        }
        if (node < NN) st4<BOUT>(hW, (size_t)node * C::CG + cg, acc[i]);
    }
    if (EPI == 2) {
        atomicMax(&smax[cg * 4 + 0], __float_as_int(mx.x));
        atomicMax(&smax[cg * 4 + 1], __float_as_int(mx.y));
        atomicMax(&smax[cg * 4 + 2], __float_as_int(mx.z));
        atomicMax(&smax[cg * 4 + 3], __float_as_int(mx.w));
        __syncthreads();
        if (t < COUT) atomicMax((int*)&xmax[t], smax[t]);
    }
}

// ---------- MFMA GEMM: Out[node][n] = In[node][k] @ W[k][n], bf16 in/out, fp32 acc ----------
// Wt is W transposed: Wt[n][k], bf16. A-frag: A[m=lane&15][k=quad*8+j] (m120-verified).
// C/D: col=lane&15, row=quad*4+reg (m89-verified). EPI: 0 plain, 1 bias+relu.
template<int K, int NOUT, int EPI>
__global__ __launch_bounds__(256) void k_mgemm(const short* __restrict__ A,
                                               const short* __restrict__ Wt,
                                               unsigned short* __restrict__ Out,
                                               const float* __restrict__ bias) {
    constexpr int KS = K / 32;
    constexpr int NT = NOUT / 16;
    const int wave = threadIdx.x >> 6;
    const int lane = threadIdx.x & 63;
    const int m = lane & 15, quad = lane >> 4;
    const int base = blockIdx.x * 64 + wave * 16;
    int anode = base + m;
    if (anode >= NN) anode = NN - 1;
    s16x8 a[KS];
#pragma unroll
    for (int s = 0; s < KS; s++)
        a[s] = *(const s16x8*)(A + ((size_t)anode * K + s * 32 + quad * 8));
    f32x4 acc[NT];
#pragma unroll
    for (int t = 0; t < NT; t++) {
        acc[t] = (f32x4){0.f, 0.f, 0.f, 0.f};
#pragma unroll
        for (int s = 0; s < KS; s++) {
            s16x8 b = *(const s16x8*)(Wt + ((size_t)(t * 16 + m) * K + s * 32 + quad * 8));
            acc[t] = __builtin_amdgcn_mfma_f32_16x16x32_bf16(a[s], b, acc[t], 0, 0, 0);
        }
    }
    const int orow = base + quad * 4;
#pragma unroll
    for (int t = 0; t < NT; t++) {
        float bb = (EPI == 1) ? bias[t * 16 + m] : 0.f;
#pragma unroll
        for (int r = 0; r < 4; r++) {
            int nd = orow + r;
            if (nd < NN) {
                float v = acc[t][r];
                if (EPI == 1) v = fmaxf(v + bb, 0.f);
                Out[(size_t)nd * NOUT + t * 16 + m] = (unsigned short)f2bu(v);
            }
        }
    }
}

// ---------- fp32 aggregate for L1 (width 8) ----------
__global__ __launch_bounds__(256) void k_ag8(const float* __restrict__ hin,
        const float* __restrict__ dinv, const int* __restrict__ row_off,
        const int* __restrict__ counts, const int* __restrict__ srcs,
        const float* __restrict__ normv, float* __restrict__ outF) {
    int tid = blockIdx.x * 256 + threadIdx.x;
    int n = tid >> 1, g = tid & 1;
    if (n >= NN) return;
    float di = dinv[n];
    float d2 = di * di;
    const float4* h4 = (const float4*)hin;
    float4 s4 = h4[(size_t)n * 2 + g];
    float4 acc = make_float4(s4.x * d2, s4.y * d2, s4.z * d2, s4.w * d2);
    int start = row_off[n], len = counts[n];
    int i = 0;
    for (; i + 2 <= len; i += 2) {
        int s0 = srcs[start + i], s1 = srcs[start + i + 1];
        float w0 = normv[start + i], w1 = normv[start + i + 1];
        float4 v0 = h4[(size_t)s0 * 2 + g];
        float4 v1 = h4[(size_t)s1 * 2 + g];
        acc.x = fmaf(w0, v0.x, acc.x); acc.y = fmaf(w0, v0.y, acc.y);
        acc.z = fmaf(w0, v0.z, acc.z); acc.w = fmaf(w0, v0.w, acc.w);
        acc.x = fmaf(w1, v1.x, acc.x); acc.y = fmaf(w1, v1.y, acc.y);
        acc.z = fmaf(w1, v1.z, acc.z); acc.w = fmaf(w1, v1.w, acc.w);
    }
    if (i < len) {
        int s0 = srcs[start + i];
        float w0 = normv[start + i];
        float4 v0 = h4[(size_t)s0 * 2 + g];
        acc.x = fmaf(w0, v0.x, acc.x); acc.y = fmaf(w0, v0.y, acc.y);
        acc.z = fmaf(w0, v0.z, acc.z); acc.w = fmaf(w0, v0.w, acc.w);
    }
    ((float4*)outF)[(size_t)n * 2 + g] = acc;
}

// ---------- bf16 aggregate, 16B/lane (8 cols/thread) ----------
// EPI: 0 = store bf16; 1 = bias+relu+store bf16; 3 = bias+relu+colmax, NO store
template<int W, int EPI>
__global__ __launch_bounds__(256) void k_ag16(const uint4* __restrict__ hin,
        const float* __restrict__ dinv, const int* __restrict__ row_off,
        const int* __restrict__ counts, const int* __restrict__ srcs,
        const float* __restrict__ normv, const float* __restrict__ bias,
        uint4* __restrict__ outB, float* __restrict__ xmax) {
    constexpr int TPN = W / 8;
    __shared__ int smax[(EPI == 3) ? W : 1];
    int tid = blockIdx.x * 256 + threadIdx.x;
    int n = tid / TPN, c = tid % TPN;
    if (EPI == 3) {
        if (threadIdx.x < W) smax[threadIdx.x] = 0;
        __syncthreads();
    }
    float acc[8];
    bool valid = (n < NN);
    if (valid) {
        float di = dinv[n];
        float d2 = di * di;
        float a[8];
        up8(hin[(size_t)n * TPN + c], a);
#pragma unroll
        for (int j = 0; j < 8; j++) acc[j] = a[j] * d2;
        int start = row_off[n], len = counts[n];
        int i = 0;
        for (; i + 2 <= len; i += 2) {
            int s0 = srcs[start + i], s1 = srcs[start + i + 1];
            float w0 = normv[start + i], w1 = normv[start + i + 1];
            uint4 u0 = hin[(size_t)s0 * TPN + c];
            uint4 u1 = hin[(size_t)s1 * TPN + c];
            float a0[8], a1[8];
            up8(u0, a0); up8(u1, a1);
#pragma unroll
            for (int j = 0; j < 8; j++) acc[j] = fmaf(w0, a0[j], acc[j]);
#pragma unroll
            for (int j = 0; j < 8; j++) acc[j] = fmaf(w1, a1[j], acc[j]);
        }
        if (i < len) {
            int s0 = srcs[start + i];
            float w0 = normv[start + i];
            float a0[8];
            up8(hin[(size_t)s0 * TPN + c], a0);
#pragma unroll
            for (int j = 0; j < 8; j++) acc[j] = fmaf(w0, a0[j], acc[j]);
        }
        if (EPI >= 1) {
#pragma unroll
            for (int j = 0; j < 8; j++) acc[j] = fmaxf(acc[j] + bias[c * 8 + j], 0.f);
        }
        if (EPI != 3) {
            uint4 o;
            o.x = f2bu(acc[0]) | (f2bu(acc[1]) << 16);
            o.y = f2bu(acc[2]) | (f2bu(acc[3]) << 16);
            o.z = f2bu(acc[4]) | (f2bu(acc[5]) << 16);
            o.w = f2bu(acc[6]) | (f2bu(acc[7]) << 16);
            outB[(size_t)n * TPN + c] = o;
        } else {
#pragma unroll
            for (int j = 0; j < 8; j++) atomicMax(&smax[c * 8 + j], __float_as_int(acc[j]));
        }
    }
    if (EPI == 3) {
        __syncthreads();
        if (threadIdx.x < W) atomicMax((int*)&xmax[threadIdx.x], smax[threadIdx.x]);
    }
}

// ---------- head MLP + softmax + fp32 output ----------
__global__ void k_mlp(const float* x0x1, const float* Pc, float* out) {
    const float* C2  = Pc + 25152;
    const float* L1W = Pc + 25156;
    const float* L1b = Pc + 33860;
    const float* L2W = Pc + 33988;
    const float* L2b = Pc + 50372;
    const float* L3W = Pc + 50500;
    const float* L3b = Pc + 51780;
    __shared__ float code[68], z1[128], z2[128];
    int t = threadIdx.x;
    if (t < 64) code[t] = x0x1[t];
    else if (t < 68) code[t] = C2[t - 64];
    __syncthreads();
    float acc = L1b[t];
    for (int i = 0; i < 68; i++) acc = fmaf(code[i], L1W[i * 128 + t], acc);
    z1[t] = fmaxf(acc, 0.f);
    __syncthreads();
    acc = L2b[t];
    for (int i = 0; i < 128; i++) acc = fmaf(z1[i], L2W[i * 128 + t], acc);
    z2[t] = fmaxf(acc, 0.f);
    __syncthreads();
    if (t == 0) {
        float lg[10];
        for (int c = 0; c < 10; c++) {
            float a = L3b[c];
            for (int i = 0; i < 128; i++) a = fmaf(z2[i], L3W[i * 10 + c], a);
            lg[c] = a;
        }
        float m = lg[0];
        for (int c = 1; c < 10; c++) m = fmaxf(m, lg[c]);
        float s = 0.f;
        for (int c = 0; c < 10; c++) { lg[c] = __expf(lg[c] - m); s += lg[c]; }
        float inv = 1.f / s;
        for (int c = 0; c < 10; c++) out[c] = lg[c] * inv;
    }
    if (t < 68) out[10 + t] = code[t];
}

extern "C" void kernel_launch(void* const* d_in, const int* in_sizes, int n_in,
                              void* d_out, int out_size, void* d_ws, size_t ws_size,
                              hipStream_t stream) {
    const void* x    = d_in[0];
    const int*  ei   = (const int*)d_in[1];
    const void* ew   = d_in[2];
    const void* C2ER = d_in[4];
    float* out = (float*)d_out;
    (void)in_sizes; (void)n_in; (void)out_size; (void)ws_size;

    const size_t szF = (size_t)NN * 128 * 4;
    char* p = (char*)d_ws;
    char* H      = p;          p += szF;
    char* T      = p;          p += szF;
    float* xf    = (float*)p;  p += (size_t)NN * 8 * 4;
    float* ewf   = (float*)p;  p += (size_t)NE * 4;
    int*   srcs  = (int*)p;    p += (size_t)NE * 4;
    float* normv = (float*)p;  p += (size_t)NE * 4;
    float* dinv  = (float*)p;  p += (size_t)NN * 4;
    int*   counts= (int*)p;    p += (size_t)NN * 4;
    int*   rowoff= (int*)p;    p += (size_t)NN * 4;
    int*   cursor= (int*)p;    p += (size_t)NN * 4;
    int*   blk   = (int*)p;    p += 1024;
    float* x0x1  = (float*)p;  p += 256 * 4;
    float* Pc    = (float*)p;  p += 51792 * 4;
    int*   flag  = (int*)p;    p += 64;
    short* Wt2   = (short*)p;  p += 4096 * 2;
    short* Wt3   = (short*)p;  p += 16384 * 2;
    short* Wt4   = (short*)p;  p += 4096 * 2;

    const int* srcI = ei;
    const int* dstI = ei + NE;

    dim3 B(256);
    k_probe<<<dim3(1), B, 0, stream>>>(x, flag);
    k_cvt<<<dim3((NN * 8 + 255) / 256), B, 0, stream>>>(x, xf, NN * 8, flag);
    k_cvt<<<dim3((NE + 255) / 256), B, 0, stream>>>(ew, ewf, NE, flag);
    k_cvt_params<<<dim3((51790 + 255) / 256), B, 0, stream>>>(
        d_in[5], d_in[6], d_in[7], d_in[8], d_in[9], d_in[10], d_in[11], d_in[12],
        C2ER, d_in[13], d_in[14], d_in[15], d_in[16], d_in[17], d_in[18], Pc, flag);
    k_wt<<<dim3(96), B, 0, stream>>>(Pc, Wt2, Wt3, Wt4);

    k_init<<<dim3((NN + 255) / 256), B, 0, stream>>>(counts, cursor, x0x1);
    k_count<<<dim3((NE + 255) / 256), B, 0, stream>>>(dstI, counts);
    k_scan1<<<dim3(98), dim3(1024), 0, stream>>>(counts, rowoff, blk);
    k_scan2<<<dim3(1), dim3(64), 0, stream>>>(blk);
    k_scan3<<<dim3((NN + 255) / 256), B, 0, stream>>>(rowoff, blk);
    k_fill<<<dim3((NE + 255) / 256), B, 0, stream>>>(srcI, dstI, ewf, rowoff, cursor, srcs, normv);
    k_deg<<<dim3((NN + 255) / 256), B, 0, stream>>>(rowoff, counts, normv, dinv);
    k_norm<<<dim3((NN + 255) / 256), B, 0, stream>>>(rowoff, counts, srcs, dinv, normv);

    const float* W1f = Pc,        * b1f = Pc + 256;
    const float* b2f_ = Pc + 4384;
    const float* b3f_ = Pc + 20896;
    const float* b4f_ = Pc + 25120;

    constexpr int TN1 = GemmCfg<8, 32>::TN;
    const int MG = (NN + 63) / 64;   // 1563 blocks, 4 waves x 16 nodes

    // L1: agg xf @8 fp32 -> T1 fp32; VALU gemm 8->32 +bias+relu+max -> H1 bf16
    k_ag8<<<dim3((NN * 2 + 255) / 256), B, 0, stream>>>(xf, dinv, rowoff, counts, srcs, normv, (float*)T);
    k_gemm<8, 32, false, true, 2><<<dim3((NN + TN1 - 1) / TN1), B, 0, stream>>>(T, W1f, H, b1f, x0x1);
    // L2: agg H1 bf16 @32 -> T2 bf16; MFMA gemm 32->128 +bias+relu -> H2 bf16
    k_ag16<32, 0><<<dim3((NN * 4 + 255) / 256), B, 0, stream>>>(
        (const uint4*)H, dinv, rowoff, counts, srcs, normv, nullptr, (uint4*)T, nullptr);
    k_mgemm<32, 128, 1><<<dim3(MG), B, 0, stream>>>((const short*)T, Wt2, (unsigned short*)H, b2f_);
    // L3: MFMA gemm 128->128 -> T3 bf16; agg @128 +bias+relu -> H3 bf16
    k_mgemm<128, 128, 0><<<dim3(MG), B, 0, stream>>>((const short*)H, Wt3, (unsigned short*)T, nullptr);
    k_ag16<128, 1><<<dim3((NN * 16 + 255) / 256), B, 0, stream>>>(
        (const uint4*)T, dinv, rowoff, counts, srcs, normv, b3f_, (uint4*)H, nullptr);
    // L4: MFMA gemm 128->32 -> T4 bf16; agg @32 +bias+relu+max (no store)
    k_mgemm<128, 32, 0><<<dim3(MG), B, 0, stream>>>((const short*)H, Wt4, (unsigned short*)T, nullptr);
    k_ag16<32, 3><<<dim3((NN * 4 + 255) / 256), B, 0, stream>>>(
        (const uint4*)T, dinv, rowoff, counts, srcs, normv, b4f_, nullptr, x0x1 + 32);

    k_mlp<<<dim3(1), dim3(128), 0, stream>>>(x0x1, Pc, out);
}

// Round 10
// 339.038 us; speedup vs baseline: 1.9522x; 1.0385x over previous
//
#include <hip/hip_runtime.h>
#include <hip/hip_bf16.h>

#define NN 100000
#define NE 600000

using bf16 = __hip_bfloat16;
typedef float f32x4 __attribute__((ext_vector_type(4)));
typedef short s16x8 __attribute__((ext_vector_type(8)));

__device__ __forceinline__ float bu2f(unsigned int u16) {
    union { float f; unsigned int i; } c; c.i = u16 << 16; return c.f;
}
__device__ __forceinline__ unsigned int f2bu(float f) {
    bf16 h = __float2bfloat16(f);
    return (unsigned int)*reinterpret_cast<unsigned short*>(&h);
}
__device__ __forceinline__ float4 ld4bf(uint2 u) {
    float4 r;
    r.x = bu2f(u.x & 0xffffu); r.y = bu2f(u.x >> 16);
    r.z = bu2f(u.y & 0xffffu); r.w = bu2f(u.y >> 16);
    return r;
}
__device__ __forceinline__ uint2 st4bf(float4 a) {
    uint2 u;
    u.x = f2bu(a.x) | (f2bu(a.y) << 16);
    u.y = f2bu(a.z) | (f2bu(a.w) << 16);
    return u;
}
__device__ __forceinline__ void up8(uint4 u, float* a) {
    a[0] = bu2f(u.x & 0xffffu); a[1] = bu2f(u.x >> 16);
    a[2] = bu2f(u.y & 0xffffu); a[3] = bu2f(u.y >> 16);
    a[4] = bu2f(u.z & 0xffffu); a[5] = bu2f(u.z >> 16);
    a[6] = bu2f(u.w & 0xffffu); a[7] = bu2f(u.w >> 16);
}

// ---------- fused prep: zero counts/x0x1 + bf16 weight transposes ----------
__global__ void k_prep(int* counts, float* x0x1,
                       const float* W2, const float* W3, const float* W4,
                       short* Wt2, short* Wt3, short* Wt4) {
    int i = blockIdx.x * 256 + threadIdx.x;
    if (i < NN) counts[i] = 0;
    if (i < 64) x0x1[i] = 0.0f;
    if (i < 4096) {                       // W2: [k=32][n=128] -> Wt2[n][k]
        int n = i >> 5, k = i & 31;
        Wt2[n * 32 + k] = (short)f2bu(W2[k * 128 + n]);
    }
    if (i >= 4096 && i < 20480) {         // W3: [128][128] -> Wt3[n][k]
        int j = i - 4096; int n = j >> 7, k = j & 127;
        Wt3[n * 128 + k] = (short)f2bu(W3[k * 128 + n]);
    }
    if (i >= 20480 && i < 24576) {        // W4: [k=128][n=32] -> Wt4[n][k]
        int j = i - 20480; int n = j >> 7, k = j & 127;
        Wt4[n * 128 + k] = (short)f2bu(W4[k * 32 + n]);
    }
}

__global__ void k_count(const int* dstI, int* counts) {
    int e = blockIdx.x * 256 + threadIdx.x;
    if (e >= NE) return;
    atomicAdd(&counts[dstI[e]], 1);
}

__global__ void k_scan1(const int* counts, int* row_off, int* blk) {
    __shared__ int sm[1024];
    int t = threadIdx.x;
    int i = blockIdx.x * 1024 + t;
    int v = (i < NN) ? counts[i] : 0;
    sm[t] = v;
    __syncthreads();
    for (int off = 1; off < 1024; off <<= 1) {
        int x = (t >= off) ? sm[t - off] : 0;
        __syncthreads();
        sm[t] += x;
        __syncthreads();
    }
    if (i < NN) row_off[i] = sm[t] - v;
    if (t == 1023) blk[blockIdx.x] = sm[t];
}

__global__ void k_scan2(int* blk) {
    if (threadIdx.x == 0 && blockIdx.x == 0) {
        int acc = 0;
        for (int i = 0; i < 98; i++) { int v = blk[i]; blk[i] = acc; acc += v; }
    }
}

// finalize row_off and seed cursor = row_off
__global__ void k_scan3(int* row_off, const int* blk, int* cursor) {
    int i = blockIdx.x * 256 + threadIdx.x;
    if (i < NN) {
        int v = row_off[i] + blk[i >> 10];
        row_off[i] = v;
        cursor[i] = v;
    }
}

// CSR fill: single packed 8B record per edge
__global__ void k_fill(const int* srcI, const int* dstI, const float* ew,
                       int* cursor, uint2* edges) {
    int e = blockIdx.x * 256 + threadIdx.x;
    if (e >= NE) return;
    int d = dstI[e];
    int pos = atomicAdd(&cursor[d], 1);
    edges[pos] = make_uint2((unsigned)srcI[e], __float_as_uint(ew[e]));
}

__global__ void k_deg(const int* row_off, const int* counts, const uint2* edges, float* dinv) {
    int n = blockIdx.x * 256 + threadIdx.x;
    if (n >= NN) return;
    int st = row_off[n], len = counts[n];
    float s = 1.0f;
    for (int i = 0; i < len; i++) s += __uint_as_float(edges[st + i].y);
    dinv[n] = rsqrtf(s);
}

__global__ void k_norm(const int* row_off, const int* counts, const float* dinv, uint2* edges) {
    int n = blockIdx.x * 256 + threadIdx.x;
    if (n >= NN) return;
    float dn = dinv[n];
    int st = row_off[n], len = counts[n];
    float* wf = (float*)edges;
    for (int i = 0; i < len; i++) {
        uint2 e = edges[st + i];
        wf[2 * (st + i) + 1] = __uint_as_float(e.y) * dinv[e.x] * dn;
    }
}

// ---------- VALU GEMM (8->32 only): fp32 in, bf16 out, bias+relu+colmax ----------
__global__ __launch_bounds__(256) void k_gemm8(const float* __restrict__ hin,
                                               const float* __restrict__ Wf,
                                               unsigned int* __restrict__ hW,
                                               const float* __restrict__ bias,
                                               float* xmax) {
    // CG=8 col-groups, NG=32 node-groups, NPT=8 -> TN=256 nodes/block
    __shared__ float xs[256 * 12];
    __shared__ int smax[32];
    const int base = blockIdx.x * 256;
    const int t = threadIdx.x;
#pragma unroll
    for (int i = 0; i < 2; i++) {
        int idx = t + 256 * i;
        int row = idx >> 1, k4 = idx & 1;
        int node = base + row;
        if (node >= NN) node = NN - 1;
        float4 v = ((const float4*)hin)[(size_t)node * 2 + k4];
        *(float4*)&xs[row * 12 + 4 * k4] = v;
    }
    if (t < 32) smax[t] = 0;
    __syncthreads();
    const int cg = t & 7, ng = t >> 3;
    float4 acc[8];
#pragma unroll
    for (int i = 0; i < 8; i++) acc[i] = make_float4(0.f, 0.f, 0.f, 0.f);
    const float4* wr = (const float4*)Wf;
#pragma unroll
    for (int k = 0; k < 8; k++) {
        float4 w = wr[k * 8 + cg];
#pragma unroll
        for (int i = 0; i < 8; i++) {
            float xv = xs[(ng * 8 + i) * 12 + k];
            acc[i].x = fmaf(xv, w.x, acc[i].x);
            acc[i].y = fmaf(xv, w.y, acc[i].y);
            acc[i].z = fmaf(xv, w.z, acc[i].z);
            acc[i].w = fmaf(xv, w.w, acc[i].w);
        }
    }
    float4 bb = ((const float4*)bias)[cg];
    float4 mx = make_float4(0.f, 0.f, 0.f, 0.f);
#pragma unroll
    for (int i = 0; i < 8; i++) {
        int node = base + ng * 8 + i;
        acc[i].x = fmaxf(acc[i].x + bb.x, 0.f);
        acc[i].y = fmaxf(acc[i].y + bb.y, 0.f);
        acc[i].z = fmaxf(acc[i].z + bb.z, 0.f);
        acc[i].w = fmaxf(acc[i].w + bb.w, 0.f);
        mx.x = fmaxf(mx.x, acc[i].x); mx.y = fmaxf(mx.y, acc[i].y);
        mx.z = fmaxf(mx.z, acc[i].z); mx.w = fmaxf(mx.w, acc[i].w);
        if (node < NN) ((uint2*)hW)[(size_t)node * 8 + cg] = st4bf(acc[i]);
    }
    atomicMax(&smax[cg * 4 + 0], __float_as_int(mx.x));
    atomicMax(&smax[cg * 4 + 1], __float_as_int(mx.y));
    atomicMax(&smax[cg * 4 + 2], __float_as_int(mx.z));
    atomicMax(&smax[cg * 4 + 3], __float_as_int(mx.w));
    __syncthreads();
    if (t < 32) atomicMax((int*)&xmax[t], smax[t]);
}

// ---------- MFMA GEMM: Out[node][n] = In[node][k] @ W[k][n], bf16 in/out ----------
template<int K, int NOUT, int EPI>
__global__ __launch_bounds__(256) void k_mgemm(const short* __restrict__ A,
                                               const short* __restrict__ Wt,
                                               unsigned short* __restrict__ Out,
                                               const float* __restrict__ bias) {
    constexpr int KS = K / 32;
    constexpr int NT = NOUT / 16;
    const int wave = threadIdx.x >> 6;
    const int lane = threadIdx.x & 63;
    const int m = lane & 15, quad = lane >> 4;
    const int base = blockIdx.x * 64 + wave * 16;
    int anode = base + m;
    if (anode >= NN) anode = NN - 1;
    s16x8 a[KS];
#pragma unroll
    for (int s = 0; s < KS; s++)
        a[s] = *(const s16x8*)(A + ((size_t)anode * K + s * 32 + quad * 8));
    f32x4 acc[NT];
#pragma unroll
    for (int t = 0; t < NT; t++) {
        acc[t] = (f32x4){0.f, 0.f, 0.f, 0.f};
#pragma unroll
        for (int s = 0; s < KS; s++) {
            s16x8 b = *(const s16x8*)(Wt + ((size_t)(t * 16 + m) * K + s * 32 + quad * 8));
            acc[t] = __builtin_amdgcn_mfma_f32_16x16x32_bf16(a[s], b, acc[t], 0, 0, 0);
        }
    }
    const int orow = base + quad * 4;
#pragma unroll
    for (int t = 0; t < NT; t++) {
        float bb = (EPI == 1) ? bias[t * 16 + m] : 0.f;
#pragma unroll
        for (int r = 0; r < 4; r++) {
            int nd = orow + r;
            if (nd < NN) {
                float v = acc[t][r];
                if (EPI == 1) v = fmaxf(v + bb, 0.f);
                Out[(size_t)nd * NOUT + t * 16 + m] = (unsigned short)f2bu(v);
            }
        }
    }
}

// ---------- fp32 aggregate for L1 (width 8, reads x directly) ----------
__global__ __launch_bounds__(256) void k_ag8(const float* __restrict__ hin,
        const float* __restrict__ dinv, const int* __restrict__ row_off,
        const int* __restrict__ counts, const uint2* __restrict__ edges,
        float* __restrict__ outF) {
    int tid = blockIdx.x * 256 + threadIdx.x;
    int n = tid >> 1, g = tid & 1;
    if (n >= NN) return;
    float di = dinv[n];
    float d2 = di * di;
    const float4* h4 = (const float4*)hin;
    float4 s4 = h4[(size_t)n * 2 + g];
    float4 acc = make_float4(s4.x * d2, s4.y * d2, s4.z * d2, s4.w * d2);
    int start = row_off[n], len = counts[n];
    int i = 0;
    for (; i + 2 <= len; i += 2) {
        uint2 e0 = edges[start + i], e1 = edges[start + i + 1];
        float w0 = __uint_as_float(e0.y), w1 = __uint_as_float(e1.y);
        float4 v0 = h4[(size_t)e0.x * 2 + g];
        float4 v1 = h4[(size_t)e1.x * 2 + g];
        acc.x = fmaf(w0, v0.x, acc.x); acc.y = fmaf(w0, v0.y, acc.y);
        acc.z = fmaf(w0, v0.z, acc.z); acc.w = fmaf(w0, v0.w, acc.w);
        acc.x = fmaf(w1, v1.x, acc.x); acc.y = fmaf(w1, v1.y, acc.y);
        acc.z = fmaf(w1, v1.z, acc.z); acc.w = fmaf(w1, v1.w, acc.w);
    }
    if (i < len) {
        uint2 e0 = edges[start + i];
        float w0 = __uint_as_float(e0.y);
        float4 v0 = h4[(size_t)e0.x * 2 + g];
        acc.x = fmaf(w0, v0.x, acc.x); acc.y = fmaf(w0, v0.y, acc.y);
        acc.z = fmaf(w0, v0.z, acc.z); acc.w = fmaf(w0, v0.w, acc.w);
    }
    ((float4*)outF)[(size_t)n * 2 + g] = acc;
}

// ---------- bf16 aggregate, 16B/lane ----------
// EPI: 0 = store bf16; 1 = bias+relu+store bf16; 3 = bias+relu+colmax, NO store
template<int W, int EPI>
__global__ __launch_bounds__(256) void k_ag16(const uint4* __restrict__ hin,
        const float* __restrict__ dinv, const int* __restrict__ row_off,
        const int* __restrict__ counts, const uint2* __restrict__ edges,
        const float* __restrict__ bias, uint4* __restrict__ outB,
        float* __restrict__ xmax) {
    constexpr int TPN = W / 8;
    __shared__ int smax[(EPI == 3) ? W : 1];
    int tid = blockIdx.x * 256 + threadIdx.x;
    int n = tid / TPN, c = tid % TPN;
    if (EPI == 3) {
        if (threadIdx.x < W) smax[threadIdx.x] = 0;
        __syncthreads();
    }
    float acc[8];
    bool valid = (n < NN);
    if (valid) {
        float di = dinv[n];
        float d2 = di * di;
        float a[8];
        up8(hin[(size_t)n * TPN + c], a);
#pragma unroll
        for (int j = 0; j < 8; j++) acc[j] = a[j] * d2;
        int start = row_off[n], len = counts[n];
        int i = 0;
        for (; i + 2 <= len; i += 2) {
            uint2 e0 = edges[start + i], e1 = edges[start + i + 1];
            float w0 = __uint_as_float(e0.y), w1 = __uint_as_float(e1.y);
            uint4 u0 = hin[(size_t)e0.x * TPN + c];
            uint4 u1 = hin[(size_t)e1.x * TPN + c];
            float a0[8], a1[8];
            up8(u0, a0); up8(u1, a1);
#pragma unroll
            for (int j = 0; j < 8; j++) acc[j] = fmaf(w0, a0[j], acc[j]);
#pragma unroll
            for (int j = 0; j < 8; j++) acc[j] = fmaf(w1, a1[j], acc[j]);
        }
        if (i < len) {
            uint2 e0 = edges[start + i];
            float w0 = __uint_as_float(e0.y);
            float a0[8];
            up8(hin[(size_t)e0.x * TPN + c], a0);
#pragma unroll
            for (int j = 0; j < 8; j++) acc[j] = fmaf(w0, a0[j], acc[j]);
        }
        if (EPI >= 1) {
#pragma unroll
            for (int j = 0; j < 8; j++) acc[j] = fmaxf(acc[j] + bias[c * 8 + j], 0.f);
        }
        if (EPI != 3) {
            uint4 o;
            o.x = f2bu(acc[0]) | (f2bu(acc[1]) << 16);
            o.y = f2bu(acc[2]) | (f2bu(acc[3]) << 16);
            o.z = f2bu(acc[4]) | (f2bu(acc[5]) << 16);
            o.w = f2bu(acc[6]) | (f2bu(acc[7]) << 16);
            outB[(size_t)n * TPN + c] = o;
        } else {
#pragma unroll
            for (int j = 0; j < 8; j++) atomicMax(&smax[c * 8 + j], __float_as_int(acc[j]));
        }
    }
    if (EPI == 3) {
        __syncthreads();
        if (threadIdx.x < W) atomicMax((int*)&xmax[threadIdx.x], smax[threadIdx.x]);
    }
}

// ---------- head MLP + softmax + fp32 output ----------
__global__ void k_mlp(const float* x0x1, const float* C2,
                      const float* L1W, const float* L1b,
                      const float* L2W, const float* L2b,
                      const float* L3W, const float* L3b, float* out) {
    __shared__ float code[68], z1[128], z2[128];
    int t = threadIdx.x;
    if (t < 64) code[t] = x0x1[t];
    else if (t < 68) code[t] = C2[t - 64];
    __syncthreads();
    float acc = L1b[t];
    for (int i = 0; i < 68; i++) acc = fmaf(code[i], L1W[i * 128 + t], acc);
    z1[t] = fmaxf(acc, 0.f);
    __syncthreads();
    acc = L2b[t];
    for (int i = 0; i < 128; i++) acc = fmaf(z1[i], L2W[i * 128 + t], acc);
    z2[t] = fmaxf(acc, 0.f);
    __syncthreads();
    if (t == 0) {
        float lg[10];
        for (int c = 0; c < 10; c++) {
            float a = L3b[c];
            for (int i = 0; i < 128; i++) a = fmaf(z2[i], L3W[i * 10 + c], a);
            lg[c] = a;
        }
        float m = lg[0];
        for (int c = 1; c < 10; c++) m = fmaxf(m, lg[c]);
        float s = 0.f;
        for (int c = 0; c < 10; c++) { lg[c] = __expf(lg[c] - m); s += lg[c]; }
        float inv = 1.f / s;
        for (int c = 0; c < 10; c++) out[c] = lg[c] * inv;
    }
    if (t < 68) out[10 + t] = code[t];
}

extern "C" void kernel_launch(void* const* d_in, const int* in_sizes, int n_in,
                              void* d_out, int out_size, void* d_ws, size_t ws_size,
                              hipStream_t stream) {
    const float* x   = (const float*)d_in[0];
    const int*   ei  = (const int*)d_in[1];
    const float* ew  = (const float*)d_in[2];
    const float* C2  = (const float*)d_in[4];
    const float* W1  = (const float*)d_in[5],  * b1 = (const float*)d_in[6];
    const float* W2  = (const float*)d_in[7],  * b2 = (const float*)d_in[8];
    const float* W3  = (const float*)d_in[9],  * b3 = (const float*)d_in[10];
    const float* W4  = (const float*)d_in[11], * b4 = (const float*)d_in[12];
    const float* L1W = (const float*)d_in[13], * L1b = (const float*)d_in[14];
    const float* L2W = (const float*)d_in[15], * L2b = (const float*)d_in[16];
    const float* L3W = (const float*)d_in[17], * L3b = (const float*)d_in[18];
    float* out = (float*)d_out;
    (void)in_sizes; (void)n_in; (void)out_size; (void)ws_size;

    const size_t szF = (size_t)NN * 128 * 4;
    char* p = (char*)d_ws;
    char* H      = p;          p += szF;
    char* T      = p;          p += szF;
    uint2* edges = (uint2*)p;  p += (size_t)NE * 8;
    float* dinv  = (float*)p;  p += (size_t)NN * 4;
    int*   counts= (int*)p;    p += (size_t)NN * 4;
    int*   rowoff= (int*)p;    p += (size_t)NN * 4;
    int*   cursor= (int*)p;    p += (size_t)NN * 4;
    int*   blk   = (int*)p;    p += 1024;
    float* x0x1  = (float*)p;  p += 256 * 4;
    short* Wt2   = (short*)p;  p += 4096 * 2;
    short* Wt3   = (short*)p;  p += 16384 * 2;
    short* Wt4   = (short*)p;  p += 4096 * 2;

    const int* srcI = ei;
    const int* dstI = ei + NE;

    dim3 B(256);
    k_prep<<<dim3((NN + 255) / 256), B, 0, stream>>>(counts, x0x1, W2, W3, W4, Wt2, Wt3, Wt4);
    k_count<<<dim3((NE + 255) / 256), B, 0, stream>>>(dstI, counts);
    k_scan1<<<dim3(98), dim3(1024), 0, stream>>>(counts, rowoff, blk);
    k_scan2<<<dim3(1), dim3(64), 0, stream>>>(blk);
    k_scan3<<<dim3((NN + 255) / 256), B, 0, stream>>>(rowoff, blk, cursor);
    k_fill<<<dim3((NE + 255) / 256), B, 0, stream>>>(srcI, dstI, ew, cursor, edges);
    k_deg<<<dim3((NN + 255) / 256), B, 0, stream>>>(rowoff, counts, edges, dinv);
    k_norm<<<dim3((NN + 255) / 256), B, 0, stream>>>(rowoff, counts, dinv, edges);

    const int MG = (NN + 63) / 64;

    // L1: agg x @8 fp32 -> T fp32; VALU gemm 8->32 +bias+relu+max -> H bf16
    k_ag8<<<dim3((NN * 2 + 255) / 256), B, 0, stream>>>(x, dinv, rowoff, counts, edges, (float*)T);
    k_gemm8<<<dim3((NN + 255) / 256), B, 0, stream>>>((const float*)T, W1, (unsigned int*)H, b1, x0x1);
    // L2: agg H bf16 @32 -> T bf16; MFMA 32->128 +bias+relu -> H bf16
    k_ag16<32, 0><<<dim3((NN * 4 + 255) / 256), B, 0, stream>>>(
        (const uint4*)H, dinv, rowoff, counts, edges, nullptr, (uint4*)T, nullptr);
    k_mgemm<32, 128, 1><<<dim3(MG), B, 0, stream>>>((const short*)T, Wt2, (unsigned short*)H, b2);
    // L3: MFMA 128->128 -> T bf16; agg @128 +bias+relu -> H bf16
    k_mgemm<128, 128, 0><<<dim3(MG), B, 0, stream>>>((const short*)H, Wt3, (unsigned short*)T, nullptr);
    k_ag16<128, 1><<<dim3((NN * 16 + 255) / 256), B, 0, stream>>>(
        (const uint4*)T, dinv, rowoff, counts, edges, b3, (uint4*)H, nullptr);
    // L4: MFMA 128->32 -> T bf16; agg @32 +bias+relu+max (no store)
    k_mgemm<128, 32, 0><<<dim3(MG), B, 0, stream>>>((const short*)H, Wt4, (unsigned short*)T, nullptr);
    k_ag16<32, 3><<<dim3((NN * 4 + 255) / 256), B, 0, stream>>>(
        (const uint4*)T, dinv, rowoff, counts, edges, b4, nullptr, x0x1 + 32);

    k_mlp<<<dim3(1), dim3(128), 0, stream>>>(x0x1, C2, L1W, L1b, L2W, L2b, L3W, L3b, out);
}

// Round 11
// 338.684 us; speedup vs baseline: 1.9542x; 1.0010x over previous
//
#include <hip/hip_runtime.h>
#include <hip/hip_bf16.h>

#define NN 100000
#define NE 600000

using bf16 = __hip_bfloat16;
typedef float f32x4 __attribute__((ext_vector_type(4)));
typedef short s16x8 __attribute__((ext_vector_type(8)));

__device__ __forceinline__ float bu2f(unsigned int u16) {
    union { float f; unsigned int i; } c; c.i = u16 << 16; return c.f;
}
__device__ __forceinline__ unsigned int f2bu(float f) {
    bf16 h = __float2bfloat16(f);
    return (unsigned int)*reinterpret_cast<unsigned short*>(&h);
}
__device__ __forceinline__ uint2 st4bf(float4 a) {
    uint2 u;
    u.x = f2bu(a.x) | (f2bu(a.y) << 16);
    u.y = f2bu(a.z) | (f2bu(a.w) << 16);
    return u;
}
__device__ __forceinline__ void up8(uint4 u, float* a) {
    a[0] = bu2f(u.x & 0xffffu); a[1] = bu2f(u.x >> 16);
    a[2] = bu2f(u.y & 0xffffu); a[3] = bu2f(u.y >> 16);
    a[4] = bu2f(u.z & 0xffffu); a[5] = bu2f(u.z >> 16);
    a[6] = bu2f(u.w & 0xffffu); a[7] = bu2f(u.w >> 16);
}

// ---------- fused prep: zero counts8/x0x1 + bf16 weight transposes ----------
__global__ void k_prep(int* counts8, float* x0x1,
                       const float* W2, const float* W3, const float* W4,
                       short* Wt2, short* Wt3, short* Wt4) {
    int i = blockIdx.x * 256 + threadIdx.x;
    if (i < NN) {
#pragma unroll
        for (int g = 0; g < 8; g++) counts8[g * NN + i] = 0;
    }
    if (i < 64) x0x1[i] = 0.0f;
    if (i < 4096) {                       // W2: [k=32][n=128] -> Wt2[n][k]
        int n = i >> 5, k = i & 31;
        Wt2[n * 32 + k] = (short)f2bu(W2[k * 128 + n]);
    }
    if (i >= 4096 && i < 20480) {         // W3: [128][128] -> Wt3[n][k]
        int j = i - 4096; int n = j >> 7, k = j & 127;
        Wt3[n * 128 + k] = (short)f2bu(W3[k * 128 + n]);
    }
    if (i >= 20480 && i < 24576) {        // W4: [k=128][n=32] -> Wt4[n][k]
        int j = i - 20480; int n = j >> 7, k = j & 127;
        Wt4[n * 128 + k] = (short)f2bu(W4[k * 32 + n]);
    }
}

// XCD-bucketed count: bucket g = blockIdx&7 (== XCD under round-robin dispatch).
// Atomic lines of bucket g touched only by XCD g -> no cross-XCD L2 ping-pong.
__global__ void k_count(const int* dstI, int* counts8) {
    int e = blockIdx.x * 256 + threadIdx.x;
    if (e >= NE) return;
    int g = blockIdx.x & 7;
    atomicAdd(&counts8[g * NN + dstI[e]], 1);
}

__global__ void k_scan1(const int* counts8, int* counts_tot, int* row_off, int* blk) {
    __shared__ int sm[1024];
    int t = threadIdx.x;
    int i = blockIdx.x * 1024 + t;
    int v = 0;
    if (i < NN) {
#pragma unroll
        for (int g = 0; g < 8; g++) v += counts8[g * NN + i];
        counts_tot[i] = v;
    }
    sm[t] = v;
    __syncthreads();
    for (int off = 1; off < 1024; off <<= 1) {
        int x = (t >= off) ? sm[t - off] : 0;
        __syncthreads();
        sm[t] += x;
        __syncthreads();
    }
    if (i < NN) row_off[i] = sm[t] - v;
    if (t == 1023) blk[blockIdx.x] = sm[t];
}

__global__ void k_scan2(int* blk) {
    if (threadIdx.x == 0 && blockIdx.x == 0) {
        int acc = 0;
        for (int i = 0; i < 98; i++) { int v = blk[i]; blk[i] = acc; acc += v; }
    }
}

// finalize row_off; per-(bucket,node) fill cursors cur8 = segmented sub-offsets
__global__ void k_scan3(int* row_off, const int* blk, const int* counts8, int* cur8) {
    int i = blockIdx.x * 256 + threadIdx.x;
    if (i >= NN) return;
    int base = row_off[i] + blk[i >> 10];
    row_off[i] = base;
#pragma unroll
    for (int g = 0; g < 8; g++) {
        cur8[g * NN + i] = base;
        base += counts8[g * NN + i];
    }
}

// CSR fill: packed 8B record; cursor + record region private to pseudo-XCD g
__global__ void k_fill(const int* srcI, const int* dstI, const float* ew,
                       int* cur8, uint2* edges) {
    int e = blockIdx.x * 256 + threadIdx.x;
    if (e >= NE) return;
    int g = blockIdx.x & 7;
    int pos = atomicAdd(&cur8[g * NN + dstI[e]], 1);
    edges[pos] = make_uint2((unsigned)srcI[e], __float_as_uint(ew[e]));
}

__global__ void k_deg(const int* row_off, const int* counts, const uint2* edges, float* dinv) {
    int n = blockIdx.x * 256 + threadIdx.x;
    if (n >= NN) return;
    int st = row_off[n], len = counts[n];
    float s = 1.0f;
    for (int i = 0; i < len; i++) s += __uint_as_float(edges[st + i].y);
    dinv[n] = rsqrtf(s);
}

__global__ void k_norm(const int* row_off, const int* counts, const float* dinv, uint2* edges) {
    int n = blockIdx.x * 256 + threadIdx.x;
    if (n >= NN) return;
    float dn = dinv[n];
    int st = row_off[n], len = counts[n];
    float* wf = (float*)edges;
    for (int i = 0; i < len; i++) {
        uint2 e = edges[st + i];
        wf[2 * (st + i) + 1] = __uint_as_float(e.y) * dinv[e.x] * dn;
    }
}

// ---------- VALU GEMM (8->32): fp32 in, bf16 out, bias+relu+colmax ----------
__global__ __launch_bounds__(256) void k_gemm8(const float* __restrict__ hin,
                                               const float* __restrict__ Wf,
                                               unsigned int* __restrict__ hW,
                                               const float* __restrict__ bias,
                                               float* xmax) {
    __shared__ float xs[256 * 12];
    __shared__ int smax[32];
    const int base = blockIdx.x * 256;
    const int t = threadIdx.x;
#pragma unroll
    for (int i = 0; i < 2; i++) {
        int idx = t + 256 * i;
        int row = idx >> 1, k4 = idx & 1;
        int node = base + row;
        if (node >= NN) node = NN - 1;
        float4 v = ((const float4*)hin)[(size_t)node * 2 + k4];
        *(float4*)&xs[row * 12 + 4 * k4] = v;
    }
    if (t < 32) smax[t] = 0;
    __syncthreads();
    const int cg = t & 7, ng = t >> 3;
    float4 acc[8];
#pragma unroll
    for (int i = 0; i < 8; i++) acc[i] = make_float4(0.f, 0.f, 0.f, 0.f);
    const float4* wr = (const float4*)Wf;
#pragma unroll
    for (int k = 0; k < 8; k++) {
        float4 w = wr[k * 8 + cg];
#pragma unroll
        for (int i = 0; i < 8; i++) {
            float xv = xs[(ng * 8 + i) * 12 + k];
            acc[i].x = fmaf(xv, w.x, acc[i].x);
            acc[i].y = fmaf(xv, w.y, acc[i].y);
            acc[i].z = fmaf(xv, w.z, acc[i].z);
            acc[i].w = fmaf(xv, w.w, acc[i].w);
        }
    }
    float4 bb = ((const float4*)bias)[cg];
    float4 mx = make_float4(0.f, 0.f, 0.f, 0.f);
#pragma unroll
    for (int i = 0; i < 8; i++) {
        int node = base + ng * 8 + i;
        acc[i].x = fmaxf(acc[i].x + bb.x, 0.f);
        acc[i].y = fmaxf(acc[i].y + bb.y, 0.f);
        acc[i].z = fmaxf(acc[i].z + bb.z, 0.f);
        acc[i].w = fmaxf(acc[i].w + bb.w, 0.f);
        mx.x = fmaxf(mx.x, acc[i].x); mx.y = fmaxf(mx.y, acc[i].y);
        mx.z = fmaxf(mx.z, acc[i].z); mx.w = fmaxf(mx.w, acc[i].w);
        if (node < NN) ((uint2*)hW)[(size_t)node * 8 + cg] = st4bf(acc[i]);
    }
    atomicMax(&smax[cg * 4 + 0], __float_as_int(mx.x));
    atomicMax(&smax[cg * 4 + 1], __float_as_int(mx.y));
    atomicMax(&smax[cg * 4 + 2], __float_as_int(mx.z));
    atomicMax(&smax[cg * 4 + 3], __float_as_int(mx.w));
    __syncthreads();
    if (t < 32) atomicMax((int*)&xmax[t], smax[t]);
}

// ---------- MFMA GEMM: Out[node][n] = In[node][k] @ W[k][n], bf16 in/out ----------
template<int K, int NOUT, int EPI>
__global__ __launch_bounds__(256) void k_mgemm(const short* __restrict__ A,
                                               const short* __restrict__ Wt,
                                               unsigned short* __restrict__ Out,
                                               const float* __restrict__ bias) {
    constexpr int KS = K / 32;
    constexpr int NT = NOUT / 16;
    const int wave = threadIdx.x >> 6;
    const int lane = threadIdx.x & 63;
    const int m = lane & 15, quad = lane >> 4;
    const int base = blockIdx.x * 64 + wave * 16;
    int anode = base + m;
    if (anode >= NN) anode = NN - 1;
    s16x8 a[KS];
#pragma unroll
    for (int s = 0; s < KS; s++)
        a[s] = *(const s16x8*)(A + ((size_t)anode * K + s * 32 + quad * 8));
    f32x4 acc[NT];
#pragma unroll
    for (int t = 0; t < NT; t++) {
        acc[t] = (f32x4){0.f, 0.f, 0.f, 0.f};
#pragma unroll
        for (int s = 0; s < KS; s++) {
            s16x8 b = *(const s16x8*)(Wt + ((size_t)(t * 16 + m) * K + s * 32 + quad * 8));
            acc[t] = __builtin_amdgcn_mfma_f32_16x16x32_bf16(a[s], b, acc[t], 0, 0, 0);
        }
    }
    const int orow = base + quad * 4;
#pragma unroll
    for (int t = 0; t < NT; t++) {
        float bb = (EPI == 1) ? bias[t * 16 + m] : 0.f;
#pragma unroll
        for (int r = 0; r < 4; r++) {
            int nd = orow + r;
            if (nd < NN) {
                float v = acc[t][r];
                if (EPI == 1) v = fmaxf(v + bb, 0.f);
                Out[(size_t)nd * NOUT + t * 16 + m] = (unsigned short)f2bu(v);
            }
        }
    }
}

// ---------- fp32 aggregate for L1 (width 8, reads x directly) ----------
__global__ __launch_bounds__(256) void k_ag8(const float* __restrict__ hin,
        const float* __restrict__ dinv, const int* __restrict__ row_off,
        const int* __restrict__ counts, const uint2* __restrict__ edges,
        float* __restrict__ outF) {
    int tid = blockIdx.x * 256 + threadIdx.x;
    int n = tid >> 1, g = tid & 1;
    if (n >= NN) return;
    float di = dinv[n];
    float d2 = di * di;
    const float4* h4 = (const float4*)hin;
    float4 s4 = h4[(size_t)n * 2 + g];
    float4 acc = make_float4(s4.x * d2, s4.y * d2, s4.z * d2, s4.w * d2);
    int start = row_off[n], len = counts[n];
    int i = 0;
    for (; i + 2 <= len; i += 2) {
        uint2 e0 = edges[start + i], e1 = edges[start + i + 1];
        float w0 = __uint_as_float(e0.y), w1 = __uint_as_float(e1.y);
        float4 v0 = h4[(size_t)e0.x * 2 + g];
        float4 v1 = h4[(size_t)e1.x * 2 + g];
        acc.x = fmaf(w0, v0.x, acc.x); acc.y = fmaf(w0, v0.y, acc.y);
        acc.z = fmaf(w0, v0.z, acc.z); acc.w = fmaf(w0, v0.w, acc.w);
        acc.x = fmaf(w1, v1.x, acc.x); acc.y = fmaf(w1, v1.y, acc.y);
        acc.z = fmaf(w1, v1.z, acc.z); acc.w = fmaf(w1, v1.w, acc.w);
    }
    if (i < len) {
        uint2 e0 = edges[start + i];
        float w0 = __uint_as_float(e0.y);
        float4 v0 = h4[(size_t)e0.x * 2 + g];
        acc.x = fmaf(w0, v0.x, acc.x); acc.y = fmaf(w0, v0.y, acc.y);
        acc.z = fmaf(w0, v0.z, acc.z); acc.w = fmaf(w0, v0.w, acc.w);
    }
    ((float4*)outF)[(size_t)n * 2 + g] = acc;
}

// ---------- bf16 aggregate, 16B/lane ----------
// EPI: 0 = store bf16; 1 = bias+relu+store bf16; 3 = bias+relu+colmax, NO store
template<int W, int EPI>
__global__ __launch_bounds__(256) void k_ag16(const uint4* __restrict__ hin,
        const float* __restrict__ dinv, const int* __restrict__ row_off,
        const int* __restrict__ counts, const uint2* __restrict__ edges,
        const float* __restrict__ bias, uint4* __restrict__ outB,
        float* __restrict__ xmax) {
    constexpr int TPN = W / 8;
    __shared__ int smax[(EPI == 3) ? W : 1];
    int tid = blockIdx.x * 256 + threadIdx.x;
    int n = tid / TPN, c = tid % TPN;
    if (EPI == 3) {
        if (threadIdx.x < W) smax[threadIdx.x] = 0;
        __syncthreads();
    }
    float acc[8];
    bool valid = (n < NN);
    if (valid) {
        float di = dinv[n];
        float d2 = di * di;
        float a[8];
        up8(hin[(size_t)n * TPN + c], a);
#pragma unroll
        for (int j = 0; j < 8; j++) acc[j] = a[j] * d2;
        int start = row_off[n], len = counts[n];
        int i = 0;
        for (; i + 2 <= len; i += 2) {
            uint2 e0 = edges[start + i], e1 = edges[start + i + 1];
            float w0 = __uint_as_float(e0.y), w1 = __uint_as_float(e1.y);
            uint4 u0 = hin[(size_t)e0.x * TPN + c];
            uint4 u1 = hin[(size_t)e1.x * TPN + c];
            float a0[8], a1[8];
            up8(u0, a0); up8(u1, a1);
#pragma unroll
            for (int j = 0; j < 8; j++) acc[j] = fmaf(w0, a0[j], acc[j]);
#pragma unroll
            for (int j = 0; j < 8; j++) acc[j] = fmaf(w1, a1[j], acc[j]);
        }
        if (i < len) {
            uint2 e0 = edges[start + i];
            float w0 = __uint_as_float(e0.y);
            float a0[8];
            up8(hin[(size_t)e0.x * TPN + c], a0);
#pragma unroll
            for (int j = 0; j < 8; j++) acc[j] = fmaf(w0, a0[j], acc[j]);
        }
        if (EPI >= 1) {
#pragma unroll
            for (int j = 0; j < 8; j++) acc[j] = fmaxf(acc[j] + bias[c * 8 + j], 0.f);
        }
        if (EPI != 3) {
            uint4 o;
            o.x = f2bu(acc[0]) | (f2bu(acc[1]) << 16);
            o.y = f2bu(acc[2]) | (f2bu(acc[3]) << 16);
            o.z = f2bu(acc[4]) | (f2bu(acc[5]) << 16);
            o.w = f2bu(acc[6]) | (f2bu(acc[7]) << 16);
            outB[(size_t)n * TPN + c] = o;
        } else {
#pragma unroll
            for (int j = 0; j < 8; j++) atomicMax(&smax[c * 8 + j], __float_as_int(acc[j]));
        }
    }
    if (EPI == 3) {
        __syncthreads();
        if (threadIdx.x < W) atomicMax((int*)&xmax[threadIdx.x], smax[threadIdx.x]);
    }
}

// ---------- head MLP + softmax + fp32 output ----------
__global__ void k_mlp(const float* x0x1, const float* C2,
                      const float* L1W, const float* L1b,
                      const float* L2W, const float* L2b,
                      const float* L3W, const float* L3b, float* out) {
    __shared__ float code[68], z1[128], z2[128];
    int t = threadIdx.x;
    if (t < 64) code[t] = x0x1[t];
    else if (t < 68) code[t] = C2[t - 64];
    __syncthreads();
    float acc = L1b[t];
    for (int i = 0; i < 68; i++) acc = fmaf(code[i], L1W[i * 128 + t], acc);
    z1[t] = fmaxf(acc, 0.f);
    __syncthreads();
    acc = L2b[t];
    for (int i = 0; i < 128; i++) acc = fmaf(z1[i], L2W[i * 128 + t], acc);
    z2[t] = fmaxf(acc, 0.f);
    __syncthreads();
    if (t == 0) {
        float lg[10];
        for (int c = 0; c < 10; c++) {
            float a = L3b[c];
            for (int i = 0; i < 128; i++) a = fmaf(z2[i], L3W[i * 10 + c], a);
            lg[c] = a;
        }
        float m = lg[0];
        for (int c = 1; c < 10; c++) m = fmaxf(m, lg[c]);
        float s = 0.f;
        for (int c = 0; c < 10; c++) { lg[c] = __expf(lg[c] - m); s += lg[c]; }
        float inv = 1.f / s;
        for (int c = 0; c < 10; c++) out[c] = lg[c] * inv;
    }
    if (t < 68) out[10 + t] = code[t];
}

extern "C" void kernel_launch(void* const* d_in, const int* in_sizes, int n_in,
                              void* d_out, int out_size, void* d_ws, size_t ws_size,
                              hipStream_t stream) {
    const float* x   = (const float*)d_in[0];
    const int*   ei  = (const int*)d_in[1];
    const float* ew  = (const float*)d_in[2];
    const float* C2  = (const float*)d_in[4];
    const float* W1  = (const float*)d_in[5],  * b1 = (const float*)d_in[6];
    const float* W2  = (const float*)d_in[7],  * b2 = (const float*)d_in[8];
    const float* W3  = (const float*)d_in[9],  * b3 = (const float*)d_in[10];
    const float* W4  = (const float*)d_in[11], * b4 = (const float*)d_in[12];
    const float* L1W = (const float*)d_in[13], * L1b = (const float*)d_in[14];
    const float* L2W = (const float*)d_in[15], * L2b = (const float*)d_in[16];
    const float* L3W = (const float*)d_in[17], * L3b = (const float*)d_in[18];
    float* out = (float*)d_out;
    (void)in_sizes; (void)n_in; (void)out_size; (void)ws_size;

    const size_t szF = (size_t)NN * 128 * 4;
    char* p = (char*)d_ws;
    char* H       = p;          p += szF;
    char* T       = p;          p += szF;
    uint2* edges  = (uint2*)p;  p += (size_t)NE * 8;
    float* dinv   = (float*)p;  p += (size_t)NN * 4;
    int*   ctot   = (int*)p;    p += (size_t)NN * 4;
    int*   rowoff = (int*)p;    p += (size_t)NN * 4;
    int*   counts8= (int*)p;    p += (size_t)NN * 8 * 4;
    int*   cur8   = (int*)p;    p += (size_t)NN * 8 * 4;
    int*   blk    = (int*)p;    p += 1024;
    float* x0x1   = (float*)p;  p += 256 * 4;
    short* Wt2    = (short*)p;  p += 4096 * 2;
    short* Wt3    = (short*)p;  p += 16384 * 2;
    short* Wt4    = (short*)p;  p += 4096 * 2;

    const int* srcI = ei;
    const int* dstI = ei + NE;

    dim3 B(256);
    k_prep<<<dim3((NN + 255) / 256), B, 0, stream>>>(counts8, x0x1, W2, W3, W4, Wt2, Wt3, Wt4);
    k_count<<<dim3((NE + 255) / 256), B, 0, stream>>>(dstI, counts8);
    k_scan1<<<dim3(98), dim3(1024), 0, stream>>>(counts8, ctot, rowoff, blk);
    k_scan2<<<dim3(1), dim3(64), 0, stream>>>(blk);
    k_scan3<<<dim3((NN + 255) / 256), B, 0, stream>>>(rowoff, blk, counts8, cur8);
    k_fill<<<dim3((NE + 255) / 256), B, 0, stream>>>(srcI, dstI, ew, cur8, edges);
    k_deg<<<dim3((NN + 255) / 256), B, 0, stream>>>(rowoff, ctot, edges, dinv);
    k_norm<<<dim3((NN + 255) / 256), B, 0, stream>>>(rowoff, ctot, dinv, edges);

    const int MG = (NN + 63) / 64;

    // L1: agg x @8 fp32 -> T fp32; VALU gemm 8->32 +bias+relu+max -> H bf16
    k_ag8<<<dim3((NN * 2 + 255) / 256), B, 0, stream>>>(x, dinv, rowoff, ctot, edges, (float*)T);
    k_gemm8<<<dim3((NN + 255) / 256), B, 0, stream>>>((const float*)T, W1, (unsigned int*)H, b1, x0x1);
    // L2: agg H bf16 @32 -> T bf16; MFMA 32->128 +bias+relu -> H bf16
    k_ag16<32, 0><<<dim3((NN * 4 + 255) / 256), B, 0, stream>>>(
        (const uint4*)H, dinv, rowoff, ctot, edges, nullptr, (uint4*)T, nullptr);
    k_mgemm<32, 128, 1><<<dim3(MG), B, 0, stream>>>((const short*)T, Wt2, (unsigned short*)H, b2);
    // L3: MFMA 128->128 -> T bf16; agg @128 +bias+relu -> H bf16
    k_mgemm<128, 128, 0><<<dim3(MG), B, 0, stream>>>((const short*)H, Wt3, (unsigned short*)T, nullptr);
    k_ag16<128, 1><<<dim3((NN * 16 + 255) / 256), B, 0, stream>>>(
        (const uint4*)T, dinv, rowoff, ctot, edges, b3, (uint4*)H, nullptr);
    // L4: MFMA 128->32 -> T bf16; agg @32 +bias+relu+max (no store)
    k_mgemm<128, 32, 0><<<dim3(MG), B, 0, stream>>>((const short*)H, Wt4, (unsigned short*)T, nullptr);
    k_ag16<32, 3><<<dim3((NN * 4 + 255) / 256), B, 0, stream>>>(
        (const uint4*)T, dinv, rowoff, ctot, edges, b4, nullptr, x0x1 + 32);

    k_mlp<<<dim3(1), dim3(128), 0, stream>>>(x0x1, C2, L1W, L1b, L2W, L2b, L3W, L3b, out);
}